// Round 1
// baseline (3998.971 us; speedup 1.0000x reference)
//
#include <hip/hip_runtime.h>
#include <math.h>

// Problem constants (fixed by setup_inputs):
// T=4096, M=512, NH=8, HD=64, FF=2048, NL=2, NI=256 (16 tok/seg), NO=32 (8 seg/outer)

__device__ __forceinline__ float wave_sum64(float v) {
#pragma unroll
  for (int o = 32; o > 0; o >>= 1) v += __shfl_xor(v, o);
  return v;
}

// ---------------- GEMM: C[M,N] = act(A[M,K] @ B[N,K]^T + bias[N]) ----------------
// Requires M%64==0, N%64==0, K%16==0. ACT: 0=none 1=relu 2=tanh 3=sigmoid
template<int ACT>
__global__ __launch_bounds__(256) void gemm_bias(
    const float* __restrict__ A, const float* __restrict__ B,
    const float* __restrict__ bias, float* __restrict__ C,
    int M, int N, int K)
{
  __shared__ float As[16][68];
  __shared__ float Bs[16][68];
  const int tid = threadIdx.x;
  const int tx = tid & 15, ty = tid >> 4;
  const int m0 = blockIdx.y * 64, n0 = blockIdx.x * 64;
  const int lr = tid >> 2;          // 0..63 row within tile
  const int lk = (tid & 3) * 4;     // 0,4,8,12 k within tile
  float acc[4][4] = {};
  for (int k0 = 0; k0 < K; k0 += 16) {
    __syncthreads();
    float4 av = *(const float4*)&A[(size_t)(m0 + lr) * K + k0 + lk];
    float4 bv = *(const float4*)&B[(size_t)(n0 + lr) * K + k0 + lk];
    As[lk + 0][lr] = av.x; As[lk + 1][lr] = av.y; As[lk + 2][lr] = av.z; As[lk + 3][lr] = av.w;
    Bs[lk + 0][lr] = bv.x; Bs[lk + 1][lr] = bv.y; Bs[lk + 2][lr] = bv.z; Bs[lk + 3][lr] = bv.w;
    __syncthreads();
#pragma unroll
    for (int k = 0; k < 16; k++) {
      float a[4], b[4];
#pragma unroll
      for (int i = 0; i < 4; i++) a[i] = As[k][ty * 4 + i];
#pragma unroll
      for (int j = 0; j < 4; j++) b[j] = Bs[k][tx * 4 + j];
#pragma unroll
      for (int i = 0; i < 4; i++)
#pragma unroll
        for (int j = 0; j < 4; j++)
          acc[i][j] = fmaf(a[i], b[j], acc[i][j]);
    }
  }
  const float4 bv4 = *(const float4*)&bias[n0 + tx * 4];
  const float bb[4] = {bv4.x, bv4.y, bv4.z, bv4.w};
#pragma unroll
  for (int i = 0; i < 4; i++) {
    float r[4];
#pragma unroll
    for (int j = 0; j < 4; j++) {
      float x = acc[i][j] + bb[j];
      if (ACT == 1) x = fmaxf(x, 0.f);
      if (ACT == 2) x = tanhf(x);
      if (ACT == 3) x = 1.f / (1.f + expf(-x));
      r[j] = x;
    }
    *(float4*)&C[(size_t)(m0 + ty * 4 + i) * N + n0 + tx * 4] =
        make_float4(r[0], r[1], r[2], r[3]);
  }
}

// ---------------- Flash attention (fp32), 8 heads, hd=64, T=4096 ----------------
// qkv: (4096, 1536) = [Q | K | V], O: (4096, 512). block: (qt, head), 256 threads.
__global__ __launch_bounds__(256) void flash_attn(
    const float* __restrict__ qkv, float* __restrict__ O)
{
  __shared__ float Qs[64][68];
  __shared__ float Ks[64][68];   // reused to hold P after scores are consumed
  __shared__ float Vs[64][68];
  const int tid = threadIdx.x;
  const int h = blockIdx.y;
  const int qt = blockIdx.x;
  const int r = tid >> 2;            // 0..63
  const int cb = (tid & 3) * 16;     // 0,16,32,48
  {
    const float* qp = qkv + (size_t)(qt * 64 + r) * 1536 + h * 64 + cb;
#pragma unroll
    for (int i = 0; i < 4; i++)
      *(float4*)&Qs[r][cb + 4 * i] = *(const float4*)(qp + 4 * i);
  }
  const int q = tid >> 2, g = tid & 3;
  float m = -1e30f, l = 0.f;
  float oacc[16];
#pragma unroll
  for (int j = 0; j < 16; j++) oacc[j] = 0.f;

  for (int kt = 0; kt < 64; kt++) {
    __syncthreads();  // prior PV reads of Ks/Vs done
    {
      const float* kp = qkv + (size_t)(kt * 64 + r) * 1536 + 512 + h * 64 + cb;
      const float* vp = kp + 512;
#pragma unroll
      for (int i = 0; i < 4; i++) {
        *(float4*)&Ks[r][cb + 4 * i] = *(const float4*)(kp + 4 * i);
        *(float4*)&Vs[r][cb + 4 * i] = *(const float4*)(vp + 4 * i);
      }
    }
    __syncthreads();
    // scores: s[kk] = Q[q,:] . K[g*16+kk,:]
    float s[16];
#pragma unroll
    for (int kk = 0; kk < 16; kk++) s[kk] = 0.f;
    for (int d4 = 0; d4 < 16; d4++) {
      float4 qv = *(const float4*)&Qs[q][d4 * 4];
#pragma unroll
      for (int kk = 0; kk < 16; kk++) {
        float4 kv = *(const float4*)&Ks[g * 16 + kk][d4 * 4];
        s[kk] = fmaf(qv.x, kv.x, s[kk]);
        s[kk] = fmaf(qv.y, kv.y, s[kk]);
        s[kk] = fmaf(qv.z, kv.z, s[kk]);
        s[kk] = fmaf(qv.w, kv.w, s[kk]);
      }
    }
    float tmax = -1e30f;
#pragma unroll
    for (int kk = 0; kk < 16; kk++) { s[kk] *= 0.125f; tmax = fmaxf(tmax, s[kk]); }
    tmax = fmaxf(tmax, __shfl_xor(tmax, 1));
    tmax = fmaxf(tmax, __shfl_xor(tmax, 2));
    float mnew = fmaxf(m, tmax);
    float alpha = expf(m - mnew);
    float p[16];
    float psum = 0.f;
#pragma unroll
    for (int kk = 0; kk < 16; kk++) { p[kk] = expf(s[kk] - mnew); psum += p[kk]; }
    psum += __shfl_xor(psum, 1);
    psum += __shfl_xor(psum, 2);
    l = l * alpha + psum;
    m = mnew;
#pragma unroll
    for (int j = 0; j < 16; j++) oacc[j] *= alpha;
    __syncthreads();  // all score reads of Ks done; reuse Ks as P
#pragma unroll
    for (int i = 0; i < 4; i++)
      *(float4*)&Ks[q][g * 16 + 4 * i] =
          make_float4(p[4 * i], p[4 * i + 1], p[4 * i + 2], p[4 * i + 3]);
    __syncthreads();
    // PV: oacc[j] += sum_k P[q,k] * V[k, g*16+j]
    for (int k = 0; k < 64; k++) {
      float pk = Ks[q][k];
      float4 v0 = *(const float4*)&Vs[k][g * 16 + 0];
      float4 v1 = *(const float4*)&Vs[k][g * 16 + 4];
      float4 v2 = *(const float4*)&Vs[k][g * 16 + 8];
      float4 v3 = *(const float4*)&Vs[k][g * 16 + 12];
      oacc[0]  = fmaf(pk, v0.x, oacc[0]);  oacc[1]  = fmaf(pk, v0.y, oacc[1]);
      oacc[2]  = fmaf(pk, v0.z, oacc[2]);  oacc[3]  = fmaf(pk, v0.w, oacc[3]);
      oacc[4]  = fmaf(pk, v1.x, oacc[4]);  oacc[5]  = fmaf(pk, v1.y, oacc[5]);
      oacc[6]  = fmaf(pk, v1.z, oacc[6]);  oacc[7]  = fmaf(pk, v1.w, oacc[7]);
      oacc[8]  = fmaf(pk, v2.x, oacc[8]);  oacc[9]  = fmaf(pk, v2.y, oacc[9]);
      oacc[10] = fmaf(pk, v2.z, oacc[10]); oacc[11] = fmaf(pk, v2.w, oacc[11]);
      oacc[12] = fmaf(pk, v3.x, oacc[12]); oacc[13] = fmaf(pk, v3.y, oacc[13]);
      oacc[14] = fmaf(pk, v3.z, oacc[14]); oacc[15] = fmaf(pk, v3.w, oacc[15]);
    }
  }
  float inv = 1.f / l;
  float* op = O + (size_t)(qt * 64 + q) * 512 + h * 64 + g * 16;
#pragma unroll
  for (int i = 0; i < 4; i++)
    *(float4*)(op + 4 * i) = make_float4(oacc[4 * i] * inv, oacc[4 * i + 1] * inv,
                                         oacc[4 * i + 2] * inv, oacc[4 * i + 3] * inv);
}

// ---------------- out = LayerNorm(x + res) over last dim (512) ----------------
__global__ __launch_bounds__(64) void residual_ln(
    const float* __restrict__ x, const float* __restrict__ res,
    const float* __restrict__ g, const float* __restrict__ b,
    float* __restrict__ out)
{
  const int row = blockIdx.x, lane = threadIdx.x;
  const float* xp = x + (size_t)row * 512;
  const float* rp = res + (size_t)row * 512;
  float v[8];
  float s = 0.f;
#pragma unroll
  for (int i = 0; i < 8; i++) { v[i] = xp[lane + 64 * i] + rp[lane + 64 * i]; s += v[i]; }
  s = wave_sum64(s);
  float mu = s * (1.f / 512.f);
  float vs = 0.f;
#pragma unroll
  for (int i = 0; i < 8; i++) { float d = v[i] - mu; vs = fmaf(d, d, vs); }
  vs = wave_sum64(vs);
  float rstd = rsqrtf(vs * (1.f / 512.f) + 1e-5f);
  float* op = out + (size_t)row * 512;
#pragma unroll
  for (int i = 0; i < 8; i++)
    op[lane + 64 * i] = (v[i] - mu) * rstd * g[lane + 64 * i] + b[lane + 64 * i];
}

// ---------------- A[t] = sum_l Gv[t,l]*Gu[t,l]*Ww[l] + bw ----------------
__global__ __launch_bounds__(128) void gate_dot(
    const float* __restrict__ Gv, const float* __restrict__ Gu,
    const float* __restrict__ Ww, const float* __restrict__ bw,
    float* __restrict__ A)
{
  const int t = blockIdx.x, l = threadIdx.x;
  float v = Gv[(size_t)t * 128 + l] * Gu[(size_t)t * 128 + l] * Ww[l];
  v = wave_sum64(v);
  __shared__ float red[2];
  if ((l & 63) == 0) red[l >> 6] = v;
  __syncthreads();
  if (l == 0) A[t] = red[0] + red[1] + bw[0];
}

// ------- per-contiguous-segment softmax (w) + weighted pooled sum over X (D=512) -------
__global__ __launch_bounds__(256) void seg_pool(
    const float* __restrict__ A, const float* __restrict__ X,
    float* __restrict__ w_out, float* __restrict__ out, int seg_len)
{
  const int s = blockIdx.x, tid = threadIdx.x;
  __shared__ float ws[16];
  if (tid < 64) {
    float a = (tid < seg_len) ? A[s * seg_len + tid] : -1e30f;
    float mx = a;
#pragma unroll
    for (int o = 1; o < 16; o <<= 1) mx = fmaxf(mx, __shfl_xor(mx, o));
    float e = (tid < seg_len) ? expf(a - mx) : 0.f;
    float se = e;
#pragma unroll
    for (int o = 1; o < 16; o <<= 1) se += __shfl_xor(se, o);
    if (tid < seg_len) {
      float w = e / se;
      ws[tid] = w;
      w_out[s * seg_len + tid] = w;
    }
  }
  __syncthreads();
  for (int d = tid; d < 512; d += 256) {
    float acc = 0.f;
    for (int i = 0; i < seg_len; i++)
      acc = fmaf(ws[i], X[(size_t)(s * seg_len + i) * 512 + d], acc);
    out[(size_t)s * 512 + d] = acc;
  }
}

// ---------------- conv1: (32,1,512) -> (32,128,512), K=4, pad (1,2), BN, relu ----------------
__global__ void conv1_bn_relu(
    const float* __restrict__ x, const float* __restrict__ K,
    const float* __restrict__ bias, const float* __restrict__ g,
    const float* __restrict__ bb, float* __restrict__ y)
{
  int idx = blockIdx.x * 256 + threadIdx.x;   // 32*128*512
  int i = idx & 511, o = (idx >> 9) & 127, n = idx >> 16;
  const float* xp = x + n * 512;
  float acc = bias[o];
#pragma unroll
  for (int k = 0; k < 4; k++) {
    int p = i + k - 1;
    float xv = (p >= 0 && p < 512) ? xp[p] : 0.f;
    acc = fmaf(xv, K[o * 4 + k], acc);
  }
  float sc = g[o] * rsqrtf(1.f + 1e-5f);
  y[idx] = fmaxf(fmaf(acc, sc, bb[o]), 0.f);
}

// ------- convK: (32,128,LEN) -> (32,128,LEN), kernel KS, symmetric-ish pad, BN, relu -------
template<int KS, int PAD, int LEN>
__global__ void convK_bn_relu(
    const float* __restrict__ x, const float* __restrict__ K,
    const float* __restrict__ bias, const float* __restrict__ g,
    const float* __restrict__ bb, float* __restrict__ y)
{
  int idx = blockIdx.x * 256 + threadIdx.x;   // 32*128*LEN
  int i = idx % LEN;
  int o = (idx / LEN) & 127;
  int n = idx / (LEN * 128);
  const float* xn = x + (size_t)n * 128 * LEN;
  const float* kw = K + (size_t)o * 128 * KS;
  float acc = bias[o];
  for (int c = 0; c < 128; c++) {
    const float* xc = xn + c * LEN;
#pragma unroll
    for (int k = 0; k < KS; k++) {
      int p = i + k - PAD;
      float xv = (p >= 0 && p < LEN) ? xc[p] : 0.f;
      acc = fmaf(xv, kw[c * KS + k], acc);
    }
  }
  float sc = g[o] * rsqrtf(1.f + 1e-5f);
  y[idx] = fmaxf(fmaf(acc, sc, bb[o]), 0.f);
}

// ---------------- mean over adjacent pairs along last dim ----------------
__global__ void avgpool2(const float* __restrict__ x, float* __restrict__ y, int n_out)
{
  int idx = blockIdx.x * 256 + threadIdx.x;
  if (idx < n_out) y[idx] = 0.5f * (x[2 * idx] + x[2 * idx + 1]);
}

// ---------------- FC1: (32,16384)@(256,16384)^T, relu then BN ----------------
__global__ __launch_bounds__(256) void fc1_kernel(
    const float* __restrict__ x, const float* __restrict__ W,
    const float* __restrict__ bias, const float* __restrict__ g,
    const float* __restrict__ bb, float* __restrict__ y)
{
  int o = blockIdx.x & 255, n = blockIdx.x >> 8;
  const float* xp = x + (size_t)n * 16384;
  const float* wp = W + (size_t)o * 16384;
  float s = 0.f;
  for (int j = threadIdx.x * 4; j < 16384; j += 1024) {
    float4 a = *(const float4*)(xp + j);
    float4 b = *(const float4*)(wp + j);
    s = fmaf(a.x, b.x, s); s = fmaf(a.y, b.y, s);
    s = fmaf(a.z, b.z, s); s = fmaf(a.w, b.w, s);
  }
  s = wave_sum64(s);
  __shared__ float red[4];
  if ((threadIdx.x & 63) == 0) red[threadIdx.x >> 6] = s;
  __syncthreads();
  if (threadIdx.x == 0) {
    float v = red[0] + red[1] + red[2] + red[3] + bias[o];
    v = fmaxf(v, 0.f);
    y[n * 256 + o] = fmaf(v, g[o] * rsqrtf(1.f + 1e-5f), bb[o]);
  }
}

// ---------------- FC2: (32,256)@(128,256)^T, relu then BN ----------------
__global__ __launch_bounds__(256) void fc2_kernel(
    const float* __restrict__ x, const float* __restrict__ W,
    const float* __restrict__ bias, const float* __restrict__ g,
    const float* __restrict__ bb, float* __restrict__ y)
{
  int o = blockIdx.x & 127, n = blockIdx.x >> 7;
  float s = x[n * 256 + threadIdx.x] * W[o * 256 + threadIdx.x];
  s = wave_sum64(s);
  __shared__ float red[4];
  if ((threadIdx.x & 63) == 0) red[threadIdx.x >> 6] = s;
  __syncthreads();
  if (threadIdx.x == 0) {
    float v = red[0] + red[1] + red[2] + red[3] + bias[o];
    v = fmaxf(v, 0.f);
    y[n * 128 + o] = fmaf(v, g[o] * rsqrtf(1.f + 1e-5f), bb[o]);
  }
}

// ---------------- FC3 + sigmoid + threshold -> d_out[0:32]=Y_prob, [32:64]=Y_hat ----------------
__global__ __launch_bounds__(64) void fc3_kernel(
    const float* __restrict__ x, const float* __restrict__ W,
    const float* __restrict__ bias, float* __restrict__ out)
{
  int n = threadIdx.x;
  if (n < 32) {
    float s = bias[0];
    for (int k = 0; k < 128; k++) s = fmaf(x[n * 128 + k], W[k], s);
    float p = 1.f / (1.f + expf(-s));
    out[n] = p;
    out[32 + n] = (p >= 0.5f) ? 1.f : 0.f;
  }
}

extern "C" void kernel_launch(void* const* d_in, const int* in_sizes, int n_in,
                              void* d_out, int out_size, void* d_ws, size_t ws_size,
                              hipStream_t stream)
{
  const float* datas = (const float*)d_in[0];
  const float* Wqkv = (const float*)d_in[6];
  const float* bqkv = (const float*)d_in[7];
  const float* Wo   = (const float*)d_in[8];
  const float* bo   = (const float*)d_in[9];
  const float* ln1g = (const float*)d_in[10];
  const float* ln1b = (const float*)d_in[11];
  const float* W1   = (const float*)d_in[12];
  const float* b1   = (const float*)d_in[13];
  const float* W2   = (const float*)d_in[14];
  const float* b2   = (const float*)d_in[15];
  const float* ln2g = (const float*)d_in[16];
  const float* ln2b = (const float*)d_in[17];
  const float* Wv1  = (const float*)d_in[18];
  const float* bv1  = (const float*)d_in[19];
  const float* Wu1  = (const float*)d_in[20];
  const float* bu1  = (const float*)d_in[21];
  const float* Ww1  = (const float*)d_in[22];
  const float* bw1  = (const float*)d_in[23];
  const float* Wv2  = (const float*)d_in[24];
  const float* bv2  = (const float*)d_in[25];
  const float* Wu2  = (const float*)d_in[26];
  const float* bu2  = (const float*)d_in[27];
  const float* Ww2  = (const float*)d_in[28];
  const float* bw2  = (const float*)d_in[29];
  const float* Kc1  = (const float*)d_in[30];
  const float* bc1  = (const float*)d_in[31];
  const float* gc1  = (const float*)d_in[32];
  const float* bb1  = (const float*)d_in[33];
  const float* Kc2  = (const float*)d_in[34];
  const float* bc2  = (const float*)d_in[35];
  const float* gc2  = (const float*)d_in[36];
  const float* bb2  = (const float*)d_in[37];
  const float* Kc3  = (const float*)d_in[38];
  const float* bc3  = (const float*)d_in[39];
  const float* gc3  = (const float*)d_in[40];
  const float* bb3  = (const float*)d_in[41];
  const float* Wf1  = (const float*)d_in[42];
  const float* bf1  = (const float*)d_in[43];
  const float* g4   = (const float*)d_in[44];
  const float* b4   = (const float*)d_in[45];
  const float* Wf2  = (const float*)d_in[46];
  const float* bf2  = (const float*)d_in[47];
  const float* g5   = (const float*)d_in[48];
  const float* b5   = (const float*)d_in[49];
  const float* Wf3  = (const float*)d_in[50];
  const float* bf3  = (const float*)d_in[51];

  float* ws  = (float*)d_ws;
  float* h   = ws;                  // 4096*512       = 2,097,152
  float* big = ws + 2097152;        // 8,388,608 (qkv / ff1 / pooling+CNN overlays)
  float* tmp = ws + 10485760;       // 2,097,152 (attn-O / ff2 / conv1 out)
  // total ws need: 12,582,912 floats = 50.3 MB

  float* out_f = (float*)d_out;

  hipMemcpyAsync(h, datas, (size_t)2097152 * sizeof(float),
                 hipMemcpyDeviceToDevice, stream);

  for (int l = 0; l < 2; l++) {
    // qkv = h @ Wqkv^T + bqkv   (4096,1536)
    gemm_bias<0><<<dim3(24, 64), 256, 0, stream>>>(
        h, Wqkv + (size_t)l * 1536 * 512, bqkv + (size_t)l * 1536, big, 4096, 1536, 512);
    // attention -> tmp (4096,512)
    flash_attn<<<dim3(64, 8), 256, 0, stream>>>(big, tmp);
    // proj = tmp @ Wo^T + bo -> big
    gemm_bias<0><<<dim3(8, 64), 256, 0, stream>>>(
        tmp, Wo + (size_t)l * 512 * 512, bo + (size_t)l * 512, big, 4096, 512, 512);
    // h = LN(proj + h)
    residual_ln<<<4096, 64, 0, stream>>>(big, h, ln1g + l * 512, ln1b + l * 512, h);
    // ff1 = relu(h @ W1^T + b1) -> big (4096,2048)
    gemm_bias<1><<<dim3(32, 64), 256, 0, stream>>>(
        h, W1 + (size_t)l * 2048 * 512, b1 + (size_t)l * 2048, big, 4096, 2048, 512);
    // ff2 = ff1 @ W2^T + b2 -> tmp (4096,512)
    gemm_bias<0><<<dim3(8, 64), 256, 0, stream>>>(
        big, W2 + (size_t)l * 512 * 2048, b2 + (size_t)l * 512, tmp, 4096, 512, 2048);
    // h = LN(ff2 + h)
    residual_ln<<<4096, 64, 0, stream>>>(tmp, h, ln2g + l * 512, ln2b + l * 512, h);
  }

  // ---- gated pooling stage 1 (4096 tokens -> 256 segments) ----
  float* Gv   = big;
  float* Gu   = big + 524288;
  float* A1   = big + 1048576;
  float* out1 = big + 1052672;      // 256*512
  float* Gv2  = big + 1183744;
  float* Gu2  = big + 1216512;
  float* A2   = big + 1249280;
  float* out2 = big + 1249536;      // 32*512

  gemm_bias<2><<<dim3(2, 64), 256, 0, stream>>>(h, Wv1, bv1, Gv, 4096, 128, 512);
  gemm_bias<3><<<dim3(2, 64), 256, 0, stream>>>(h, Wu1, bu1, Gu, 4096, 128, 512);
  gate_dot<<<4096, 128, 0, stream>>>(Gv, Gu, Ww1, bw1, A1);
  seg_pool<<<256, 256, 0, stream>>>(A1, h, out_f + 64, out1, 16);

  // ---- stage 2 (256 segments -> 32 outer) ----
  gemm_bias<2><<<dim3(2, 4), 256, 0, stream>>>(out1, Wv2, bv2, Gv2, 256, 128, 512);
  gemm_bias<3><<<dim3(2, 4), 256, 0, stream>>>(out1, Wu2, bu2, Gu2, 256, 128, 512);
  gate_dot<<<256, 128, 0, stream>>>(Gv2, Gu2, Ww2, bw2, A2);
  seg_pool<<<32, 256, 0, stream>>>(A2, out1, out_f + 4160, out2, 8);

  // ---- CNN head ----
  float* c1 = tmp;                  // 32*128*512 = 2,097,152 (exactly tmp)
  float* c2 = big + 2097152;        // 32*128*512
  float* p2 = big + 4194304;        // 32*128*256
  float* c3 = big + 5242880;        // 32*128*256
  float* p3 = big + 6291456;        // 32*128*128
  float* f1 = big + 6815744;        // 32*256
  float* f2 = big + 6823936;        // 32*128

  conv1_bn_relu<<<8192, 256, 0, stream>>>(out2, Kc1, bc1, gc1, bb1, c1);
  convK_bn_relu<5, 2, 512><<<8192, 256, 0, stream>>>(c1, Kc2, bc2, gc2, bb2, c2);
  avgpool2<<<4096, 256, 0, stream>>>(c2, p2, 1048576);
  convK_bn_relu<7, 3, 256><<<4096, 256, 0, stream>>>(p2, Kc3, bc3, gc3, bb3, c3);
  avgpool2<<<2048, 256, 0, stream>>>(c3, p3, 524288);
  fc1_kernel<<<8192, 256, 0, stream>>>(p3, Wf1, bf1, g4, b4, f1);
  fc2_kernel<<<4096, 256, 0, stream>>>(f1, Wf2, bf2, g5, b5, f2);
  fc3_kernel<<<1, 64, 0, stream>>>(f2, Wf3, bf3, out_f);
}

// Round 2
// 1201.203 us; speedup vs baseline: 3.3291x; 3.3291x over previous
//
#include <hip/hip_runtime.h>
#include <math.h>

// T=4096, M=512, NH=8, HD=64, FF=2048, NL=2, NI=256 (16 tok/seg), NO=32 (8 seg/outer)

typedef float f32x4 __attribute__((ext_vector_type(4)));
typedef __bf16 bf16x8 __attribute__((ext_vector_type(8)));

__device__ __forceinline__ unsigned short f2bf(float x) {
  unsigned int u = __builtin_bit_cast(unsigned int, x);
  u += 0x7FFFu + ((u >> 16) & 1u);
  return (unsigned short)(u >> 16);
}

__device__ __forceinline__ float wave_sum64(float v) {
#pragma unroll
  for (int o = 32; o > 0; o >>= 1) v += __shfl_xor(v, o);
  return v;
}

// XOR swizzle for LDS tiles with 128-byte rows (64 bf16/row): spreads the
// 16-lane same-column ds_read_b128 across 8 granules (16-way -> 2-way free).
__device__ __forceinline__ int swz(int byte) {
  return byte ^ (((byte >> 7) & 7) << 4);
}

// ============ bf16 MFMA GEMM: C[M,N] = act(A[M,K] @ B[N,K]^T + bias) ============
// A,B bf16 row-major. M%128==0, N%128==0, K%64==0. 256 thr = 4 waves (2x2 of 64x64).
// ACT: 0 none, 1 relu, 2 tanh, 3 sigmoid. OUTBF: 1 -> bf16 out, 0 -> f32 out.
template<int ACT, int OUTBF>
__global__ __launch_bounds__(256) void mgemm(
    const unsigned short* __restrict__ A, const unsigned short* __restrict__ B,
    const float* __restrict__ bias, float* __restrict__ Cf,
    unsigned short* __restrict__ Cb, int M, int N, int K)
{
  __shared__ __align__(16) unsigned short As[128 * 64];
  __shared__ __align__(16) unsigned short Bs[128 * 64];
  const int tid = threadIdx.x;
  const int wid = tid >> 6, lane = tid & 63;
  const int wm = wid >> 1, wn = wid & 1;
  const int l15 = lane & 15, l4 = lane >> 4;
  const int m0 = blockIdx.y * 128, n0 = blockIdx.x * 128;
  const int srow = tid >> 3;          // 0..31
  const int scol = (tid & 7) * 8;     // 0..56

  f32x4 acc[4][4] = {};

  for (int k0 = 0; k0 < K; k0 += 64) {
    bf16x8 ra[4], rb[4];
#pragma unroll
    for (int i = 0; i < 4; i++) {
      ra[i] = *(const bf16x8*)&A[(size_t)(m0 + srow + i * 32) * K + k0 + scol];
      rb[i] = *(const bf16x8*)&B[(size_t)(n0 + srow + i * 32) * K + k0 + scol];
    }
    __syncthreads();   // all waves done reading previous tile
#pragma unroll
    for (int i = 0; i < 4; i++) {
      int byte = (srow + i * 32) * 128 + scol * 2;
      *(bf16x8*)((char*)As + swz(byte)) = ra[i];
      *(bf16x8*)((char*)Bs + swz(byte)) = rb[i];
    }
    __syncthreads();
#pragma unroll
    for (int kc = 0; kc < 2; kc++) {
      bf16x8 af[4], bf_[4];
#pragma unroll
      for (int i = 0; i < 4; i++) {
        int byteA = (wm * 64 + i * 16 + l15) * 128 + kc * 64 + l4 * 16;
        af[i] = *(const bf16x8*)((const char*)As + swz(byteA));
        int byteB = (wn * 64 + i * 16 + l15) * 128 + kc * 64 + l4 * 16;
        bf_[i] = *(const bf16x8*)((const char*)Bs + swz(byteB));
      }
#pragma unroll
      for (int i = 0; i < 4; i++)
#pragma unroll
        for (int j = 0; j < 4; j++)
          acc[i][j] = __builtin_amdgcn_mfma_f32_16x16x32_bf16(af[i], bf_[j], acc[i][j], 0, 0, 0);
    }
  }
#pragma unroll
  for (int i = 0; i < 4; i++) {
#pragma unroll
    for (int j = 0; j < 4; j++) {
      int col = n0 + wn * 64 + j * 16 + l15;
      float bv = bias[col];
#pragma unroll
      for (int r = 0; r < 4; r++) {
        int row = m0 + wm * 64 + i * 16 + l4 * 4 + r;
        float x = acc[i][j][r] + bv;
        if (ACT == 1) x = fmaxf(x, 0.f);
        if (ACT == 2) x = tanhf(x);
        if (ACT == 3) x = 1.f / (1.f + expf(-x));
        if (OUTBF) Cb[(size_t)row * N + col] = f2bf(x);
        else       Cf[(size_t)row * N + col] = x;
      }
    }
  }
}

// ============ MFMA flash attention: qkv bf16 [4096][1536] -> O bf16 [4096][512] ============
// block = (qt 64 rows, head). 4 waves; wave w owns q-rows w*16..w*16+15.
__global__ __launch_bounds__(256) void attn_mfma(
    const unsigned short* __restrict__ qkv, unsigned short* __restrict__ O)
{
  __shared__ __align__(16) unsigned short Ks[64 * 64];   // [krow][d]  swizzled
  __shared__ __align__(16) unsigned short VTs[64 * 64];  // [d][krow]  swizzled
  __shared__ __align__(16) unsigned short Ps[64 * 64];   // [qrow][k]  swizzled
  const int tid = threadIdx.x;
  const int w = tid >> 6, lane = tid & 63;
  const int l15 = lane & 15, l4 = lane >> 4;
  const int h = blockIdx.y, qt = blockIdx.x;

  bf16x8 qf[2];
#pragma unroll
  for (int kc = 0; kc < 2; kc++)
    qf[kc] = *(const bf16x8*)&qkv[(size_t)(qt * 64 + w * 16 + l15) * 1536 + h * 64 + kc * 32 + l4 * 8];

  f32x4 oacc[4] = {};
  float mrow[4], lrow[4];
#pragma unroll
  for (int r = 0; r < 4; r++) { mrow[r] = -1e30f; lrow[r] = 0.f; }

  const int sr = tid >> 3;          // K staging row 0..31 (+32)
  const int sc = (tid & 7) * 8;
  const int vk = tid & 63;          // V staging: k index
  const int vd0 = (tid >> 6) * 8;   // d base (+32 second round)

  for (int kt = 0; kt < 64; kt++) {
    const unsigned short* kb = qkv + (size_t)(kt * 64) * 1536 + 512 + h * 64;
    const unsigned short* vb = qkv + (size_t)(kt * 64) * 1536 + 1024 + h * 64;
    bf16x8 rk0 = *(const bf16x8*)&kb[(size_t)sr * 1536 + sc];
    bf16x8 rk1 = *(const bf16x8*)&kb[(size_t)(sr + 32) * 1536 + sc];
    bf16x8 rv0 = *(const bf16x8*)&vb[(size_t)vk * 1536 + vd0];
    bf16x8 rv1 = *(const bf16x8*)&vb[(size_t)vk * 1536 + vd0 + 32];
    __syncthreads();   // previous tile fully consumed
    {
      int b0 = sr * 128 + sc * 2;
      *(bf16x8*)((char*)Ks + swz(b0)) = rk0;
      int b1 = (sr + 32) * 128 + sc * 2;
      *(bf16x8*)((char*)Ks + swz(b1)) = rk1;
      union { bf16x8 v; unsigned short u[8]; } c0, c1;
      c0.v = rv0; c1.v = rv1;
#pragma unroll
      for (int j = 0; j < 8; j++) {
        int bb0 = (vd0 + j) * 128 + vk * 2;
        *(unsigned short*)((char*)VTs + swz(bb0)) = c0.u[j];
        int bb1 = (vd0 + 32 + j) * 128 + vk * 2;
        *(unsigned short*)((char*)VTs + swz(bb1)) = c1.u[j];
      }
    }
    __syncthreads();

    // S = Q K^T : D[m=q][n=krow]
    f32x4 sacc[4] = {};
#pragma unroll
    for (int kc = 0; kc < 2; kc++) {
#pragma unroll
      for (int nb = 0; nb < 4; nb++) {
        int byte = (nb * 16 + l15) * 128 + kc * 64 + l4 * 16;
        bf16x8 kf = *(const bf16x8*)((const char*)Ks + swz(byte));
        sacc[nb] = __builtin_amdgcn_mfma_f32_16x16x32_bf16(qf[kc], kf, sacc[nb], 0, 0, 0);
      }
    }
    // online softmax over the 64 k-cols (cols live across 16-lane group + 4 nb)
    float p[4][4];
#pragma unroll
    for (int r = 0; r < 4; r++) {
      float s0 = sacc[0][r] * 0.125f, s1 = sacc[1][r] * 0.125f;
      float s2 = sacc[2][r] * 0.125f, s3 = sacc[3][r] * 0.125f;
      float tm = fmaxf(fmaxf(s0, s1), fmaxf(s2, s3));
      tm = fmaxf(tm, __shfl_xor(tm, 1));
      tm = fmaxf(tm, __shfl_xor(tm, 2));
      tm = fmaxf(tm, __shfl_xor(tm, 4));
      tm = fmaxf(tm, __shfl_xor(tm, 8));
      float mn = fmaxf(mrow[r], tm);
      float alpha = __expf(mrow[r] - mn);
      float e0 = __expf(s0 - mn), e1 = __expf(s1 - mn);
      float e2 = __expf(s2 - mn), e3 = __expf(s3 - mn);
      float ps = e0 + e1 + e2 + e3;
      ps += __shfl_xor(ps, 1);
      ps += __shfl_xor(ps, 2);
      ps += __shfl_xor(ps, 4);
      ps += __shfl_xor(ps, 8);
      lrow[r] = lrow[r] * alpha + ps;
      mrow[r] = mn;
      p[0][r] = e0; p[1][r] = e1; p[2][r] = e2; p[3][r] = e3;
#pragma unroll
      for (int nb = 0; nb < 4; nb++) oacc[nb][r] = oacc[nb][r] * alpha;
    }
    // P -> LDS (bf16); wave writes and reads only its own 16 rows (no barrier)
#pragma unroll
    for (int nb = 0; nb < 4; nb++)
#pragma unroll
      for (int r = 0; r < 4; r++) {
        int byte = (w * 16 + l4 * 4 + r) * 128 + (nb * 16 + l15) * 2;
        *(unsigned short*)((char*)Ps + swz(byte)) = f2bf(p[nb][r]);
      }
    // O += P V : D[m=q][n=d]
#pragma unroll
    for (int kc = 0; kc < 2; kc++) {
      int bytea = (w * 16 + l15) * 128 + kc * 64 + l4 * 16;
      bf16x8 pa = *(const bf16x8*)((const char*)Ps + swz(bytea));
#pragma unroll
      for (int nb = 0; nb < 4; nb++) {
        int byteb = (nb * 16 + l15) * 128 + kc * 64 + l4 * 16;
        bf16x8 vf = *(const bf16x8*)((const char*)VTs + swz(byteb));
        oacc[nb] = __builtin_amdgcn_mfma_f32_16x16x32_bf16(pa, vf, oacc[nb], 0, 0, 0);
      }
    }
  }
#pragma unroll
  for (int nb = 0; nb < 4; nb++)
#pragma unroll
    for (int r = 0; r < 4; r++) {
      float inv = 1.f / lrow[r];
      int row = qt * 64 + w * 16 + l4 * 4 + r;
      int col = h * 64 + nb * 16 + l15;
      O[(size_t)row * 512 + col] = f2bf(oacc[nb][r] * inv);
    }
}

// ---------------- fp32 GEMM (kept for tiny stage-2 gating) ----------------
template<int ACT>
__global__ __launch_bounds__(256) void gemm_bias(
    const float* __restrict__ A, const float* __restrict__ B,
    const float* __restrict__ bias, float* __restrict__ C,
    int M, int N, int K)
{
  __shared__ float As[16][68];
  __shared__ float Bs[16][68];
  const int tid = threadIdx.x;
  const int tx = tid & 15, ty = tid >> 4;
  const int m0 = blockIdx.y * 64, n0 = blockIdx.x * 64;
  const int lr = tid >> 2;
  const int lk = (tid & 3) * 4;
  float acc[4][4] = {};
  for (int k0 = 0; k0 < K; k0 += 16) {
    __syncthreads();
    float4 av = *(const float4*)&A[(size_t)(m0 + lr) * K + k0 + lk];
    float4 bv = *(const float4*)&B[(size_t)(n0 + lr) * K + k0 + lk];
    As[lk + 0][lr] = av.x; As[lk + 1][lr] = av.y; As[lk + 2][lr] = av.z; As[lk + 3][lr] = av.w;
    Bs[lk + 0][lr] = bv.x; Bs[lk + 1][lr] = bv.y; Bs[lk + 2][lr] = bv.z; Bs[lk + 3][lr] = bv.w;
    __syncthreads();
#pragma unroll
    for (int k = 0; k < 16; k++) {
      float a[4], b[4];
#pragma unroll
      for (int i = 0; i < 4; i++) a[i] = As[k][ty * 4 + i];
#pragma unroll
      for (int j = 0; j < 4; j++) b[j] = Bs[k][tx * 4 + j];
#pragma unroll
      for (int i = 0; i < 4; i++)
#pragma unroll
        for (int j = 0; j < 4; j++)
          acc[i][j] = fmaf(a[i], b[j], acc[i][j]);
    }
  }
#pragma unroll
  for (int i = 0; i < 4; i++)
#pragma unroll
    for (int j = 0; j < 4; j++) {
      float x = acc[i][j] + bias[n0 + tx * 4 + j];
      if (ACT == 1) x = fmaxf(x, 0.f);
      if (ACT == 2) x = tanhf(x);
      if (ACT == 3) x = 1.f / (1.f + expf(-x));
      C[(size_t)(m0 + ty * 4 + i) * N + n0 + tx * 4 + j] = x;
    }
}

// ---------------- LayerNorm(x + res), writes f32 + bf16 ----------------
__global__ __launch_bounds__(64) void residual_ln(
    const float* __restrict__ x, const float* __restrict__ res,
    const float* __restrict__ g, const float* __restrict__ b,
    float* __restrict__ out, unsigned short* __restrict__ out_bf)
{
  const int row = blockIdx.x, lane = threadIdx.x;
  const float* xp = x + (size_t)row * 512;
  const float* rp = res + (size_t)row * 512;
  float v[8];
  float s = 0.f;
#pragma unroll
  for (int i = 0; i < 8; i++) { v[i] = xp[lane + 64 * i] + rp[lane + 64 * i]; s += v[i]; }
  s = wave_sum64(s);
  float mu = s * (1.f / 512.f);
  float vs = 0.f;
#pragma unroll
  for (int i = 0; i < 8; i++) { float d = v[i] - mu; vs = fmaf(d, d, vs); }
  vs = wave_sum64(vs);
  float rstd = rsqrtf(vs * (1.f / 512.f) + 1e-5f);
  float* op = out + (size_t)row * 512;
  unsigned short* ob = out_bf + (size_t)row * 512;
#pragma unroll
  for (int i = 0; i < 8; i++) {
    float y = (v[i] - mu) * rstd * g[lane + 64 * i] + b[lane + 64 * i];
    op[lane + 64 * i] = y;
    ob[lane + 64 * i] = f2bf(y);
  }
}

// ---------------- casts ----------------
__global__ void cast_bf16(const float* __restrict__ in, unsigned short* __restrict__ out, int n4)
{
  int i = blockIdx.x * 256 + threadIdx.x;
  if (i < n4) {
    float4 v = ((const float4*)in)[i];
    ushort4 u;
    u.x = f2bf(v.x); u.y = f2bf(v.y); u.z = f2bf(v.z); u.w = f2bf(v.w);
    ((ushort4*)out)[i] = u;
  }
}

__global__ void init_h(const float* __restrict__ in, float* __restrict__ hf,
                       unsigned short* __restrict__ hb, int n4)
{
  int i = blockIdx.x * 256 + threadIdx.x;
  if (i < n4) {
    float4 v = ((const float4*)in)[i];
    ((float4*)hf)[i] = v;
    ushort4 u;
    u.x = f2bf(v.x); u.y = f2bf(v.y); u.z = f2bf(v.z); u.w = f2bf(v.w);
    ((ushort4*)hb)[i] = u;
  }
}

// ---------------- A[t] = sum_l Gv*Gu*Ww + bw ----------------
__global__ __launch_bounds__(128) void gate_dot(
    const float* __restrict__ Gv, const float* __restrict__ Gu,
    const float* __restrict__ Ww, const float* __restrict__ bw,
    float* __restrict__ A)
{
  const int t = blockIdx.x, l = threadIdx.x;
  float v = Gv[(size_t)t * 128 + l] * Gu[(size_t)t * 128 + l] * Ww[l];
  v = wave_sum64(v);
  __shared__ float red[2];
  if ((l & 63) == 0) red[l >> 6] = v;
  __syncthreads();
  if (l == 0) A[t] = red[0] + red[1] + bw[0];
}

// ------- contiguous-segment softmax + weighted pooled sum (D=512) -------
__global__ __launch_bounds__(256) void seg_pool(
    const float* __restrict__ A, const float* __restrict__ X,
    float* __restrict__ w_out, float* __restrict__ out, int seg_len)
{
  const int s = blockIdx.x, tid = threadIdx.x;
  __shared__ float ws[16];
  if (tid < 64) {
    float a = (tid < seg_len) ? A[s * seg_len + tid] : -1e30f;
    float mx = a;
#pragma unroll
    for (int o = 1; o < 16; o <<= 1) mx = fmaxf(mx, __shfl_xor(mx, o));
    float e = (tid < seg_len) ? expf(a - mx) : 0.f;
    float se = e;
#pragma unroll
    for (int o = 1; o < 16; o <<= 1) se += __shfl_xor(se, o);
    if (tid < seg_len) {
      float w = e / se;
      ws[tid] = w;
      w_out[s * seg_len + tid] = w;
    }
  }
  __syncthreads();
  for (int d = tid; d < 512; d += 256) {
    float acc = 0.f;
    for (int i = 0; i < seg_len; i++)
      acc = fmaf(ws[i], X[(size_t)(s * seg_len + i) * 512 + d], acc);
    out[(size_t)s * 512 + d] = acc;
  }
}

// ---------------- CNN head ----------------
__global__ void conv1_bn_relu(
    const float* __restrict__ x, const float* __restrict__ K,
    const float* __restrict__ bias, const float* __restrict__ g,
    const float* __restrict__ bb, float* __restrict__ y)
{
  int idx = blockIdx.x * 256 + threadIdx.x;
  int i = idx & 511, o = (idx >> 9) & 127, n = idx >> 16;
  const float* xp = x + n * 512;
  float acc = bias[o];
#pragma unroll
  for (int k = 0; k < 4; k++) {
    int p = i + k - 1;
    float xv = (p >= 0 && p < 512) ? xp[p] : 0.f;
    acc = fmaf(xv, K[o * 4 + k], acc);
  }
  float sc = g[o] * rsqrtf(1.f + 1e-5f);
  y[idx] = fmaxf(fmaf(acc, sc, bb[o]), 0.f);
}

template<int KS, int PAD, int LEN>
__global__ void convK_bn_relu(
    const float* __restrict__ x, const float* __restrict__ K,
    const float* __restrict__ bias, const float* __restrict__ g,
    const float* __restrict__ bb, float* __restrict__ y)
{
  int idx = blockIdx.x * 256 + threadIdx.x;
  int i = idx % LEN;
  int o = (idx / LEN) & 127;
  int n = idx / (LEN * 128);
  const float* xn = x + (size_t)n * 128 * LEN;
  const float* kw = K + (size_t)o * 128 * KS;
  float acc = bias[o];
  for (int c = 0; c < 128; c++) {
    const float* xc = xn + c * LEN;
#pragma unroll
    for (int k = 0; k < KS; k++) {
      int p = i + k - PAD;
      float xv = (p >= 0 && p < LEN) ? xc[p] : 0.f;
      acc = fmaf(xv, kw[c * KS + k], acc);
    }
  }
  float sc = g[o] * rsqrtf(1.f + 1e-5f);
  y[idx] = fmaxf(fmaf(acc, sc, bb[o]), 0.f);
}

__global__ void avgpool2(const float* __restrict__ x, float* __restrict__ y, int n_out)
{
  int idx = blockIdx.x * 256 + threadIdx.x;
  if (idx < n_out) y[idx] = 0.5f * (x[2 * idx] + x[2 * idx + 1]);
}

__global__ __launch_bounds__(256) void fc1_kernel(
    const float* __restrict__ x, const float* __restrict__ W,
    const float* __restrict__ bias, const float* __restrict__ g,
    const float* __restrict__ bb, float* __restrict__ y)
{
  int o = blockIdx.x & 255, n = blockIdx.x >> 8;
  const float* xp = x + (size_t)n * 16384;
  const float* wp = W + (size_t)o * 16384;
  float s = 0.f;
  for (int j = threadIdx.x * 4; j < 16384; j += 1024) {
    float4 a = *(const float4*)(xp + j);
    float4 b = *(const float4*)(wp + j);
    s = fmaf(a.x, b.x, s); s = fmaf(a.y, b.y, s);
    s = fmaf(a.z, b.z, s); s = fmaf(a.w, b.w, s);
  }
  s = wave_sum64(s);
  __shared__ float red[4];
  if ((threadIdx.x & 63) == 0) red[threadIdx.x >> 6] = s;
  __syncthreads();
  if (threadIdx.x == 0) {
    float v = red[0] + red[1] + red[2] + red[3] + bias[o];
    v = fmaxf(v, 0.f);
    y[n * 256 + o] = fmaf(v, g[o] * rsqrtf(1.f + 1e-5f), bb[o]);
  }
}

__global__ __launch_bounds__(256) void fc2_kernel(
    const float* __restrict__ x, const float* __restrict__ W,
    const float* __restrict__ bias, const float* __restrict__ g,
    const float* __restrict__ bb, float* __restrict__ y)
{
  int o = blockIdx.x & 127, n = blockIdx.x >> 7;
  float s = x[n * 256 + threadIdx.x] * W[o * 256 + threadIdx.x];
  s = wave_sum64(s);
  __shared__ float red[4];
  if ((threadIdx.x & 63) == 0) red[threadIdx.x >> 6] = s;
  __syncthreads();
  if (threadIdx.x == 0) {
    float v = red[0] + red[1] + red[2] + red[3] + bias[o];
    v = fmaxf(v, 0.f);
    y[n * 128 + o] = fmaf(v, g[o] * rsqrtf(1.f + 1e-5f), bb[o]);
  }
}

__global__ __launch_bounds__(64) void fc3_kernel(
    const float* __restrict__ x, const float* __restrict__ W,
    const float* __restrict__ bias, float* __restrict__ out)
{
  int n = threadIdx.x;
  if (n < 32) {
    float s = bias[0];
    for (int k = 0; k < 128; k++) s = fmaf(x[n * 128 + k], W[k], s);
    float p = 1.f / (1.f + expf(-s));
    out[n] = p;
    out[32 + n] = (p >= 0.5f) ? 1.f : 0.f;
  }
}

extern "C" void kernel_launch(void* const* d_in, const int* in_sizes, int n_in,
                              void* d_out, int out_size, void* d_ws, size_t ws_size,
                              hipStream_t stream)
{
  const float* datas = (const float*)d_in[0];
  const float* Wqkv = (const float*)d_in[6];
  const float* bqkv = (const float*)d_in[7];
  const float* Wo   = (const float*)d_in[8];
  const float* bo   = (const float*)d_in[9];
  const float* ln1g = (const float*)d_in[10];
  const float* ln1b = (const float*)d_in[11];
  const float* W1   = (const float*)d_in[12];
  const float* b1   = (const float*)d_in[13];
  const float* W2   = (const float*)d_in[14];
  const float* b2   = (const float*)d_in[15];
  const float* ln2g = (const float*)d_in[16];
  const float* ln2b = (const float*)d_in[17];
  const float* Wv1  = (const float*)d_in[18];
  const float* bv1  = (const float*)d_in[19];
  const float* Wu1  = (const float*)d_in[20];
  const float* bu1  = (const float*)d_in[21];
  const float* Ww1  = (const float*)d_in[22];
  const float* bw1  = (const float*)d_in[23];
  const float* Wv2  = (const float*)d_in[24];
  const float* bv2  = (const float*)d_in[25];
  const float* Wu2  = (const float*)d_in[26];
  const float* bu2  = (const float*)d_in[27];
  const float* Ww2  = (const float*)d_in[28];
  const float* bw2  = (const float*)d_in[29];
  const float* Kc1  = (const float*)d_in[30];
  const float* bc1  = (const float*)d_in[31];
  const float* gc1  = (const float*)d_in[32];
  const float* bb1  = (const float*)d_in[33];
  const float* Kc2  = (const float*)d_in[34];
  const float* bc2  = (const float*)d_in[35];
  const float* gc2  = (const float*)d_in[36];
  const float* bb2  = (const float*)d_in[37];
  const float* Kc3  = (const float*)d_in[38];
  const float* bc3  = (const float*)d_in[39];
  const float* gc3  = (const float*)d_in[40];
  const float* bb3  = (const float*)d_in[41];
  const float* Wf1  = (const float*)d_in[42];
  const float* bf1  = (const float*)d_in[43];
  const float* g4   = (const float*)d_in[44];
  const float* b4   = (const float*)d_in[45];
  const float* Wf2  = (const float*)d_in[46];
  const float* bf2  = (const float*)d_in[47];
  const float* g5   = (const float*)d_in[48];
  const float* b5   = (const float*)d_in[49];
  const float* Wf3  = (const float*)d_in[50];
  const float* bf3  = (const float*)d_in[51];

  float* ws = (float*)d_ws;
  // layout (floats): h_f32[2.10M] | R2[6.29M] | h_bf16(as 1.05M f) | wbuf(1.57M f)
  float* h_f32 = ws;                              // 2,097,152
  float* R2f   = ws + 2097152;                    // 6,291,456
  unsigned short* h_bf = (unsigned short*)(ws + 8388608);   // 2,097,152 ush
  unsigned short* wbuf = (unsigned short*)(ws + 9437184);   // 3,145,728 ush

  // R2 overlays
  unsigned short* qkv_bf = (unsigned short*)R2f;            // 6,291,456 ush
  unsigned short* O_bf   = (unsigned short*)(R2f + 3145728);// 2,097,152 ush
  unsigned short* ff1_bf = (unsigned short*)R2f;            // 8,388,608 ush
  float* projf = R2f + 4194304;                             // 2,097,152 f

  // per-layer weight slots in wbuf (ush offsets)
  unsigned short* WqkvB = wbuf;            // 786,432
  unsigned short* WoB   = wbuf + 786432;   // 262,144
  unsigned short* W1B   = wbuf + 1048576;  // 1,048,576
  unsigned short* W2B   = wbuf + 2097152;  // 1,048,576
  unsigned short* Wv1B  = wbuf;            // 65,536 (after layers)
  unsigned short* Wu1B  = wbuf + 65536;

  float* out_f = (float*)d_out;

  init_h<<<2048, 256, 0, stream>>>(datas, h_f32, h_bf, 524288);

  for (int l = 0; l < 2; l++) {
    cast_bf16<<<768, 256, 0, stream>>>(Wqkv + (size_t)l * 786432, WqkvB, 196608);
    cast_bf16<<<256, 256, 0, stream>>>(Wo + (size_t)l * 262144, WoB, 65536);
    cast_bf16<<<1024, 256, 0, stream>>>(W1 + (size_t)l * 1048576, W1B, 262144);
    cast_bf16<<<1024, 256, 0, stream>>>(W2 + (size_t)l * 1048576, W2B, 262144);

    // qkv (4096,1536)
    mgemm<0, 1><<<dim3(12, 32), 256, 0, stream>>>(
        h_bf, WqkvB, bqkv + (size_t)l * 1536, nullptr, qkv_bf, 4096, 1536, 512);
    // attention -> O_bf
    attn_mfma<<<dim3(64, 8), 256, 0, stream>>>(qkv_bf, O_bf);
    // proj -> projf (f32)
    mgemm<0, 0><<<dim3(4, 32), 256, 0, stream>>>(
        O_bf, WoB, bo + (size_t)l * 512, projf, nullptr, 4096, 512, 512);
    residual_ln<<<4096, 64, 0, stream>>>(projf, h_f32, ln1g + l * 512, ln1b + l * 512,
                                         h_f32, h_bf);
    // ff1 relu -> bf16
    mgemm<1, 1><<<dim3(16, 32), 256, 0, stream>>>(
        h_bf, W1B, b1 + (size_t)l * 2048, nullptr, ff1_bf, 4096, 2048, 512);
    // ff2 -> projf
    mgemm<0, 0><<<dim3(4, 32), 256, 0, stream>>>(
        ff1_bf, W2B, b2 + (size_t)l * 512, projf, nullptr, 4096, 512, 2048);
    residual_ln<<<4096, 64, 0, stream>>>(projf, h_f32, ln2g + l * 512, ln2b + l * 512,
                                         h_f32, h_bf);
  }

  // ---- gated pooling stage 1 ----
  float* Gv   = R2f;
  float* Gu   = R2f + 524288;
  float* A1   = R2f + 1048576;
  float* out1 = R2f + 1052672;
  float* Gv2  = R2f + 1183744;
  float* Gu2  = R2f + 1216512;
  float* A2   = R2f + 1249280;
  float* out2 = R2f + 1249536;

  cast_bf16<<<64, 256, 0, stream>>>(Wv1, Wv1B, 16384);
  cast_bf16<<<64, 256, 0, stream>>>(Wu1, Wu1B, 16384);
  mgemm<2, 0><<<dim3(1, 32), 256, 0, stream>>>(h_bf, Wv1B, bv1, Gv, nullptr, 4096, 128, 512);
  mgemm<3, 0><<<dim3(1, 32), 256, 0, stream>>>(h_bf, Wu1B, bu1, Gu, nullptr, 4096, 128, 512);
  gate_dot<<<4096, 128, 0, stream>>>(Gv, Gu, Ww1, bw1, A1);
  seg_pool<<<256, 256, 0, stream>>>(A1, h_f32, out_f + 64, out1, 16);

  // ---- stage 2 (fp32, tiny) ----
  gemm_bias<2><<<dim3(2, 4), 256, 0, stream>>>(out1, Wv2, bv2, Gv2, 256, 128, 512);
  gemm_bias<3><<<dim3(2, 4), 256, 0, stream>>>(out1, Wu2, bu2, Gu2, 256, 128, 512);
  gate_dot<<<256, 128, 0, stream>>>(Gv2, Gu2, Ww2, bw2, A2);
  seg_pool<<<32, 256, 0, stream>>>(A2, out1, out_f + 4160, out2, 8);

  // ---- CNN head (R2 overlays; all sources dead by first use) ----
  float* c1 = R2f + 1310720;   // 2,097,152
  float* c2 = R2f + 3407872;   // 2,097,152
  float* p2 = R2f;             // 1,048,576
  float* c3 = R2f + 3407872;   // 1,048,576 (c2 dead)
  float* p3 = R2f;             // 524,288  (p2 dead)
  float* f1 = R2f + 524288;    // 8,192
  float* f2 = R2f + 532480;    // 4,096

  conv1_bn_relu<<<8192, 256, 0, stream>>>(out2, Kc1, bc1, gc1, bb1, c1);
  convK_bn_relu<5, 2, 512><<<8192, 256, 0, stream>>>(c1, Kc2, bc2, gc2, bb2, c2);
  avgpool2<<<4096, 256, 0, stream>>>(c2, p2, 1048576);
  convK_bn_relu<7, 3, 256><<<4096, 256, 0, stream>>>(p2, Kc3, bc3, gc3, bb3, c3);
  avgpool2<<<2048, 256, 0, stream>>>(c3, p3, 524288);
  fc1_kernel<<<8192, 256, 0, stream>>>(p3, Wf1, bf1, g4, b4, f1);
  fc2_kernel<<<4096, 256, 0, stream>>>(f1, Wf2, bf2, g5, b5, f2);
  fc3_kernel<<<1, 64, 0, stream>>>(f2, Wf3, bf3, out_f);
}

// Round 3
// 761.754 us; speedup vs baseline: 5.2497x; 1.5769x over previous
//
#include <hip/hip_runtime.h>
#include <math.h>

// T=4096, M=512, NH=8, HD=64, FF=2048, NL=2, NI=256 (16 tok/seg), NO=32 (8 seg/outer)

typedef float f32x4 __attribute__((ext_vector_type(4)));
typedef __bf16 bf16x8 __attribute__((ext_vector_type(8)));

__device__ __forceinline__ unsigned short f2bf(float x) {
  unsigned int u = __builtin_bit_cast(unsigned int, x);
  u += 0x7FFFu + ((u >> 16) & 1u);
  return (unsigned short)(u >> 16);
}
__device__ __forceinline__ float bf2f(unsigned short u) {
  unsigned int x = ((unsigned int)u) << 16;
  return __builtin_bit_cast(float, x);
}

__device__ __forceinline__ float wave_sum64(float v) {
#pragma unroll
  for (int o = 32; o > 0; o >>= 1) v += __shfl_xor(v, o);
  return v;
}

// XOR swizzle for LDS tiles with 128-byte rows (64 bf16/row).
__device__ __forceinline__ int swz(int byte) {
  return byte ^ (((byte >> 7) & 7) << 4);
}
// XOR swizzle for LDS tiles with 256-byte rows (128 bf16/row).
__device__ __forceinline__ int swz256(int byte) {
  return byte ^ (((byte >> 8) & 7) << 4);
}

// ============ bf16 MFMA GEMM: C[M,N] = act(A[M,K] @ B[N,K]^T + bias) ============
template<int ACT, int OUTBF>
__global__ __launch_bounds__(256) void mgemm(
    const unsigned short* __restrict__ A, const unsigned short* __restrict__ B,
    const float* __restrict__ bias, float* __restrict__ Cf,
    unsigned short* __restrict__ Cb, int M, int N, int K)
{
  __shared__ __align__(16) unsigned short As[128 * 64];
  __shared__ __align__(16) unsigned short Bs[128 * 64];
  const int tid = threadIdx.x;
  const int wid = tid >> 6, lane = tid & 63;
  const int wm = wid >> 1, wn = wid & 1;
  const int l15 = lane & 15, l4 = lane >> 4;
  const int m0 = blockIdx.y * 128, n0 = blockIdx.x * 128;
  const int srow = tid >> 3;
  const int scol = (tid & 7) * 8;

  f32x4 acc[4][4] = {};

  for (int k0 = 0; k0 < K; k0 += 64) {
    bf16x8 ra[4], rb[4];
#pragma unroll
    for (int i = 0; i < 4; i++) {
      ra[i] = *(const bf16x8*)&A[(size_t)(m0 + srow + i * 32) * K + k0 + scol];
      rb[i] = *(const bf16x8*)&B[(size_t)(n0 + srow + i * 32) * K + k0 + scol];
    }
    __syncthreads();
#pragma unroll
    for (int i = 0; i < 4; i++) {
      int byte = (srow + i * 32) * 128 + scol * 2;
      *(bf16x8*)((char*)As + swz(byte)) = ra[i];
      *(bf16x8*)((char*)Bs + swz(byte)) = rb[i];
    }
    __syncthreads();
#pragma unroll
    for (int kc = 0; kc < 2; kc++) {
      bf16x8 af[4], bf_[4];
#pragma unroll
      for (int i = 0; i < 4; i++) {
        int byteA = (wm * 64 + i * 16 + l15) * 128 + kc * 64 + l4 * 16;
        af[i] = *(const bf16x8*)((const char*)As + swz(byteA));
        int byteB = (wn * 64 + i * 16 + l15) * 128 + kc * 64 + l4 * 16;
        bf_[i] = *(const bf16x8*)((const char*)Bs + swz(byteB));
      }
#pragma unroll
      for (int i = 0; i < 4; i++)
#pragma unroll
        for (int j = 0; j < 4; j++)
          acc[i][j] = __builtin_amdgcn_mfma_f32_16x16x32_bf16(af[i], bf_[j], acc[i][j], 0, 0, 0);
    }
  }
#pragma unroll
  for (int i = 0; i < 4; i++) {
#pragma unroll
    for (int j = 0; j < 4; j++) {
      int col = n0 + wn * 64 + j * 16 + l15;
      float bv = bias[col];
#pragma unroll
      for (int r = 0; r < 4; r++) {
        int row = m0 + wm * 64 + i * 16 + l4 * 4 + r;
        float x = acc[i][j][r] + bv;
        if (ACT == 1) x = fmaxf(x, 0.f);
        if (ACT == 2) x = tanhf(x);
        if (ACT == 3) x = 1.f / (1.f + expf(-x));
        if (OUTBF) Cb[(size_t)row * N + col] = f2bf(x);
        else       Cf[(size_t)row * N + col] = x;
      }
    }
  }
}

// ============ MFMA flash attention ============
__global__ __launch_bounds__(256) void attn_mfma(
    const unsigned short* __restrict__ qkv, unsigned short* __restrict__ O)
{
  __shared__ __align__(16) unsigned short Ks[64 * 64];
  __shared__ __align__(16) unsigned short VTs[64 * 64];
  __shared__ __align__(16) unsigned short Ps[64 * 64];
  const int tid = threadIdx.x;
  const int w = tid >> 6, lane = tid & 63;
  const int l15 = lane & 15, l4 = lane >> 4;
  const int h = blockIdx.y, qt = blockIdx.x;

  bf16x8 qf[2];
#pragma unroll
  for (int kc = 0; kc < 2; kc++)
    qf[kc] = *(const bf16x8*)&qkv[(size_t)(qt * 64 + w * 16 + l15) * 1536 + h * 64 + kc * 32 + l4 * 8];

  f32x4 oacc[4] = {};
  float mrow[4], lrow[4];
#pragma unroll
  for (int r = 0; r < 4; r++) { mrow[r] = -1e30f; lrow[r] = 0.f; }

  const int sr = tid >> 3;
  const int sc = (tid & 7) * 8;
  const int vk = tid & 63;
  const int vd0 = (tid >> 6) * 8;

  for (int kt = 0; kt < 64; kt++) {
    const unsigned short* kb = qkv + (size_t)(kt * 64) * 1536 + 512 + h * 64;
    const unsigned short* vb = qkv + (size_t)(kt * 64) * 1536 + 1024 + h * 64;
    bf16x8 rk0 = *(const bf16x8*)&kb[(size_t)sr * 1536 + sc];
    bf16x8 rk1 = *(const bf16x8*)&kb[(size_t)(sr + 32) * 1536 + sc];
    bf16x8 rv0 = *(const bf16x8*)&vb[(size_t)vk * 1536 + vd0];
    bf16x8 rv1 = *(const bf16x8*)&vb[(size_t)vk * 1536 + vd0 + 32];
    __syncthreads();
    {
      int b0 = sr * 128 + sc * 2;
      *(bf16x8*)((char*)Ks + swz(b0)) = rk0;
      int b1 = (sr + 32) * 128 + sc * 2;
      *(bf16x8*)((char*)Ks + swz(b1)) = rk1;
      union { bf16x8 v; unsigned short u[8]; } c0, c1;
      c0.v = rv0; c1.v = rv1;
#pragma unroll
      for (int j = 0; j < 8; j++) {
        int bb0 = (vd0 + j) * 128 + vk * 2;
        *(unsigned short*)((char*)VTs + swz(bb0)) = c0.u[j];
        int bb1 = (vd0 + 32 + j) * 128 + vk * 2;
        *(unsigned short*)((char*)VTs + swz(bb1)) = c1.u[j];
      }
    }
    __syncthreads();

    f32x4 sacc[4] = {};
#pragma unroll
    for (int kc = 0; kc < 2; kc++) {
#pragma unroll
      for (int nb = 0; nb < 4; nb++) {
        int byte = (nb * 16 + l15) * 128 + kc * 64 + l4 * 16;
        bf16x8 kf = *(const bf16x8*)((const char*)Ks + swz(byte));
        sacc[nb] = __builtin_amdgcn_mfma_f32_16x16x32_bf16(qf[kc], kf, sacc[nb], 0, 0, 0);
      }
    }
    float p[4][4];
#pragma unroll
    for (int r = 0; r < 4; r++) {
      float s0 = sacc[0][r] * 0.125f, s1 = sacc[1][r] * 0.125f;
      float s2 = sacc[2][r] * 0.125f, s3 = sacc[3][r] * 0.125f;
      float tm = fmaxf(fmaxf(s0, s1), fmaxf(s2, s3));
      tm = fmaxf(tm, __shfl_xor(tm, 1));
      tm = fmaxf(tm, __shfl_xor(tm, 2));
      tm = fmaxf(tm, __shfl_xor(tm, 4));
      tm = fmaxf(tm, __shfl_xor(tm, 8));
      float mn = fmaxf(mrow[r], tm);
      float alpha = __expf(mrow[r] - mn);
      float e0 = __expf(s0 - mn), e1 = __expf(s1 - mn);
      float e2 = __expf(s2 - mn), e3 = __expf(s3 - mn);
      float ps = e0 + e1 + e2 + e3;
      ps += __shfl_xor(ps, 1);
      ps += __shfl_xor(ps, 2);
      ps += __shfl_xor(ps, 4);
      ps += __shfl_xor(ps, 8);
      lrow[r] = lrow[r] * alpha + ps;
      mrow[r] = mn;
      p[0][r] = e0; p[1][r] = e1; p[2][r] = e2; p[3][r] = e3;
#pragma unroll
      for (int nb = 0; nb < 4; nb++) oacc[nb][r] = oacc[nb][r] * alpha;
    }
#pragma unroll
    for (int nb = 0; nb < 4; nb++)
#pragma unroll
      for (int r = 0; r < 4; r++) {
        int byte = (w * 16 + l4 * 4 + r) * 128 + (nb * 16 + l15) * 2;
        *(unsigned short*)((char*)Ps + swz(byte)) = f2bf(p[nb][r]);
      }
#pragma unroll
    for (int kc = 0; kc < 2; kc++) {
      int bytea = (w * 16 + l15) * 128 + kc * 64 + l4 * 16;
      bf16x8 pa = *(const bf16x8*)((const char*)Ps + swz(bytea));
#pragma unroll
      for (int nb = 0; nb < 4; nb++) {
        int byteb = (nb * 16 + l15) * 128 + kc * 64 + l4 * 16;
        bf16x8 vf = *(const bf16x8*)((const char*)VTs + swz(byteb));
        oacc[nb] = __builtin_amdgcn_mfma_f32_16x16x32_bf16(pa, vf, oacc[nb], 0, 0, 0);
      }
    }
  }
#pragma unroll
  for (int nb = 0; nb < 4; nb++)
#pragma unroll
    for (int r = 0; r < 4; r++) {
      float inv = 1.f / lrow[r];
      int row = qt * 64 + w * 16 + l4 * 4 + r;
      int col = h * 64 + nb * 16 + l15;
      O[(size_t)row * 512 + col] = f2bf(oacc[nb][r] * inv);
    }
}

// ---------------- fp32 GEMM (tiny stage-2 gating) ----------------
template<int ACT>
__global__ __launch_bounds__(256) void gemm_bias(
    const float* __restrict__ A, const float* __restrict__ B,
    const float* __restrict__ bias, float* __restrict__ C,
    int M, int N, int K)
{
  __shared__ float As[16][68];
  __shared__ float Bs[16][68];
  const int tid = threadIdx.x;
  const int tx = tid & 15, ty = tid >> 4;
  const int m0 = blockIdx.y * 64, n0 = blockIdx.x * 64;
  const int lr = tid >> 2;
  const int lk = (tid & 3) * 4;
  float acc[4][4] = {};
  for (int k0 = 0; k0 < K; k0 += 16) {
    __syncthreads();
    float4 av = *(const float4*)&A[(size_t)(m0 + lr) * K + k0 + lk];
    float4 bv = *(const float4*)&B[(size_t)(n0 + lr) * K + k0 + lk];
    As[lk + 0][lr] = av.x; As[lk + 1][lr] = av.y; As[lk + 2][lr] = av.z; As[lk + 3][lr] = av.w;
    Bs[lk + 0][lr] = bv.x; Bs[lk + 1][lr] = bv.y; Bs[lk + 2][lr] = bv.z; Bs[lk + 3][lr] = bv.w;
    __syncthreads();
#pragma unroll
    for (int k = 0; k < 16; k++) {
      float a[4], b[4];
#pragma unroll
      for (int i = 0; i < 4; i++) a[i] = As[k][ty * 4 + i];
#pragma unroll
      for (int j = 0; j < 4; j++) b[j] = Bs[k][tx * 4 + j];
#pragma unroll
      for (int i = 0; i < 4; i++)
#pragma unroll
        for (int j = 0; j < 4; j++)
          acc[i][j] = fmaf(a[i], b[j], acc[i][j]);
    }
  }
#pragma unroll
  for (int i = 0; i < 4; i++)
#pragma unroll
    for (int j = 0; j < 4; j++) {
      float x = acc[i][j] + bias[n0 + tx * 4 + j];
      if (ACT == 1) x = fmaxf(x, 0.f);
      if (ACT == 2) x = tanhf(x);
      if (ACT == 3) x = 1.f / (1.f + expf(-x));
      C[(size_t)(m0 + ty * 4 + i) * N + n0 + tx * 4 + j] = x;
    }
}

// ---------------- LayerNorm(x + res), writes f32 + bf16 ----------------
__global__ __launch_bounds__(64) void residual_ln(
    const float* __restrict__ x, const float* __restrict__ res,
    const float* __restrict__ g, const float* __restrict__ b,
    float* __restrict__ out, unsigned short* __restrict__ out_bf)
{
  const int row = blockIdx.x, lane = threadIdx.x;
  const float* xp = x + (size_t)row * 512;
  const float* rp = res + (size_t)row * 512;
  float v[8];
  float s = 0.f;
#pragma unroll
  for (int i = 0; i < 8; i++) { v[i] = xp[lane + 64 * i] + rp[lane + 64 * i]; s += v[i]; }
  s = wave_sum64(s);
  float mu = s * (1.f / 512.f);
  float vs = 0.f;
#pragma unroll
  for (int i = 0; i < 8; i++) { float d = v[i] - mu; vs = fmaf(d, d, vs); }
  vs = wave_sum64(vs);
  float rstd = rsqrtf(vs * (1.f / 512.f) + 1e-5f);
  float* op = out + (size_t)row * 512;
  unsigned short* ob = out_bf + (size_t)row * 512;
#pragma unroll
  for (int i = 0; i < 8; i++) {
    float y = (v[i] - mu) * rstd * g[lane + 64 * i] + b[lane + 64 * i];
    op[lane + 64 * i] = y;
    ob[lane + 64 * i] = f2bf(y);
  }
}

// ---------------- casts ----------------
__global__ void cast_bf16(const float* __restrict__ in, unsigned short* __restrict__ out, int n4)
{
  int i = blockIdx.x * 256 + threadIdx.x;
  if (i < n4) {
    float4 v = ((const float4*)in)[i];
    ushort4 u;
    u.x = f2bf(v.x); u.y = f2bf(v.y); u.z = f2bf(v.z); u.w = f2bf(v.w);
    ((ushort4*)out)[i] = u;
  }
}

__global__ void init_h(const float* __restrict__ in, float* __restrict__ hf,
                       unsigned short* __restrict__ hb, int n4)
{
  int i = blockIdx.x * 256 + threadIdx.x;
  if (i < n4) {
    float4 v = ((const float4*)in)[i];
    ((float4*)hf)[i] = v;
    ushort4 u;
    u.x = f2bf(v.x); u.y = f2bf(v.y); u.z = f2bf(v.z); u.w = f2bf(v.w);
    ((ushort4*)hb)[i] = u;
  }
}

// ---------------- A[t] = sum_l Gv*Gu*Ww + bw ----------------
__global__ __launch_bounds__(128) void gate_dot(
    const float* __restrict__ Gv, const float* __restrict__ Gu,
    const float* __restrict__ Ww, const float* __restrict__ bw,
    float* __restrict__ A)
{
  const int t = blockIdx.x, l = threadIdx.x;
  float v = Gv[(size_t)t * 128 + l] * Gu[(size_t)t * 128 + l] * Ww[l];
  v = wave_sum64(v);
  __shared__ float red[2];
  if ((l & 63) == 0) red[l >> 6] = v;
  __syncthreads();
  if (l == 0) A[t] = red[0] + red[1] + bw[0];
}

// ------- contiguous-segment softmax + weighted pooled sum (D=512) -------
__global__ __launch_bounds__(256) void seg_pool(
    const float* __restrict__ A, const float* __restrict__ X,
    float* __restrict__ w_out, float* __restrict__ out, int seg_len)
{
  const int s = blockIdx.x, tid = threadIdx.x;
  __shared__ float ws[16];
  if (tid < 64) {
    float a = (tid < seg_len) ? A[s * seg_len + tid] : -1e30f;
    float mx = a;
#pragma unroll
    for (int o = 1; o < 16; o <<= 1) mx = fmaxf(mx, __shfl_xor(mx, o));
    float e = (tid < seg_len) ? expf(a - mx) : 0.f;
    float se = e;
#pragma unroll
    for (int o = 1; o < 16; o <<= 1) se += __shfl_xor(se, o);
    if (tid < seg_len) {
      float w = e / se;
      ws[tid] = w;
      w_out[s * seg_len + tid] = w;
    }
  }
  __syncthreads();
  for (int d = tid; d < 512; d += 256) {
    float acc = 0.f;
    for (int i = 0; i < seg_len; i++)
      acc = fmaf(ws[i], X[(size_t)(s * seg_len + i) * 512 + d], acc);
    out[(size_t)s * 512 + d] = acc;
  }
}

// ======================= CNN head (channels-last [n][L][C=128]) =======================

// conv1: out2 (32,512) f32 -> c1T (32,512,128) bf16. K=4, pad left 1.
__global__ void conv1_bnT(
    const float* __restrict__ x, const float* __restrict__ K4,
    const float* __restrict__ bias, const float* __restrict__ g,
    const float* __restrict__ bb, unsigned short* __restrict__ y)
{
  int idx = blockIdx.x * 256 + threadIdx.x;   // (n*512+i)*128+o
  int o = idx & 127, i = (idx >> 7) & 511, n = idx >> 16;
  const float* xp = x + n * 512;
  float acc = bias[o];
#pragma unroll
  for (int k = 0; k < 4; k++) {
    int p = i + k - 1;
    float xv = (p >= 0 && p < 512) ? xp[p] : 0.f;
    acc = fmaf(xv, K4[o * 4 + k], acc);
  }
  float sc = g[o] * rsqrtf(1.f + 1e-5f);
  y[idx] = f2bf(fmaxf(fmaf(acc, sc, bb[o]), 0.f));
}

// reorder conv weights (o,c,kk) f32 -> Wr[o][kk*128+c] bf16
__global__ void reorder_w(const float* __restrict__ Kc, unsigned short* __restrict__ Wr,
                          int KS, int total)
{
  int idx = blockIdx.x * 256 + threadIdx.x;
  if (idx < total) {
    int c = idx & 127;
    int kk = (idx >> 7) % KS;
    int o = idx / (128 * KS);
    Wr[idx] = f2bf(Kc[(o * 128 + c) * KS + kk]);
  }
}

// Implicit-GEMM conv via MFMA. X [n][LEN][128] bf16 -> Y [n][LEN][128].
// block = 64 i-rows x 64 o-cols; 4 waves each own a 16-row strip.
template<int KS, int PAD, int LEN, int OUTF>
__global__ __launch_bounds__(256) void convT_mfma(
    const unsigned short* __restrict__ X, const unsigned short* __restrict__ Wr,
    const float* __restrict__ bias, const float* __restrict__ g,
    const float* __restrict__ bb,
    unsigned short* __restrict__ Yb, float* __restrict__ Yf)
{
  constexpr int ROWS = 64 + KS - 1;
  __shared__ __align__(16) unsigned short XT[ROWS * 128];
  const int tid = threadIdx.x;
  const int w = tid >> 6, lane = tid & 63;
  const int l15 = lane & 15, l4 = lane >> 4;
  const int i0 = (blockIdx.x >> 1) * 64;
  const int o0 = (blockIdx.x & 1) * 64;
  const int n = blockIdx.y;

  {
    const int c = (tid & 15) * 8;
    for (int r = tid >> 4; r < ROWS; r += 16) {
      int gi = i0 - PAD + r;
      bf16x8 v = {};
      if (gi >= 0 && gi < LEN)
        v = *(const bf16x8*)&X[((size_t)n * LEN + gi) * 128 + c];
      int byte = r * 256 + c * 2;
      *(bf16x8*)((char*)XT + swz256(byte)) = v;
    }
  }
  __syncthreads();

  f32x4 acc[4] = {};
#pragma unroll
  for (int kk = 0; kk < KS; kk++) {
#pragma unroll
    for (int cc = 0; cc < 4; cc++) {
      int r = w * 16 + l15 + kk;
      int byte = r * 256 + cc * 64 + l4 * 16;
      bf16x8 a = *(const bf16x8*)((const char*)XT + swz256(byte));
      bf16x8 bfr[4];
#pragma unroll
      for (int nb = 0; nb < 4; nb++)
        bfr[nb] = *(const bf16x8*)&Wr[(size_t)(o0 + nb * 16 + l15) * (KS * 128) +
                                      kk * 128 + cc * 32 + l4 * 8];
#pragma unroll
      for (int nb = 0; nb < 4; nb++)
        acc[nb] = __builtin_amdgcn_mfma_f32_16x16x32_bf16(a, bfr[nb], acc[nb], 0, 0, 0);
    }
  }

#pragma unroll
  for (int nb = 0; nb < 4; nb++) {
    int o = o0 + nb * 16 + l15;
    float sc = g[o] * rsqrtf(1.f + 1e-5f);
    float bs = bias[o], bo_ = bb[o];
#pragma unroll
    for (int rr = 0; rr < 4; rr++) {
      int i = i0 + w * 16 + l4 * 4 + rr;
      float v = fmaxf(fmaf(acc[nb][rr] + bs, sc, bo_), 0.f);
      size_t oidx = ((size_t)n * LEN + i) * 128 + o;
      if (OUTF) Yf[oidx] = v;
      else Yb[oidx] = f2bf(v);
    }
  }
}

// pairwise mean along L, channels-last bf16. nI = output length.
__global__ void avgpool2_bf(const unsigned short* __restrict__ x,
                            unsigned short* __restrict__ y, int nI, int nTot4)
{
  int j = blockIdx.x * 256 + threadIdx.x;
  if (j >= nTot4) return;
  int cq = j & 31;
  int i = (j >> 5) % nI;
  int n = j / (nI * 32);
  const ushort4* a = (const ushort4*)&x[(((size_t)n * nI + i) * 2) * 128 + cq * 4];
  const ushort4* b = (const ushort4*)&x[(((size_t)n * nI + i) * 2 + 1) * 128 + cq * 4];
  ushort4 ua = *a, ub = *b;
  ushort4 r;
  r.x = f2bf(0.5f * (bf2f(ua.x) + bf2f(ub.x)));
  r.y = f2bf(0.5f * (bf2f(ua.y) + bf2f(ub.y)));
  r.z = f2bf(0.5f * (bf2f(ua.z) + bf2f(ub.z)));
  r.w = f2bf(0.5f * (bf2f(ua.w) + bf2f(ub.w)));
  ((ushort4*)y)[j] = r;
}

// pool (pairs along L) + transpose to reference flat order [n][c*128+i], f32 out.
__global__ void pool3_transpose(const float* __restrict__ x, float* __restrict__ y)
{
  int j = blockIdx.x * 256 + threadIdx.x;   // n*16384 + c*128 + i
  if (j >= 524288) return;
  int i = j & 127, c = (j >> 7) & 127, n = j >> 14;
  const float* b = x + ((size_t)n * 256 + 2 * i) * 128 + c;
  y[j] = 0.5f * (b[0] + b[128]);
}

__global__ __launch_bounds__(256) void fc1_kernel(
    const float* __restrict__ x, const float* __restrict__ W,
    const float* __restrict__ bias, const float* __restrict__ g,
    const float* __restrict__ bb, float* __restrict__ y)
{
  int o = blockIdx.x & 255, n = blockIdx.x >> 8;
  const float* xp = x + (size_t)n * 16384;
  const float* wp = W + (size_t)o * 16384;
  float s = 0.f;
  for (int j = threadIdx.x * 4; j < 16384; j += 1024) {
    float4 a = *(const float4*)(xp + j);
    float4 b = *(const float4*)(wp + j);
    s = fmaf(a.x, b.x, s); s = fmaf(a.y, b.y, s);
    s = fmaf(a.z, b.z, s); s = fmaf(a.w, b.w, s);
  }
  s = wave_sum64(s);
  __shared__ float red[4];
  if ((threadIdx.x & 63) == 0) red[threadIdx.x >> 6] = s;
  __syncthreads();
  if (threadIdx.x == 0) {
    float v = red[0] + red[1] + red[2] + red[3] + bias[o];
    v = fmaxf(v, 0.f);
    y[n * 256 + o] = fmaf(v, g[o] * rsqrtf(1.f + 1e-5f), bb[o]);
  }
}

__global__ __launch_bounds__(256) void fc2_kernel(
    const float* __restrict__ x, const float* __restrict__ W,
    const float* __restrict__ bias, const float* __restrict__ g,
    const float* __restrict__ bb, float* __restrict__ y)
{
  int o = blockIdx.x & 127, n = blockIdx.x >> 7;
  float s = x[n * 256 + threadIdx.x] * W[o * 256 + threadIdx.x];
  s = wave_sum64(s);
  __shared__ float red[4];
  if ((threadIdx.x & 63) == 0) red[threadIdx.x >> 6] = s;
  __syncthreads();
  if (threadIdx.x == 0) {
    float v = red[0] + red[1] + red[2] + red[3] + bias[o];
    v = fmaxf(v, 0.f);
    y[n * 128 + o] = fmaf(v, g[o] * rsqrtf(1.f + 1e-5f), bb[o]);
  }
}

__global__ __launch_bounds__(64) void fc3_kernel(
    const float* __restrict__ x, const float* __restrict__ W,
    const float* __restrict__ bias, float* __restrict__ out)
{
  int n = threadIdx.x;
  if (n < 32) {
    float s = bias[0];
    for (int k = 0; k < 128; k++) s = fmaf(x[n * 128 + k], W[k], s);
    float p = 1.f / (1.f + expf(-s));
    out[n] = p;
    out[32 + n] = (p >= 0.5f) ? 1.f : 0.f;
  }
}

extern "C" void kernel_launch(void* const* d_in, const int* in_sizes, int n_in,
                              void* d_out, int out_size, void* d_ws, size_t ws_size,
                              hipStream_t stream)
{
  const float* datas = (const float*)d_in[0];
  const float* Wqkv = (const float*)d_in[6];
  const float* bqkv = (const float*)d_in[7];
  const float* Wo   = (const float*)d_in[8];
  const float* bo   = (const float*)d_in[9];
  const float* ln1g = (const float*)d_in[10];
  const float* ln1b = (const float*)d_in[11];
  const float* W1   = (const float*)d_in[12];
  const float* b1   = (const float*)d_in[13];
  const float* W2   = (const float*)d_in[14];
  const float* b2   = (const float*)d_in[15];
  const float* ln2g = (const float*)d_in[16];
  const float* ln2b = (const float*)d_in[17];
  const float* Wv1  = (const float*)d_in[18];
  const float* bv1  = (const float*)d_in[19];
  const float* Wu1  = (const float*)d_in[20];
  const float* bu1  = (const float*)d_in[21];
  const float* Ww1  = (const float*)d_in[22];
  const float* bw1  = (const float*)d_in[23];
  const float* Wv2  = (const float*)d_in[24];
  const float* bv2  = (const float*)d_in[25];
  const float* Wu2  = (const float*)d_in[26];
  const float* bu2  = (const float*)d_in[27];
  const float* Ww2  = (const float*)d_in[28];
  const float* bw2  = (const float*)d_in[29];
  const float* Kc1  = (const float*)d_in[30];
  const float* bc1  = (const float*)d_in[31];
  const float* gc1  = (const float*)d_in[32];
  const float* bb1  = (const float*)d_in[33];
  const float* Kc2  = (const float*)d_in[34];
  const float* bc2  = (const float*)d_in[35];
  const float* gc2  = (const float*)d_in[36];
  const float* bb2  = (const float*)d_in[37];
  const float* Kc3  = (const float*)d_in[38];
  const float* bc3  = (const float*)d_in[39];
  const float* gc3  = (const float*)d_in[40];
  const float* bb3  = (const float*)d_in[41];
  const float* Wf1  = (const float*)d_in[42];
  const float* bf1  = (const float*)d_in[43];
  const float* g4   = (const float*)d_in[44];
  const float* b4   = (const float*)d_in[45];
  const float* Wf2  = (const float*)d_in[46];
  const float* bf2  = (const float*)d_in[47];
  const float* g5   = (const float*)d_in[48];
  const float* b5   = (const float*)d_in[49];
  const float* Wf3  = (const float*)d_in[50];
  const float* bf3  = (const float*)d_in[51];

  float* ws = (float*)d_ws;
  float* h_f32 = ws;                              // 2,097,152 f
  float* R2f   = ws + 2097152;                    // 6,291,456 f
  unsigned short* h_bf = (unsigned short*)(ws + 8388608);   // 2,097,152 ush
  unsigned short* wbuf = (unsigned short*)(ws + 9437184);   // 3,145,728 ush

  unsigned short* qkv_bf = (unsigned short*)R2f;
  unsigned short* O_bf   = (unsigned short*)(R2f + 3145728);
  unsigned short* ff1_bf = (unsigned short*)R2f;
  float* projf = R2f + 4194304;

  unsigned short* WqkvB = wbuf;
  unsigned short* WoB   = wbuf + 786432;
  unsigned short* W1B   = wbuf + 1048576;
  unsigned short* W2B   = wbuf + 2097152;
  unsigned short* Wv1B  = wbuf;
  unsigned short* Wu1B  = wbuf + 65536;
  unsigned short* Wr2B  = wbuf + 262144;   // 81,920 ush
  unsigned short* Wr3B  = wbuf + 344064;   // 114,688 ush

  float* out_f = (float*)d_out;

  init_h<<<2048, 256, 0, stream>>>(datas, h_f32, h_bf, 524288);

  for (int l = 0; l < 2; l++) {
    cast_bf16<<<768, 256, 0, stream>>>(Wqkv + (size_t)l * 786432, WqkvB, 196608);
    cast_bf16<<<256, 256, 0, stream>>>(Wo + (size_t)l * 262144, WoB, 65536);
    cast_bf16<<<1024, 256, 0, stream>>>(W1 + (size_t)l * 1048576, W1B, 262144);
    cast_bf16<<<1024, 256, 0, stream>>>(W2 + (size_t)l * 1048576, W2B, 262144);

    mgemm<0, 1><<<dim3(12, 32), 256, 0, stream>>>(
        h_bf, WqkvB, bqkv + (size_t)l * 1536, nullptr, qkv_bf, 4096, 1536, 512);
    attn_mfma<<<dim3(64, 8), 256, 0, stream>>>(qkv_bf, O_bf);
    mgemm<0, 0><<<dim3(4, 32), 256, 0, stream>>>(
        O_bf, WoB, bo + (size_t)l * 512, projf, nullptr, 4096, 512, 512);
    residual_ln<<<4096, 64, 0, stream>>>(projf, h_f32, ln1g + l * 512, ln1b + l * 512,
                                         h_f32, h_bf);
    mgemm<1, 1><<<dim3(16, 32), 256, 0, stream>>>(
        h_bf, W1B, b1 + (size_t)l * 2048, nullptr, ff1_bf, 4096, 2048, 512);
    mgemm<0, 0><<<dim3(4, 32), 256, 0, stream>>>(
        ff1_bf, W2B, b2 + (size_t)l * 512, projf, nullptr, 4096, 512, 2048);
    residual_ln<<<4096, 64, 0, stream>>>(projf, h_f32, ln2g + l * 512, ln2b + l * 512,
                                         h_f32, h_bf);
  }

  // ---- gated pooling ----
  float* Gv   = R2f;
  float* Gu   = R2f + 524288;
  float* A1   = R2f + 1048576;
  float* out1 = R2f + 1052672;
  float* Gv2  = R2f + 1183744;
  float* Gu2  = R2f + 1216512;
  float* A2   = R2f + 1249280;
  float* out2 = R2f + 1249536;

  cast_bf16<<<64, 256, 0, stream>>>(Wv1, Wv1B, 16384);
  cast_bf16<<<64, 256, 0, stream>>>(Wu1, Wu1B, 16384);
  reorder_w<<<320, 256, 0, stream>>>(Kc2, Wr2B, 5, 81920);
  reorder_w<<<448, 256, 0, stream>>>(Kc3, Wr3B, 7, 114688);

  mgemm<2, 0><<<dim3(1, 32), 256, 0, stream>>>(h_bf, Wv1B, bv1, Gv, nullptr, 4096, 128, 512);
  mgemm<3, 0><<<dim3(1, 32), 256, 0, stream>>>(h_bf, Wu1B, bu1, Gu, nullptr, 4096, 128, 512);
  gate_dot<<<4096, 128, 0, stream>>>(Gv, Gu, Ww1, bw1, A1);
  seg_pool<<<256, 256, 0, stream>>>(A1, h_f32, out_f + 64, out1, 16);

  gemm_bias<2><<<dim3(2, 4), 256, 0, stream>>>(out1, Wv2, bv2, Gv2, 256, 128, 512);
  gemm_bias<3><<<dim3(2, 4), 256, 0, stream>>>(out1, Wu2, bu2, Gu2, 256, 128, 512);
  gate_dot<<<256, 128, 0, stream>>>(Gv2, Gu2, Ww2, bw2, A2);
  seg_pool<<<32, 256, 0, stream>>>(A2, out1, out_f + 4160, out2, 8);

  // ---- CNN head, channels-last ----
  unsigned short* c1T = (unsigned short*)(R2f + 1310720);  // 2,097,152 ush
  unsigned short* c2T = (unsigned short*)(R2f + 2359296);  // 2,097,152 ush
  unsigned short* p2T = (unsigned short*)(R2f + 3407872);  // 1,048,576 ush
  float* c3T = R2f + 3932160;                              // 1,048,576 f
  float* p3R = R2f + 4980736;                              // 524,288 f
  float* f1  = R2f + 5505024;
  float* f2  = R2f + 5513216;

  conv1_bnT<<<8192, 256, 0, stream>>>(out2, Kc1, bc1, gc1, bb1, c1T);
  convT_mfma<5, 2, 512, 0><<<dim3(16, 32), 256, 0, stream>>>(
      c1T, Wr2B, bc2, gc2, bb2, c2T, nullptr);
  avgpool2_bf<<<1024, 256, 0, stream>>>(c2T, p2T, 256, 262144);
  convT_mfma<7, 3, 256, 1><<<dim3(8, 32), 256, 0, stream>>>(
      p2T, Wr3B, bc3, gc3, bb3, nullptr, c3T);
  pool3_transpose<<<2048, 256, 0, stream>>>(c3T, p3R);
  fc1_kernel<<<8192, 256, 0, stream>>>(p3R, Wf1, bf1, g4, b4, f1);
  fc2_kernel<<<4096, 256, 0, stream>>>(f1, Wf2, bf2, g5, b5, f2);
  fc3_kernel<<<1, 64, 0, stream>>>(f2, Wf3, bf3, out_f);
}

// Round 4
// 706.416 us; speedup vs baseline: 5.6609x; 1.0783x over previous
//
#include <hip/hip_runtime.h>
#include <math.h>

// T=4096, M=512, NH=8, HD=64, FF=2048, NL=2, NI=256 (16 tok/seg), NO=32 (8 seg/outer)

typedef float f32x4 __attribute__((ext_vector_type(4)));
typedef __bf16 bf16x8 __attribute__((ext_vector_type(8)));

__device__ __forceinline__ unsigned short f2bf(float x) {
  unsigned int u = __builtin_bit_cast(unsigned int, x);
  u += 0x7FFFu + ((u >> 16) & 1u);
  return (unsigned short)(u >> 16);
}
__device__ __forceinline__ float bf2f(unsigned short u) {
  unsigned int x = ((unsigned int)u) << 16;
  return __builtin_bit_cast(float, x);
}
// pack two f32 -> two bf16 (RTNE) in one instruction
__device__ __forceinline__ unsigned int pk_bf16(float a, float b) {
  unsigned int r;
  asm("v_cvt_pk_bf16_f32 %0, %1, %2" : "=v"(r) : "v"(a), "v"(b));
  return r;
}

__device__ __forceinline__ float wave_sum64(float v) {
#pragma unroll
  for (int o = 32; o > 0; o >>= 1) v += __shfl_xor(v, o);
  return v;
}

// XOR swizzle for LDS tiles with 128-byte rows (64 bf16/row).
__device__ __forceinline__ int swz(int byte) {
  return byte ^ (((byte >> 7) & 7) << 4);
}
// XOR swizzle for LDS tiles with 256-byte rows (128 bf16/row).
__device__ __forceinline__ int swz256(int byte) {
  return byte ^ (((byte >> 8) & 7) << 4);
}

// ============ bf16 MFMA GEMM: C[M,N] = act(A[M,K] @ B[N,K]^T + bias) ============
template<int ACT, int OUTBF>
__global__ __launch_bounds__(256) void mgemm(
    const unsigned short* __restrict__ A, const unsigned short* __restrict__ B,
    const float* __restrict__ bias, float* __restrict__ Cf,
    unsigned short* __restrict__ Cb, int M, int N, int K)
{
  __shared__ __align__(16) unsigned short As[128 * 64];
  __shared__ __align__(16) unsigned short Bs[128 * 64];
  const int tid = threadIdx.x;
  const int wid = tid >> 6, lane = tid & 63;
  const int wm = wid >> 1, wn = wid & 1;
  const int l15 = lane & 15, l4 = lane >> 4;
  const int m0 = blockIdx.y * 128, n0 = blockIdx.x * 128;
  const int srow = tid >> 3;
  const int scol = (tid & 7) * 8;

  f32x4 acc[4][4] = {};

  for (int k0 = 0; k0 < K; k0 += 64) {
    bf16x8 ra[4], rb[4];
#pragma unroll
    for (int i = 0; i < 4; i++) {
      ra[i] = *(const bf16x8*)&A[(size_t)(m0 + srow + i * 32) * K + k0 + scol];
      rb[i] = *(const bf16x8*)&B[(size_t)(n0 + srow + i * 32) * K + k0 + scol];
    }
    __syncthreads();
#pragma unroll
    for (int i = 0; i < 4; i++) {
      int byte = (srow + i * 32) * 128 + scol * 2;
      *(bf16x8*)((char*)As + swz(byte)) = ra[i];
      *(bf16x8*)((char*)Bs + swz(byte)) = rb[i];
    }
    __syncthreads();
#pragma unroll
    for (int kc = 0; kc < 2; kc++) {
      bf16x8 af[4], bf_[4];
#pragma unroll
      for (int i = 0; i < 4; i++) {
        int byteA = (wm * 64 + i * 16 + l15) * 128 + kc * 64 + l4 * 16;
        af[i] = *(const bf16x8*)((const char*)As + swz(byteA));
        int byteB = (wn * 64 + i * 16 + l15) * 128 + kc * 64 + l4 * 16;
        bf_[i] = *(const bf16x8*)((const char*)Bs + swz(byteB));
      }
#pragma unroll
      for (int i = 0; i < 4; i++)
#pragma unroll
        for (int j = 0; j < 4; j++)
          acc[i][j] = __builtin_amdgcn_mfma_f32_16x16x32_bf16(af[i], bf_[j], acc[i][j], 0, 0, 0);
    }
  }
#pragma unroll
  for (int i = 0; i < 4; i++) {
#pragma unroll
    for (int j = 0; j < 4; j++) {
      int col = n0 + wn * 64 + j * 16 + l15;
      float bv = bias[col];
#pragma unroll
      for (int r = 0; r < 4; r++) {
        int row = m0 + wm * 64 + i * 16 + l4 * 4 + r;
        float x = acc[i][j][r] + bv;
        if (ACT == 1) x = fmaxf(x, 0.f);
        if (ACT == 2) x = tanhf(x);
        if (ACT == 3) x = 1.f / (1.f + expf(-x));
        if (OUTBF) Cb[(size_t)row * N + col] = f2bf(x);
        else       Cf[(size_t)row * N + col] = x;
      }
    }
  }
}

// ============ MFMA flash attention (swapped operands: lane-local softmax) ============
// qkv bf16 [4096][1536] -> O bf16 [4096][512]. block=(qt,h), 4 waves, wave w: q-rows
// w*16..w*16+15, each lane owns q = w*16 + (lane&15) across the whole kt loop.
__global__ __launch_bounds__(256) void attn_mfma(
    const unsigned short* __restrict__ qkv, unsigned short* __restrict__ O)
{
  __shared__ __align__(16) unsigned short Ks[64 * 64];   // [k][d]   swizzled
  __shared__ __align__(16) unsigned short VTs[64 * 64];  // [d][k]   swizzled
  __shared__ __align__(16) unsigned short Ps[64 * 64];   // [q][k]   swizzled
  const int tid = threadIdx.x;
  const int w = tid >> 6, lane = tid & 63;
  const int l15 = lane & 15, l4 = lane >> 4;
  const int h = blockIdx.y, qt = blockIdx.x;
  const float C = 0.18033688011112042f;   // 0.125 * log2(e)

  // Q fragment (used as the MFMA **B** operand: col = q = l15)
  bf16x8 qf[2];
#pragma unroll
  for (int kc = 0; kc < 2; kc++)
    qf[kc] = *(const bf16x8*)&qkv[(size_t)(qt * 64 + w * 16 + l15) * 1536 + h * 64 + kc * 32 + l4 * 8];

  f32x4 oaccT[4] = {};            // O^T: row = d-local, col = q = l15
  float m = -1e30f, l = 0.f;      // per-lane online-softmax state for q = w*16+l15

  const int sr = tid >> 3;
  const int sc = (tid & 7) * 8;
  const int vk = tid & 63;
  const int vd0 = (tid >> 6) * 8;

  for (int kt = 0; kt < 64; kt++) {
    const unsigned short* kb = qkv + (size_t)(kt * 64) * 1536 + 512 + h * 64;
    const unsigned short* vb = qkv + (size_t)(kt * 64) * 1536 + 1024 + h * 64;
    bf16x8 rk0 = *(const bf16x8*)&kb[(size_t)sr * 1536 + sc];
    bf16x8 rk1 = *(const bf16x8*)&kb[(size_t)(sr + 32) * 1536 + sc];
    bf16x8 rv0 = *(const bf16x8*)&vb[(size_t)vk * 1536 + vd0];
    bf16x8 rv1 = *(const bf16x8*)&vb[(size_t)vk * 1536 + vd0 + 32];
    __syncthreads();
    {
      int b0 = sr * 128 + sc * 2;
      *(bf16x8*)((char*)Ks + swz(b0)) = rk0;
      int b1 = (sr + 32) * 128 + sc * 2;
      *(bf16x8*)((char*)Ks + swz(b1)) = rk1;
      union { bf16x8 v; unsigned short u[8]; } c0, c1;
      c0.v = rv0; c1.v = rv1;
#pragma unroll
      for (int j = 0; j < 8; j++) {
        int bb0 = (vd0 + j) * 128 + vk * 2;
        *(unsigned short*)((char*)VTs + swz(bb0)) = c0.u[j];
        int bb1 = (vd0 + 32 + j) * 128 + vk * 2;
        *(unsigned short*)((char*)VTs + swz(bb1)) = c1.u[j];
      }
    }
    __syncthreads();

    // S^T = mfma(A=K, B=Q): D[m = k-local][n = q]. Lane holds st[nb][r] =
    // S[k = kt*64 + nb*16 + l4*4 + r][q = w*16 + l15].
    f32x4 st[4] = {};
#pragma unroll
    for (int kc = 0; kc < 2; kc++) {
#pragma unroll
      for (int nb = 0; nb < 4; nb++) {
        int byte = (nb * 16 + l15) * 128 + kc * 64 + l4 * 16;
        bf16x8 kf = *(const bf16x8*)((const char*)Ks + swz(byte));
        st[nb] = __builtin_amdgcn_mfma_f32_16x16x32_bf16(kf, qf[kc], st[nb], 0, 0, 0);
      }
    }

    // lane-local online softmax over the 64 k of this tile
    float tm = -1e30f;
#pragma unroll
    for (int nb = 0; nb < 4; nb++)
#pragma unroll
      for (int r = 0; r < 4; r++) tm = fmaxf(tm, st[nb][r]);
    tm = fmaxf(tm, __shfl_xor(tm, 16));
    tm = fmaxf(tm, __shfl_xor(tm, 32));
    float mn = fmaxf(m, tm);
    float alpha = exp2f((m - mn) * C);
    float e[4][4];
    float ps = 0.f;
#pragma unroll
    for (int nb = 0; nb < 4; nb++)
#pragma unroll
      for (int r = 0; r < 4; r++) {
        e[nb][r] = exp2f((st[nb][r] - mn) * C);
        ps += e[nb][r];
      }
    ps += __shfl_xor(ps, 16);
    ps += __shfl_xor(ps, 32);
    l = l * alpha + ps;
    m = mn;
#pragma unroll
    for (int nb = 0; nb < 4; nb++) oaccT[nb] *= alpha;

    // P^T rows -> Ps[q][k] (lane writes its own q-row; 4 x ds_write_b64)
#pragma unroll
    for (int nb = 0; nb < 4; nb++) {
      uint2 pr;
      pr.x = pk_bf16(e[nb][0], e[nb][1]);
      pr.y = pk_bf16(e[nb][2], e[nb][3]);
      int byte = (w * 16 + l15) * 128 + (nb * 16 + l4 * 4) * 2;
      *(uint2*)((char*)Ps + swz(byte)) = pr;
    }

    // O^T += mfma(A=V^T, B=P^T): D[m = d-local][n = q]
#pragma unroll
    for (int kc = 0; kc < 2; kc++) {
      int bp = (w * 16 + l15) * 128 + kc * 64 + l4 * 16;
      bf16x8 pb = *(const bf16x8*)((const char*)Ps + swz(bp));
#pragma unroll
      for (int nb = 0; nb < 4; nb++) {
        int bv = (nb * 16 + l15) * 128 + kc * 64 + l4 * 16;
        bf16x8 vf = *(const bf16x8*)((const char*)VTs + swz(bv));
        oaccT[nb] = __builtin_amdgcn_mfma_f32_16x16x32_bf16(vf, pb, oaccT[nb], 0, 0, 0);
      }
    }
  }

  // epilogue: in-lane 1/l, packed 8-byte stores (4 consecutive d per nb)
  float linv = 1.f / l;
  int row = qt * 64 + w * 16 + l15;
#pragma unroll
  for (int nb = 0; nb < 4; nb++) {
    uint2 ov;
    ov.x = pk_bf16(oaccT[nb][0] * linv, oaccT[nb][1] * linv);
    ov.y = pk_bf16(oaccT[nb][2] * linv, oaccT[nb][3] * linv);
    int col = h * 64 + nb * 16 + l4 * 4;
    *(uint2*)&O[(size_t)row * 512 + col] = ov;
  }
}

// ---------------- fp32 GEMM (tiny stage-2 gating) ----------------
template<int ACT>
__global__ __launch_bounds__(256) void gemm_bias(
    const float* __restrict__ A, const float* __restrict__ B,
    const float* __restrict__ bias, float* __restrict__ C,
    int M, int N, int K)
{
  __shared__ float As[16][68];
  __shared__ float Bs[16][68];
  const int tid = threadIdx.x;
  const int tx = tid & 15, ty = tid >> 4;
  const int m0 = blockIdx.y * 64, n0 = blockIdx.x * 64;
  const int lr = tid >> 2;
  const int lk = (tid & 3) * 4;
  float acc[4][4] = {};
  for (int k0 = 0; k0 < K; k0 += 16) {
    __syncthreads();
    float4 av = *(const float4*)&A[(size_t)(m0 + lr) * K + k0 + lk];
    float4 bv = *(const float4*)&B[(size_t)(n0 + lr) * K + k0 + lk];
    As[lk + 0][lr] = av.x; As[lk + 1][lr] = av.y; As[lk + 2][lr] = av.z; As[lk + 3][lr] = av.w;
    Bs[lk + 0][lr] = bv.x; Bs[lk + 1][lr] = bv.y; Bs[lk + 2][lr] = bv.z; Bs[lk + 3][lr] = bv.w;
    __syncthreads();
#pragma unroll
    for (int k = 0; k < 16; k++) {
      float a[4], b[4];
#pragma unroll
      for (int i = 0; i < 4; i++) a[i] = As[k][ty * 4 + i];
#pragma unroll
      for (int j = 0; j < 4; j++) b[j] = Bs[k][tx * 4 + j];
#pragma unroll
      for (int i = 0; i < 4; i++)
#pragma unroll
        for (int j = 0; j < 4; j++)
          acc[i][j] = fmaf(a[i], b[j], acc[i][j]);
    }
  }
#pragma unroll
  for (int i = 0; i < 4; i++)
#pragma unroll
    for (int j = 0; j < 4; j++) {
      float x = acc[i][j] + bias[n0 + tx * 4 + j];
      if (ACT == 1) x = fmaxf(x, 0.f);
      if (ACT == 2) x = tanhf(x);
      if (ACT == 3) x = 1.f / (1.f + expf(-x));
      C[(size_t)(m0 + ty * 4 + i) * N + n0 + tx * 4 + j] = x;
    }
}

// ---------------- LayerNorm(x + res), writes f32 + bf16 ----------------
__global__ __launch_bounds__(64) void residual_ln(
    const float* __restrict__ x, const float* __restrict__ res,
    const float* __restrict__ g, const float* __restrict__ b,
    float* __restrict__ out, unsigned short* __restrict__ out_bf)
{
  const int row = blockIdx.x, lane = threadIdx.x;
  const float* xp = x + (size_t)row * 512;
  const float* rp = res + (size_t)row * 512;
  float v[8];
  float s = 0.f;
#pragma unroll
  for (int i = 0; i < 8; i++) { v[i] = xp[lane + 64 * i] + rp[lane + 64 * i]; s += v[i]; }
  s = wave_sum64(s);
  float mu = s * (1.f / 512.f);
  float vs = 0.f;
#pragma unroll
  for (int i = 0; i < 8; i++) { float d = v[i] - mu; vs = fmaf(d, d, vs); }
  vs = wave_sum64(vs);
  float rstd = rsqrtf(vs * (1.f / 512.f) + 1e-5f);
  float* op = out + (size_t)row * 512;
  unsigned short* ob = out_bf + (size_t)row * 512;
#pragma unroll
  for (int i = 0; i < 8; i++) {
    float y = (v[i] - mu) * rstd * g[lane + 64 * i] + b[lane + 64 * i];
    op[lane + 64 * i] = y;
    ob[lane + 64 * i] = f2bf(y);
  }
}

// ---------------- casts ----------------
__global__ void cast_bf16(const float* __restrict__ in, unsigned short* __restrict__ out, int n4)
{
  int i = blockIdx.x * 256 + threadIdx.x;
  if (i < n4) {
    float4 v = ((const float4*)in)[i];
    ushort4 u;
    u.x = f2bf(v.x); u.y = f2bf(v.y); u.z = f2bf(v.z); u.w = f2bf(v.w);
    ((ushort4*)out)[i] = u;
  }
}

__global__ void init_h(const float* __restrict__ in, float* __restrict__ hf,
                       unsigned short* __restrict__ hb, int n4)
{
  int i = blockIdx.x * 256 + threadIdx.x;
  if (i < n4) {
    float4 v = ((const float4*)in)[i];
    ((float4*)hf)[i] = v;
    ushort4 u;
    u.x = f2bf(v.x); u.y = f2bf(v.y); u.z = f2bf(v.z); u.w = f2bf(v.w);
    ((ushort4*)hb)[i] = u;
  }
}

// ---------------- A[t] = sum_l Gv*Gu*Ww + bw ----------------
__global__ __launch_bounds__(128) void gate_dot(
    const float* __restrict__ Gv, const float* __restrict__ Gu,
    const float* __restrict__ Ww, const float* __restrict__ bw,
    float* __restrict__ A)
{
  const int t = blockIdx.x, l = threadIdx.x;
  float v = Gv[(size_t)t * 128 + l] * Gu[(size_t)t * 128 + l] * Ww[l];
  v = wave_sum64(v);
  __shared__ float red[2];
  if ((l & 63) == 0) red[l >> 6] = v;
  __syncthreads();
  if (l == 0) A[t] = red[0] + red[1] + bw[0];
}

// ------- contiguous-segment softmax + weighted pooled sum (D=512) -------
__global__ __launch_bounds__(256) void seg_pool(
    const float* __restrict__ A, const float* __restrict__ X,
    float* __restrict__ w_out, float* __restrict__ out, int seg_len)
{
  const int s = blockIdx.x, tid = threadIdx.x;
  __shared__ float ws[16];
  if (tid < 64) {
    float a = (tid < seg_len) ? A[s * seg_len + tid] : -1e30f;
    float mx = a;
#pragma unroll
    for (int o = 1; o < 16; o <<= 1) mx = fmaxf(mx, __shfl_xor(mx, o));
    float e = (tid < seg_len) ? expf(a - mx) : 0.f;
    float se = e;
#pragma unroll
    for (int o = 1; o < 16; o <<= 1) se += __shfl_xor(se, o);
    if (tid < seg_len) {
      float w = e / se;
      ws[tid] = w;
      w_out[s * seg_len + tid] = w;
    }
  }
  __syncthreads();
  for (int d = tid; d < 512; d += 256) {
    float acc = 0.f;
    for (int i = 0; i < seg_len; i++)
      acc = fmaf(ws[i], X[(size_t)(s * seg_len + i) * 512 + d], acc);
    out[(size_t)s * 512 + d] = acc;
  }
}

// ======================= CNN head (channels-last [n][L][C=128]) =======================

__global__ void conv1_bnT(
    const float* __restrict__ x, const float* __restrict__ K4,
    const float* __restrict__ bias, const float* __restrict__ g,
    const float* __restrict__ bb, unsigned short* __restrict__ y)
{
  int idx = blockIdx.x * 256 + threadIdx.x;   // (n*512+i)*128+o
  int o = idx & 127, i = (idx >> 7) & 511, n = idx >> 16;
  const float* xp = x + n * 512;
  float acc = bias[o];
#pragma unroll
  for (int k = 0; k < 4; k++) {
    int p = i + k - 1;
    float xv = (p >= 0 && p < 512) ? xp[p] : 0.f;
    acc = fmaf(xv, K4[o * 4 + k], acc);
  }
  float sc = g[o] * rsqrtf(1.f + 1e-5f);
  y[idx] = f2bf(fmaxf(fmaf(acc, sc, bb[o]), 0.f));
}

__global__ void reorder_w(const float* __restrict__ Kc, unsigned short* __restrict__ Wr,
                          int KS, int total)
{
  int idx = blockIdx.x * 256 + threadIdx.x;
  if (idx < total) {
    int c = idx & 127;
    int kk = (idx >> 7) % KS;
    int o = idx / (128 * KS);
    Wr[idx] = f2bf(Kc[(o * 128 + c) * KS + kk]);
  }
}

template<int KS, int PAD, int LEN, int OUTF>
__global__ __launch_bounds__(256) void convT_mfma(
    const unsigned short* __restrict__ X, const unsigned short* __restrict__ Wr,
    const float* __restrict__ bias, const float* __restrict__ g,
    const float* __restrict__ bb,
    unsigned short* __restrict__ Yb, float* __restrict__ Yf)
{
  constexpr int ROWS = 64 + KS - 1;
  __shared__ __align__(16) unsigned short XT[ROWS * 128];
  const int tid = threadIdx.x;
  const int w = tid >> 6, lane = tid & 63;
  const int l15 = lane & 15, l4 = lane >> 4;
  const int i0 = (blockIdx.x >> 1) * 64;
  const int o0 = (blockIdx.x & 1) * 64;
  const int n = blockIdx.y;

  {
    const int c = (tid & 15) * 8;
    for (int r = tid >> 4; r < ROWS; r += 16) {
      int gi = i0 - PAD + r;
      bf16x8 v = {};
      if (gi >= 0 && gi < LEN)
        v = *(const bf16x8*)&X[((size_t)n * LEN + gi) * 128 + c];
      int byte = r * 256 + c * 2;
      *(bf16x8*)((char*)XT + swz256(byte)) = v;
    }
  }
  __syncthreads();

  f32x4 acc[4] = {};
#pragma unroll
  for (int kk = 0; kk < KS; kk++) {
#pragma unroll
    for (int cc = 0; cc < 4; cc++) {
      int r = w * 16 + l15 + kk;
      int byte = r * 256 + cc * 64 + l4 * 16;
      bf16x8 a = *(const bf16x8*)((const char*)XT + swz256(byte));
      bf16x8 bfr[4];
#pragma unroll
      for (int nb = 0; nb < 4; nb++)
        bfr[nb] = *(const bf16x8*)&Wr[(size_t)(o0 + nb * 16 + l15) * (KS * 128) +
                                      kk * 128 + cc * 32 + l4 * 8];
#pragma unroll
      for (int nb = 0; nb < 4; nb++)
        acc[nb] = __builtin_amdgcn_mfma_f32_16x16x32_bf16(a, bfr[nb], acc[nb], 0, 0, 0);
    }
  }

#pragma unroll
  for (int nb = 0; nb < 4; nb++) {
    int o = o0 + nb * 16 + l15;
    float sc = g[o] * rsqrtf(1.f + 1e-5f);
    float bs = bias[o], bo_ = bb[o];
#pragma unroll
    for (int rr = 0; rr < 4; rr++) {
      int i = i0 + w * 16 + l4 * 4 + rr;
      float v = fmaxf(fmaf(acc[nb][rr] + bs, sc, bo_), 0.f);
      size_t oidx = ((size_t)n * LEN + i) * 128 + o;
      if (OUTF) Yf[oidx] = v;
      else Yb[oidx] = f2bf(v);
    }
  }
}

__global__ void avgpool2_bf(const unsigned short* __restrict__ x,
                            unsigned short* __restrict__ y, int nI, int nTot4)
{
  int j = blockIdx.x * 256 + threadIdx.x;
  if (j >= nTot4) return;
  int cq = j & 31;
  int i = (j >> 5) % nI;
  int n = j / (nI * 32);
  const ushort4* a = (const ushort4*)&x[(((size_t)n * nI + i) * 2) * 128 + cq * 4];
  const ushort4* b = (const ushort4*)&x[(((size_t)n * nI + i) * 2 + 1) * 128 + cq * 4];
  ushort4 ua = *a, ub = *b;
  ushort4 r;
  r.x = f2bf(0.5f * (bf2f(ua.x) + bf2f(ub.x)));
  r.y = f2bf(0.5f * (bf2f(ua.y) + bf2f(ub.y)));
  r.z = f2bf(0.5f * (bf2f(ua.z) + bf2f(ub.z)));
  r.w = f2bf(0.5f * (bf2f(ua.w) + bf2f(ub.w)));
  ((ushort4*)y)[j] = r;
}

__global__ void pool3_transpose(const float* __restrict__ x, float* __restrict__ y)
{
  int j = blockIdx.x * 256 + threadIdx.x;   // n*16384 + c*128 + i
  if (j >= 524288) return;
  int i = j & 127, c = (j >> 7) & 127, n = j >> 14;
  const float* b = x + ((size_t)n * 256 + 2 * i) * 128 + c;
  y[j] = 0.5f * (b[0] + b[128]);
}

__global__ __launch_bounds__(256) void fc1_kernel(
    const float* __restrict__ x, const float* __restrict__ W,
    const float* __restrict__ bias, const float* __restrict__ g,
    const float* __restrict__ bb, float* __restrict__ y)
{
  int o = blockIdx.x & 255, n = blockIdx.x >> 8;
  const float* xp = x + (size_t)n * 16384;
  const float* wp = W + (size_t)o * 16384;
  float s = 0.f;
  for (int j = threadIdx.x * 4; j < 16384; j += 1024) {
    float4 a = *(const float4*)(xp + j);
    float4 b = *(const float4*)(wp + j);
    s = fmaf(a.x, b.x, s); s = fmaf(a.y, b.y, s);
    s = fmaf(a.z, b.z, s); s = fmaf(a.w, b.w, s);
  }
  s = wave_sum64(s);
  __shared__ float red[4];
  if ((threadIdx.x & 63) == 0) red[threadIdx.x >> 6] = s;
  __syncthreads();
  if (threadIdx.x == 0) {
    float v = red[0] + red[1] + red[2] + red[3] + bias[o];
    v = fmaxf(v, 0.f);
    y[n * 256 + o] = fmaf(v, g[o] * rsqrtf(1.f + 1e-5f), bb[o]);
  }
}

__global__ __launch_bounds__(256) void fc2_kernel(
    const float* __restrict__ x, const float* __restrict__ W,
    const float* __restrict__ bias, const float* __restrict__ g,
    const float* __restrict__ bb, float* __restrict__ y)
{
  int o = blockIdx.x & 127, n = blockIdx.x >> 7;
  float s = x[n * 256 + threadIdx.x] * W[o * 256 + threadIdx.x];
  s = wave_sum64(s);
  __shared__ float red[4];
  if ((threadIdx.x & 63) == 0) red[threadIdx.x >> 6] = s;
  __syncthreads();
  if (threadIdx.x == 0) {
    float v = red[0] + red[1] + red[2] + red[3] + bias[o];
    v = fmaxf(v, 0.f);
    y[n * 128 + o] = fmaf(v, g[o] * rsqrtf(1.f + 1e-5f), bb[o]);
  }
}

__global__ __launch_bounds__(64) void fc3_kernel(
    const float* __restrict__ x, const float* __restrict__ W,
    const float* __restrict__ bias, float* __restrict__ out)
{
  int n = threadIdx.x;
  if (n < 32) {
    float s = bias[0];
    for (int k = 0; k < 128; k++) s = fmaf(x[n * 128 + k], W[k], s);
    float p = 1.f / (1.f + expf(-s));
    out[n] = p;
    out[32 + n] = (p >= 0.5f) ? 1.f : 0.f;
  }
}

extern "C" void kernel_launch(void* const* d_in, const int* in_sizes, int n_in,
                              void* d_out, int out_size, void* d_ws, size_t ws_size,
                              hipStream_t stream)
{
  const float* datas = (const float*)d_in[0];
  const float* Wqkv = (const float*)d_in[6];
  const float* bqkv = (const float*)d_in[7];
  const float* Wo   = (const float*)d_in[8];
  const float* bo   = (const float*)d_in[9];
  const float* ln1g = (const float*)d_in[10];
  const float* ln1b = (const float*)d_in[11];
  const float* W1   = (const float*)d_in[12];
  const float* b1   = (const float*)d_in[13];
  const float* W2   = (const float*)d_in[14];
  const float* b2   = (const float*)d_in[15];
  const float* ln2g = (const float*)d_in[16];
  const float* ln2b = (const float*)d_in[17];
  const float* Wv1  = (const float*)d_in[18];
  const float* bv1  = (const float*)d_in[19];
  const float* Wu1  = (const float*)d_in[20];
  const float* bu1  = (const float*)d_in[21];
  const float* Ww1  = (const float*)d_in[22];
  const float* bw1  = (const float*)d_in[23];
  const float* Wv2  = (const float*)d_in[24];
  const float* bv2  = (const float*)d_in[25];
  const float* Wu2  = (const float*)d_in[26];
  const float* bu2  = (const float*)d_in[27];
  const float* Ww2  = (const float*)d_in[28];
  const float* bw2  = (const float*)d_in[29];
  const float* Kc1  = (const float*)d_in[30];
  const float* bc1  = (const float*)d_in[31];
  const float* gc1  = (const float*)d_in[32];
  const float* bb1  = (const float*)d_in[33];
  const float* Kc2  = (const float*)d_in[34];
  const float* bc2  = (const float*)d_in[35];
  const float* gc2  = (const float*)d_in[36];
  const float* bb2  = (const float*)d_in[37];
  const float* Kc3  = (const float*)d_in[38];
  const float* bc3  = (const float*)d_in[39];
  const float* gc3  = (const float*)d_in[40];
  const float* bb3  = (const float*)d_in[41];
  const float* Wf1  = (const float*)d_in[42];
  const float* bf1  = (const float*)d_in[43];
  const float* g4   = (const float*)d_in[44];
  const float* b4   = (const float*)d_in[45];
  const float* Wf2  = (const float*)d_in[46];
  const float* bf2  = (const float*)d_in[47];
  const float* g5   = (const float*)d_in[48];
  const float* b5   = (const float*)d_in[49];
  const float* Wf3  = (const float*)d_in[50];
  const float* bf3  = (const float*)d_in[51];

  float* ws = (float*)d_ws;
  float* h_f32 = ws;                              // 2,097,152 f
  float* R2f   = ws + 2097152;                    // 6,291,456 f
  unsigned short* h_bf = (unsigned short*)(ws + 8388608);   // 2,097,152 ush
  unsigned short* wbuf = (unsigned short*)(ws + 9437184);   // 3,145,728 ush

  unsigned short* qkv_bf = (unsigned short*)R2f;
  unsigned short* O_bf   = (unsigned short*)(R2f + 3145728);
  unsigned short* ff1_bf = (unsigned short*)R2f;
  float* projf = R2f + 4194304;

  unsigned short* WqkvB = wbuf;
  unsigned short* WoB   = wbuf + 786432;
  unsigned short* W1B   = wbuf + 1048576;
  unsigned short* W2B   = wbuf + 2097152;
  unsigned short* Wv1B  = wbuf;
  unsigned short* Wu1B  = wbuf + 65536;
  unsigned short* Wr2B  = wbuf + 262144;   // 81,920 ush
  unsigned short* Wr3B  = wbuf + 344064;   // 114,688 ush

  float* out_f = (float*)d_out;

  init_h<<<2048, 256, 0, stream>>>(datas, h_f32, h_bf, 524288);

  for (int l = 0; l < 2; l++) {
    cast_bf16<<<768, 256, 0, stream>>>(Wqkv + (size_t)l * 786432, WqkvB, 196608);
    cast_bf16<<<256, 256, 0, stream>>>(Wo + (size_t)l * 262144, WoB, 65536);
    cast_bf16<<<1024, 256, 0, stream>>>(W1 + (size_t)l * 1048576, W1B, 262144);
    cast_bf16<<<1024, 256, 0, stream>>>(W2 + (size_t)l * 1048576, W2B, 262144);

    mgemm<0, 1><<<dim3(12, 32), 256, 0, stream>>>(
        h_bf, WqkvB, bqkv + (size_t)l * 1536, nullptr, qkv_bf, 4096, 1536, 512);
    attn_mfma<<<dim3(64, 8), 256, 0, stream>>>(qkv_bf, O_bf);
    mgemm<0, 0><<<dim3(4, 32), 256, 0, stream>>>(
        O_bf, WoB, bo + (size_t)l * 512, projf, nullptr, 4096, 512, 512);
    residual_ln<<<4096, 64, 0, stream>>>(projf, h_f32, ln1g + l * 512, ln1b + l * 512,
                                         h_f32, h_bf);
    mgemm<1, 1><<<dim3(16, 32), 256, 0, stream>>>(
        h_bf, W1B, b1 + (size_t)l * 2048, nullptr, ff1_bf, 4096, 2048, 512);
    mgemm<0, 0><<<dim3(4, 32), 256, 0, stream>>>(
        ff1_bf, W2B, b2 + (size_t)l * 512, projf, nullptr, 4096, 512, 2048);
    residual_ln<<<4096, 64, 0, stream>>>(projf, h_f32, ln2g + l * 512, ln2b + l * 512,
                                         h_f32, h_bf);
  }

  // ---- gated pooling ----
  float* Gv   = R2f;
  float* Gu   = R2f + 524288;
  float* A1   = R2f + 1048576;
  float* out1 = R2f + 1052672;
  float* Gv2  = R2f + 1183744;
  float* Gu2  = R2f + 1216512;
  float* A2   = R2f + 1249280;
  float* out2 = R2f + 1249536;

  cast_bf16<<<64, 256, 0, stream>>>(Wv1, Wv1B, 16384);
  cast_bf16<<<64, 256, 0, stream>>>(Wu1, Wu1B, 16384);
  reorder_w<<<320, 256, 0, stream>>>(Kc2, Wr2B, 5, 81920);
  reorder_w<<<448, 256, 0, stream>>>(Kc3, Wr3B, 7, 114688);

  mgemm<2, 0><<<dim3(1, 32), 256, 0, stream>>>(h_bf, Wv1B, bv1, Gv, nullptr, 4096, 128, 512);
  mgemm<3, 0><<<dim3(1, 32), 256, 0, stream>>>(h_bf, Wu1B, bu1, Gu, nullptr, 4096, 128, 512);
  gate_dot<<<4096, 128, 0, stream>>>(Gv, Gu, Ww1, bw1, A1);
  seg_pool<<<256, 256, 0, stream>>>(A1, h_f32, out_f + 64, out1, 16);

  gemm_bias<2><<<dim3(2, 4), 256, 0, stream>>>(out1, Wv2, bv2, Gv2, 256, 128, 512);
  gemm_bias<3><<<dim3(2, 4), 256, 0, stream>>>(out1, Wu2, bu2, Gu2, 256, 128, 512);
  gate_dot<<<256, 128, 0, stream>>>(Gv2, Gu2, Ww2, bw2, A2);
  seg_pool<<<32, 256, 0, stream>>>(A2, out1, out_f + 4160, out2, 8);

  // ---- CNN head, channels-last ----
  unsigned short* c1T = (unsigned short*)(R2f + 1310720);  // 2,097,152 ush
  unsigned short* c2T = (unsigned short*)(R2f + 2359296);  // 2,097,152 ush
  unsigned short* p2T = (unsigned short*)(R2f + 3407872);  // 1,048,576 ush
  float* c3T = R2f + 3932160;                              // 1,048,576 f
  float* p3R = R2f + 4980736;                              // 524,288 f
  float* f1  = R2f + 5505024;
  float* f2  = R2f + 5513216;

  conv1_bnT<<<8192, 256, 0, stream>>>(out2, Kc1, bc1, gc1, bb1, c1T);
  convT_mfma<5, 2, 512, 0><<<dim3(16, 32), 256, 0, stream>>>(
      c1T, Wr2B, bc2, gc2, bb2, c2T, nullptr);
  avgpool2_bf<<<1024, 256, 0, stream>>>(c2T, p2T, 256, 262144);
  convT_mfma<7, 3, 256, 1><<<dim3(8, 32), 256, 0, stream>>>(
      p2T, Wr3B, bc3, gc3, bb3, nullptr, c3T);
  pool3_transpose<<<2048, 256, 0, stream>>>(c3T, p3R);
  fc1_kernel<<<8192, 256, 0, stream>>>(p3R, Wf1, bf1, g4, b4, f1);
  fc2_kernel<<<4096, 256, 0, stream>>>(f1, Wf2, bf2, g5, b5, f2);
  fc3_kernel<<<1, 64, 0, stream>>>(f2, Wf3, bf3, out_f);
}

// Round 8
// 614.800 us; speedup vs baseline: 6.5045x; 1.1490x over previous
//
#include <hip/hip_runtime.h>
#include <math.h>

// T=4096, M=512, NH=8, HD=64, FF=2048, NL=2, NI=256 (16 tok/seg), NO=32 (8 seg/outer)

typedef float f32x4 __attribute__((ext_vector_type(4)));
typedef __bf16 bf16x8 __attribute__((ext_vector_type(8)));

__device__ __forceinline__ unsigned short f2bf(float x) {
  unsigned int u = __builtin_bit_cast(unsigned int, x);
  u += 0x7FFFu + ((u >> 16) & 1u);
  return (unsigned short)(u >> 16);
}
__device__ __forceinline__ float bf2f(unsigned short u) {
  unsigned int x = ((unsigned int)u) << 16;
  return __builtin_bit_cast(float, x);
}
// pack two f32 -> two bf16 (RTNE) in one instruction
__device__ __forceinline__ unsigned int pk_bf16(float a, float b) {
  unsigned int r;
  asm("v_cvt_pk_bf16_f32 %0, %1, %2" : "=v"(r) : "v"(a), "v"(b));
  return r;
}

__device__ __forceinline__ float wave_sum64(float v) {
#pragma unroll
  for (int o = 32; o > 0; o >>= 1) v += __shfl_xor(v, o);
  return v;
}

// XOR swizzle for LDS tiles with 128-byte rows (64 bf16/row).
__device__ __forceinline__ int swz(int byte) {
  return byte ^ (((byte >> 7) & 7) << 4);
}
// XOR swizzle for LDS tiles with 256-byte rows (128 bf16/row).
__device__ __forceinline__ int swz256(int byte) {
  return byte ^ (((byte >> 8) & 7) << 4);
}

// ============ bf16 MFMA GEMM: C[M,N] = act(A[M,K] @ B[N,K]^T + bias) ============
// ACT: 0 none, 1 relu, 2 tanh, 3 sigmoid, 4 col<128?tanh:sigmoid (fused gate)
// Software-prefetch: next K-tile's global loads issue right after LDS-ready
// barrier, hiding HBM latency under the MFMA phase. Bit-exact vs non-prefetch.
template<int ACT, int OUTBF>
__global__ __launch_bounds__(256) void mgemm(
    const unsigned short* __restrict__ A, const unsigned short* __restrict__ B,
    const float* __restrict__ bias, float* __restrict__ Cf,
    unsigned short* __restrict__ Cb, int M, int N, int K)
{
  __shared__ __align__(16) unsigned short As[128 * 64];
  __shared__ __align__(16) unsigned short Bs[128 * 64];
  const int tid = threadIdx.x;
  const int wid = tid >> 6, lane = tid & 63;
  const int wm = wid >> 1, wn = wid & 1;
  const int l15 = lane & 15, l4 = lane >> 4;
  const int m0 = blockIdx.y * 128, n0 = blockIdx.x * 128;
  const int srow = tid >> 3;
  const int scol = (tid & 7) * 8;

  f32x4 acc[4][4] = {};

  bf16x8 ra[4], rb[4];
#pragma unroll
  for (int i = 0; i < 4; i++) {
    ra[i] = *(const bf16x8*)&A[(size_t)(m0 + srow + i * 32) * K + scol];
    rb[i] = *(const bf16x8*)&B[(size_t)(n0 + srow + i * 32) * K + scol];
  }

  for (int k0 = 0; k0 < K; k0 += 64) {
    __syncthreads();   // all waves done reading previous LDS tile
#pragma unroll
    for (int i = 0; i < 4; i++) {
      int byte = (srow + i * 32) * 128 + scol * 2;
      *(bf16x8*)((char*)As + swz(byte)) = ra[i];
      *(bf16x8*)((char*)Bs + swz(byte)) = rb[i];
    }
    __syncthreads();   // LDS ready
    if (k0 + 64 < K) { // prefetch next tile; latency hides under MFMA below
#pragma unroll
      for (int i = 0; i < 4; i++) {
        ra[i] = *(const bf16x8*)&A[(size_t)(m0 + srow + i * 32) * K + k0 + 64 + scol];
        rb[i] = *(const bf16x8*)&B[(size_t)(n0 + srow + i * 32) * K + k0 + 64 + scol];
      }
    }
#pragma unroll
    for (int kc = 0; kc < 2; kc++) {
      bf16x8 af[4], bf_[4];
#pragma unroll
      for (int i = 0; i < 4; i++) {
        int byteA = (wm * 64 + i * 16 + l15) * 128 + kc * 64 + l4 * 16;
        af[i] = *(const bf16x8*)((const char*)As + swz(byteA));
        int byteB = (wn * 64 + i * 16 + l15) * 128 + kc * 64 + l4 * 16;
        bf_[i] = *(const bf16x8*)((const char*)Bs + swz(byteB));
      }
#pragma unroll
      for (int i = 0; i < 4; i++)
#pragma unroll
        for (int j = 0; j < 4; j++)
          acc[i][j] = __builtin_amdgcn_mfma_f32_16x16x32_bf16(af[i], bf_[j], acc[i][j], 0, 0, 0);
    }
  }
#pragma unroll
  for (int i = 0; i < 4; i++) {
#pragma unroll
    for (int j = 0; j < 4; j++) {
      int col = n0 + wn * 64 + j * 16 + l15;
      float bv = bias[col];
#pragma unroll
      for (int r = 0; r < 4; r++) {
        int row = m0 + wm * 64 + i * 16 + l4 * 4 + r;
        float x = acc[i][j][r] + bv;
        if (ACT == 1) x = fmaxf(x, 0.f);
        if (ACT == 2) x = tanhf(x);
        if (ACT == 3) x = 1.f / (1.f + expf(-x));
        if (ACT == 4) x = (col < 128) ? tanhf(x) : (1.f / (1.f + expf(-x)));
        if (OUTBF) Cb[(size_t)row * N + col] = f2bf(x);
        else       Cf[(size_t)row * N + col] = x;
      }
    }
  }
}

// ============ MFMA flash attention (swapped operands: lane-local softmax) ============
// EXACT round-3 numerics (twice-passed): always-rescale online softmax, __expf,
// scalar VTs staging. Only change: K/V global loads for kt+1 issue after the
// LDS-ready barrier (bit-exact prefetch).
__global__ __launch_bounds__(256) void attn_mfma(
    const unsigned short* __restrict__ qkv, unsigned short* __restrict__ O)
{
  __shared__ __align__(16) unsigned short Ks[64 * 64];   // [k][d]   swizzled
  __shared__ __align__(16) unsigned short VTs[64 * 64];  // [d][k]   swizzled
  __shared__ __align__(16) unsigned short Ps[64 * 64];   // [q][k]   swizzled
  const int tid = threadIdx.x;
  const int w = tid >> 6, lane = tid & 63;
  const int l15 = lane & 15, l4 = lane >> 4;
  const int h = blockIdx.y, qt = blockIdx.x;
  const float C = 0.18033688011112042f;   // 0.125 * log2(e)

  // Q fragment (B operand for S^T: col = q = l15)
  bf16x8 qf[2];
#pragma unroll
  for (int kc = 0; kc < 2; kc++)
    qf[kc] = *(const bf16x8*)&qkv[(size_t)(qt * 64 + w * 16 + l15) * 1536 + h * 64 + kc * 32 + l4 * 8];

  f32x4 oaccT[4] = {};
  float m = -1e30f, l = 0.f;

  const int sr = tid >> 3;
  const int sc = (tid & 7) * 8;
  const int vk = tid & 63;
  const int vd0 = (tid >> 6) * 8;

  const unsigned short* kp0 = qkv + (size_t)sr * 1536 + 512 + h * 64 + sc;
  const unsigned short* kp1 = kp0 + 32 * 1536;
  const unsigned short* vp0 = qkv + (size_t)vk * 1536 + 1024 + h * 64 + vd0;
  const unsigned short* vp1 = vp0 + 32;   // same k row, d+32

  bf16x8 rk0 = *(const bf16x8*)kp0;
  bf16x8 rk1 = *(const bf16x8*)kp1;
  bf16x8 rv0 = *(const bf16x8*)vp0;
  bf16x8 rv1 = *(const bf16x8*)vp1;

  for (int kt = 0; kt < 64; kt++) {
    __syncthreads();   // previous tile fully consumed
    {
      int b0 = sr * 128 + sc * 2;
      *(bf16x8*)((char*)Ks + swz(b0)) = rk0;
      int b1 = (sr + 32) * 128 + sc * 2;
      *(bf16x8*)((char*)Ks + swz(b1)) = rk1;
      union { bf16x8 v; unsigned short u[8]; } c0, c1;
      c0.v = rv0; c1.v = rv1;
#pragma unroll
      for (int j = 0; j < 8; j++) {
        int bb0 = (vd0 + j) * 128 + vk * 2;
        *(unsigned short*)((char*)VTs + swz(bb0)) = c0.u[j];
        int bb1 = (vd0 + 32 + j) * 128 + vk * 2;
        *(unsigned short*)((char*)VTs + swz(bb1)) = c1.u[j];
      }
    }
    __syncthreads();   // LDS ready
    if (kt < 63) {     // prefetch next tile (bit-exact; hides HBM latency)
      kp0 += 64 * 1536; kp1 += 64 * 1536; vp0 += 64 * 1536; vp1 += 64 * 1536;
      rk0 = *(const bf16x8*)kp0;
      rk1 = *(const bf16x8*)kp1;
      rv0 = *(const bf16x8*)vp0;
      rv1 = *(const bf16x8*)vp1;
    }

    // S^T = mfma(A=K, B=Q): lane holds st[nb][r] = S[k=nb*16+l4*4+r][q=w*16+l15]
    f32x4 st[4] = {};
#pragma unroll
    for (int kc = 0; kc < 2; kc++) {
#pragma unroll
      for (int nb = 0; nb < 4; nb++) {
        int byte = (nb * 16 + l15) * 128 + kc * 64 + l4 * 16;
        bf16x8 kf = *(const bf16x8*)((const char*)Ks + swz(byte));
        st[nb] = __builtin_amdgcn_mfma_f32_16x16x32_bf16(kf, qf[kc], st[nb], 0, 0, 0);
      }
    }

    // lane-local online softmax (round-3 exact: always rescale)
    float tm = -1e30f;
#pragma unroll
    for (int nb = 0; nb < 4; nb++)
#pragma unroll
      for (int r = 0; r < 4; r++) tm = fmaxf(tm, st[nb][r]);
    tm = fmaxf(tm, __shfl_xor(tm, 16));
    tm = fmaxf(tm, __shfl_xor(tm, 32));
    float mn = fmaxf(m, tm);
    float alpha = exp2f((m - mn) * C);
    float e[4][4];
    float ps = 0.f;
#pragma unroll
    for (int nb = 0; nb < 4; nb++)
#pragma unroll
      for (int r = 0; r < 4; r++) {
        e[nb][r] = exp2f((st[nb][r] - mn) * C);
        ps += e[nb][r];
      }
    ps += __shfl_xor(ps, 16);
    ps += __shfl_xor(ps, 32);
    l = l * alpha + ps;
    m = mn;
#pragma unroll
    for (int nb = 0; nb < 4; nb++) oaccT[nb] *= alpha;

    // P rows -> Ps[q][k] (lane writes its own q-row; wave-local, no barrier)
#pragma unroll
    for (int nb = 0; nb < 4; nb++) {
      uint2 pr;
      pr.x = pk_bf16(e[nb][0], e[nb][1]);
      pr.y = pk_bf16(e[nb][2], e[nb][3]);
      int byte = (w * 16 + l15) * 128 + (nb * 16 + l4 * 4) * 2;
      *(uint2*)((char*)Ps + swz(byte)) = pr;
    }

    // O^T += mfma(A=V^T, B=P)
#pragma unroll
    for (int kc = 0; kc < 2; kc++) {
      int bp = (w * 16 + l15) * 128 + kc * 64 + l4 * 16;
      bf16x8 pb = *(const bf16x8*)((const char*)Ps + swz(bp));
#pragma unroll
      for (int nb = 0; nb < 4; nb++) {
        int bv = (nb * 16 + l15) * 128 + kc * 64 + l4 * 16;
        bf16x8 vf = *(const bf16x8*)((const char*)VTs + swz(bv));
        oaccT[nb] = __builtin_amdgcn_mfma_f32_16x16x32_bf16(vf, pb, oaccT[nb], 0, 0, 0);
      }
    }
  }

  // epilogue: in-lane 1/l, packed 8-byte stores
  float linv = 1.f / l;
  int row = qt * 64 + w * 16 + l15;
#pragma unroll
  for (int nb = 0; nb < 4; nb++) {
    uint2 ov;
    ov.x = pk_bf16(oaccT[nb][0] * linv, oaccT[nb][1] * linv);
    ov.y = pk_bf16(oaccT[nb][2] * linv, oaccT[nb][3] * linv);
    int col = h * 64 + nb * 16 + l4 * 4;
    *(uint2*)&O[(size_t)row * 512 + col] = ov;
  }
}

// ---------------- fp32 GEMM (tiny stage-2 gating) ----------------
template<int ACT>
__global__ __launch_bounds__(256) void gemm_bias(
    const float* __restrict__ A, const float* __restrict__ B,
    const float* __restrict__ bias, float* __restrict__ C,
    int M, int N, int K)
{
  __shared__ float As[16][68];
  __shared__ float Bs[16][68];
  const int tid = threadIdx.x;
  const int tx = tid & 15, ty = tid >> 4;
  const int m0 = blockIdx.y * 64, n0 = blockIdx.x * 64;
  const int lr = tid >> 2;
  const int lk = (tid & 3) * 4;
  float acc[4][4] = {};
  for (int k0 = 0; k0 < K; k0 += 16) {
    __syncthreads();
    float4 av = *(const float4*)&A[(size_t)(m0 + lr) * K + k0 + lk];
    float4 bv = *(const float4*)&B[(size_t)(n0 + lr) * K + k0 + lk];
    As[lk + 0][lr] = av.x; As[lk + 1][lr] = av.y; As[lk + 2][lr] = av.z; As[lk + 3][lr] = av.w;
    Bs[lk + 0][lr] = bv.x; Bs[lk + 1][lr] = bv.y; Bs[lk + 2][lr] = bv.z; Bs[lk + 3][lr] = bv.w;
    __syncthreads();
#pragma unroll
    for (int k = 0; k < 16; k++) {
      float a[4], b[4];
#pragma unroll
      for (int i = 0; i < 4; i++) a[i] = As[k][ty * 4 + i];
#pragma unroll
      for (int j = 0; j < 4; j++) b[j] = Bs[k][tx * 4 + j];
#pragma unroll
      for (int i = 0; i < 4; i++)
#pragma unroll
        for (int j = 0; j < 4; j++)
          acc[i][j] = fmaf(a[i], b[j], acc[i][j]);
    }
  }
#pragma unroll
  for (int i = 0; i < 4; i++)
#pragma unroll
    for (int j = 0; j < 4; j++) {
      float x = acc[i][j] + bias[n0 + tx * 4 + j];
      if (ACT == 1) x = fmaxf(x, 0.f);
      if (ACT == 2) x = tanhf(x);
      if (ACT == 3) x = 1.f / (1.f + expf(-x));
      C[(size_t)(m0 + ty * 4 + i) * N + n0 + tx * 4 + j] = x;
    }
}

// ---------------- LayerNorm(x + res), writes f32 + bf16 ----------------
__global__ __launch_bounds__(64) void residual_ln(
    const float* __restrict__ x, const float* __restrict__ res,
    const float* __restrict__ g, const float* __restrict__ b,
    float* __restrict__ out, unsigned short* __restrict__ out_bf)
{
  const int row = blockIdx.x, lane = threadIdx.x;
  const float* xp = x + (size_t)row * 512;
  const float* rp = res + (size_t)row * 512;
  float v[8];
  float s = 0.f;
#pragma unroll
  for (int i = 0; i < 8; i++) { v[i] = xp[lane + 64 * i] + rp[lane + 64 * i]; s += v[i]; }
  s = wave_sum64(s);
  float mu = s * (1.f / 512.f);
  float vs = 0.f;
#pragma unroll
  for (int i = 0; i < 8; i++) { float d = v[i] - mu; vs = fmaf(d, d, vs); }
  vs = wave_sum64(vs);
  float rstd = rsqrtf(vs * (1.f / 512.f) + 1e-5f);
  float* op = out + (size_t)row * 512;
  unsigned short* ob = out_bf + (size_t)row * 512;
#pragma unroll
  for (int i = 0; i < 8; i++) {
    float y = (v[i] - mu) * rstd * g[lane + 64 * i] + b[lane + 64 * i];
    op[lane + 64 * i] = y;
    ob[lane + 64 * i] = f2bf(y);
  }
}

// ---------------- multi-job f32 -> bf16 cast (one launch per batch) ----------------
struct CastJobs {
  const float* src[6];
  unsigned short* dst[6];
  int n4[6];
  int njobs;
};

__global__ void cast_multi(CastJobs J)
{
  for (int j = 0; j < J.njobs; j++) {
    const float4* s = (const float4*)J.src[j];
    ushort4* d = (ushort4*)J.dst[j];
    int n = J.n4[j];
    for (int i = blockIdx.x * 256 + threadIdx.x; i < n; i += gridDim.x * 256) {
      float4 v = s[i];
      ushort4 u;
      u.x = f2bf(v.x); u.y = f2bf(v.y); u.z = f2bf(v.z); u.w = f2bf(v.w);
      d[i] = u;
    }
  }
}

__global__ void init_h(const float* __restrict__ in, float* __restrict__ hf,
                       unsigned short* __restrict__ hb, int n4)
{
  int i = blockIdx.x * 256 + threadIdx.x;
  if (i < n4) {
    float4 v = ((const float4*)in)[i];
    ((float4*)hf)[i] = v;
    ushort4 u;
    u.x = f2bf(v.x); u.y = f2bf(v.y); u.z = f2bf(v.z); u.w = f2bf(v.w);
    ((ushort4*)hb)[i] = u;
  }
}

// ---------------- A[t] = sum_l Gv*Gu*Ww + bw ----------------
__global__ __launch_bounds__(128) void gate_dot(
    const float* __restrict__ Gv, const float* __restrict__ Gu, int ld,
    const float* __restrict__ Ww, const float* __restrict__ bw,
    float* __restrict__ A)
{
  const int t = blockIdx.x, l = threadIdx.x;
  float v = Gv[(size_t)t * ld + l] * Gu[(size_t)t * ld + l] * Ww[l];
  v = wave_sum64(v);
  __shared__ float red[2];
  if ((l & 63) == 0) red[l >> 6] = v;
  __syncthreads();
  if (l == 0) A[t] = red[0] + red[1] + bw[0];
}

// ------- contiguous-segment softmax + weighted pooled sum (D=512) -------
__global__ __launch_bounds__(256) void seg_pool(
    const float* __restrict__ A, const float* __restrict__ X,
    float* __restrict__ w_out, float* __restrict__ out, int seg_len)
{
  const int s = blockIdx.x, tid = threadIdx.x;
  __shared__ float ws[16];
  if (tid < 64) {
    float a = (tid < seg_len) ? A[s * seg_len + tid] : -1e30f;
    float mx = a;
#pragma unroll
    for (int o = 1; o < 16; o <<= 1) mx = fmaxf(mx, __shfl_xor(mx, o));
    float e = (tid < seg_len) ? expf(a - mx) : 0.f;
    float se = e;
#pragma unroll
    for (int o = 1; o < 16; o <<= 1) se += __shfl_xor(se, o);
    if (tid < seg_len) {
      float w = e / se;
      ws[tid] = w;
      w_out[s * seg_len + tid] = w;
    }
  }
  __syncthreads();
  for (int d = tid; d < 512; d += 256) {
    float acc = 0.f;
    for (int i = 0; i < seg_len; i++)
      acc = fmaf(ws[i], X[(size_t)(s * seg_len + i) * 512 + d], acc);
    out[(size_t)s * 512 + d] = acc;
  }
}

// ======================= CNN head (channels-last [n][L][C=128]) =======================

__global__ void conv1_bnT(
    const float* __restrict__ x, const float* __restrict__ K4,
    const float* __restrict__ bias, const float* __restrict__ g,
    const float* __restrict__ bb, unsigned short* __restrict__ y)
{
  int idx = blockIdx.x * 256 + threadIdx.x;   // (n*512+i)*128+o
  int o = idx & 127, i = (idx >> 7) & 511, n = idx >> 16;
  const float* xp = x + n * 512;
  float acc = bias[o];
#pragma unroll
  for (int k = 0; k < 4; k++) {
    int p = i + k - 1;
    float xv = (p >= 0 && p < 512) ? xp[p] : 0.f;
    acc = fmaf(xv, K4[o * 4 + k], acc);
  }
  float sc = g[o] * rsqrtf(1.f + 1e-5f);
  y[idx] = f2bf(fmaxf(fmaf(acc, sc, bb[o]), 0.f));
}

__global__ void reorder_w(const float* __restrict__ Kc, unsigned short* __restrict__ Wr,
                          int KS, int total)
{
  int idx = blockIdx.x * 256 + threadIdx.x;
  if (idx < total) {
    int c = idx & 127;
    int kk = (idx >> 7) % KS;
    int o = idx / (128 * KS);
    Wr[idx] = f2bf(Kc[(o * 128 + c) * KS + kk]);
  }
}

template<int KS, int PAD, int LEN, int OUTF>
__global__ __launch_bounds__(256) void convT_mfma(
    const unsigned short* __restrict__ X, const unsigned short* __restrict__ Wr,
    const float* __restrict__ bias, const float* __restrict__ g,
    const float* __restrict__ bb,
    unsigned short* __restrict__ Yb, float* __restrict__ Yf)
{
  constexpr int ROWS = 64 + KS - 1;
  __shared__ __align__(16) unsigned short XT[ROWS * 128];
  const int tid = threadIdx.x;
  const int w = tid >> 6, lane = tid & 63;
  const int l15 = lane & 15, l4 = lane >> 4;
  const int i0 = (blockIdx.x >> 1) * 64;
  const int o0 = (blockIdx.x & 1) * 64;
  const int n = blockIdx.y;

  {
    const int c = (tid & 15) * 8;
    for (int r = tid >> 4; r < ROWS; r += 16) {
      int gi = i0 - PAD + r;
      bf16x8 v = {};
      if (gi >= 0 && gi < LEN)
        v = *(const bf16x8*)&X[((size_t)n * LEN + gi) * 128 + c];
      int byte = r * 256 + c * 2;
      *(bf16x8*)((char*)XT + swz256(byte)) = v;
    }
  }
  __syncthreads();

  f32x4 acc[4] = {};
#pragma unroll
  for (int kk = 0; kk < KS; kk++) {
#pragma unroll
    for (int cc = 0; cc < 4; cc++) {
      int r = w * 16 + l15 + kk;
      int byte = r * 256 + cc * 64 + l4 * 16;
      bf16x8 a = *(const bf16x8*)((const char*)XT + swz256(byte));
      bf16x8 bfr[4];
#pragma unroll
      for (int nb = 0; nb < 4; nb++)
        bfr[nb] = *(const bf16x8*)&Wr[(size_t)(o0 + nb * 16 + l15) * (KS * 128) +
                                      kk * 128 + cc * 32 + l4 * 8];
#pragma unroll
      for (int nb = 0; nb < 4; nb++)
        acc[nb] = __builtin_amdgcn_mfma_f32_16x16x32_bf16(a, bfr[nb], acc[nb], 0, 0, 0);
    }
  }

#pragma unroll
  for (int nb = 0; nb < 4; nb++) {
    int o = o0 + nb * 16 + l15;
    float sc = g[o] * rsqrtf(1.f + 1e-5f);
    float bs = bias[o], bo_ = bb[o];
#pragma unroll
    for (int rr = 0; rr < 4; rr++) {
      int i = i0 + w * 16 + l4 * 4 + rr;
      float v = fmaxf(fmaf(acc[nb][rr] + bs, sc, bo_), 0.f);
      size_t oidx = ((size_t)n * LEN + i) * 128 + o;
      if (OUTF) Yf[oidx] = v;
      else Yb[oidx] = f2bf(v);
    }
  }
}

__global__ void avgpool2_bf(const unsigned short* __restrict__ x,
                            unsigned short* __restrict__ y, int nI, int nTot4)
{
  int j = blockIdx.x * 256 + threadIdx.x;
  if (j >= nTot4) return;
  int cq = j & 31;
  int i = (j >> 5) % nI;
  int n = j / (nI * 32);
  const ushort4* a = (const ushort4*)&x[(((size_t)n * nI + i) * 2) * 128 + cq * 4];
  const ushort4* b = (const ushort4*)&x[(((size_t)n * nI + i) * 2 + 1) * 128 + cq * 4];
  ushort4 ua = *a, ub = *b;
  ushort4 r;
  r.x = f2bf(0.5f * (bf2f(ua.x) + bf2f(ub.x)));
  r.y = f2bf(0.5f * (bf2f(ua.y) + bf2f(ub.y)));
  r.z = f2bf(0.5f * (bf2f(ua.z) + bf2f(ub.z)));
  r.w = f2bf(0.5f * (bf2f(ua.w) + bf2f(ub.w)));
  ((ushort4*)y)[j] = r;
}

__global__ void pool3_transpose(const float* __restrict__ x, float* __restrict__ y)
{
  int j = blockIdx.x * 256 + threadIdx.x;   // n*16384 + c*128 + i
  if (j >= 524288) return;
  int i = j & 127, c = (j >> 7) & 127, n = j >> 14;
  const float* b = x + ((size_t)n * 256 + 2 * i) * 128 + c;
  y[j] = 0.5f * (b[0] + b[128]);
}

__global__ __launch_bounds__(256) void fc1_kernel(
    const float* __restrict__ x, const float* __restrict__ W,
    const float* __restrict__ bias, const float* __restrict__ g,
    const float* __restrict__ bb, float* __restrict__ y)
{
  int o = blockIdx.x & 255, n = blockIdx.x >> 8;
  const float* xp = x + (size_t)n * 16384;
  const float* wp = W + (size_t)o * 16384;
  float s = 0.f;
  for (int j = threadIdx.x * 4; j < 16384; j += 1024) {
    float4 a = *(const float4*)(xp + j);
    float4 b = *(const float4*)(wp + j);
    s = fmaf(a.x, b.x, s); s = fmaf(a.y, b.y, s);
    s = fmaf(a.z, b.z, s); s = fmaf(a.w, b.w, s);
  }
  s = wave_sum64(s);
  __shared__ float red[4];
  if ((threadIdx.x & 63) == 0) red[threadIdx.x >> 6] = s;
  __syncthreads();
  if (threadIdx.x == 0) {
    float v = red[0] + red[1] + red[2] + red[3] + bias[o];
    v = fmaxf(v, 0.f);
    y[n * 256 + o] = fmaf(v, g[o] * rsqrtf(1.f + 1e-5f), bb[o]);
  }
}

__global__ __launch_bounds__(256) void fc2_kernel(
    const float* __restrict__ x, const float* __restrict__ W,
    const float* __restrict__ bias, const float* __restrict__ g,
    const float* __restrict__ bb, float* __restrict__ y)
{
  int o = blockIdx.x & 127, n = blockIdx.x >> 7;
  float s = x[n * 256 + threadIdx.x] * W[o * 256 + threadIdx.x];
  s = wave_sum64(s);
  __shared__ float red[4];
  if ((threadIdx.x & 63) == 0) red[threadIdx.x >> 6] = s;
  __syncthreads();
  if (threadIdx.x == 0) {
    float v = red[0] + red[1] + red[2] + red[3] + bias[o];
    v = fmaxf(v, 0.f);
    y[n * 128 + o] = fmaf(v, g[o] * rsqrtf(1.f + 1e-5f), bb[o]);
  }
}

__global__ __launch_bounds__(64) void fc3_kernel(
    const float* __restrict__ x, const float* __restrict__ W,
    const float* __restrict__ bias, float* __restrict__ out)
{
  int n = threadIdx.x;
  if (n < 32) {
    float s = bias[0];
    for (int k = 0; k < 128; k++) s = fmaf(x[n * 128 + k], W[k], s);
    float p = 1.f / (1.f + expf(-s));
    out[n] = p;
    out[32 + n] = (p >= 0.5f) ? 1.f : 0.f;
  }
}

extern "C" void kernel_launch(void* const* d_in, const int* in_sizes, int n_in,
                              void* d_out, int out_size, void* d_ws, size_t ws_size,
                              hipStream_t stream)
{
  const float* datas = (const float*)d_in[0];
  const float* Wqkv = (const float*)d_in[6];
  const float* bqkv = (const float*)d_in[7];
  const float* Wo   = (const float*)d_in[8];
  const float* bo   = (const float*)d_in[9];
  const float* ln1g = (const float*)d_in[10];
  const float* ln1b = (const float*)d_in[11];
  const float* W1   = (const float*)d_in[12];
  const float* b1   = (const float*)d_in[13];
  const float* W2   = (const float*)d_in[14];
  const float* b2   = (const float*)d_in[15];
  const float* ln2g = (const float*)d_in[16];
  const float* ln2b = (const float*)d_in[17];
  const float* Wv1  = (const float*)d_in[18];
  const float* bv1  = (const float*)d_in[19];
  const float* Wu1  = (const float*)d_in[20];
  const float* bu1  = (const float*)d_in[21];
  const float* Ww1  = (const float*)d_in[22];
  const float* bw1  = (const float*)d_in[23];
  const float* Wv2  = (const float*)d_in[24];
  const float* bv2  = (const float*)d_in[25];
  const float* Wu2  = (const float*)d_in[26];
  const float* bu2  = (const float*)d_in[27];
  const float* Ww2  = (const float*)d_in[28];
  const float* bw2  = (const float*)d_in[29];
  const float* Kc1  = (const float*)d_in[30];
  const float* bc1  = (const float*)d_in[31];
  const float* gc1  = (const float*)d_in[32];
  const float* bb1  = (const float*)d_in[33];
  const float* Kc2  = (const float*)d_in[34];
  const float* bc2  = (const float*)d_in[35];
  const float* gc2  = (const float*)d_in[36];
  const float* bb2  = (const float*)d_in[37];
  const float* Kc3  = (const float*)d_in[38];
  const float* bc3  = (const float*)d_in[39];
  const float* gc3  = (const float*)d_in[40];
  const float* bb3  = (const float*)d_in[41];
  const float* Wf1  = (const float*)d_in[42];
  const float* bf1  = (const float*)d_in[43];
  const float* g4   = (const float*)d_in[44];
  const float* b4   = (const float*)d_in[45];
  const float* Wf2  = (const float*)d_in[46];
  const float* bf2  = (const float*)d_in[47];
  const float* g5   = (const float*)d_in[48];
  const float* b5   = (const float*)d_in[49];
  const float* Wf3  = (const float*)d_in[50];
  const float* bf3  = (const float*)d_in[51];

  float* ws = (float*)d_ws;
  float* h_f32 = ws;                              // 2,097,152 f
  float* R2f   = ws + 2097152;                    // 6,291,456 f
  unsigned short* h_bf = (unsigned short*)(ws + 8388608);   // 2,097,152 ush
  unsigned short* wbuf = (unsigned short*)(ws + 9437184);   // 3,473,408 ush
  float* biasG = ws + 11173888;                   // 256 f   (total ~44.7 MB)

  unsigned short* qkv_bf = (unsigned short*)R2f;
  unsigned short* O_bf   = (unsigned short*)(R2f + 3145728);
  unsigned short* ff1_bf = (unsigned short*)R2f;
  float* projf = R2f + 4194304;

  unsigned short* WqkvB = wbuf;                 // 786,432 (per-layer reuse)
  unsigned short* WoB   = wbuf + 786432;        // 262,144
  unsigned short* W1B   = wbuf + 1048576;       // 1,048,576
  unsigned short* W2B   = wbuf + 2097152;       // 1,048,576
  unsigned short* WvuB  = wbuf + 3145728;       // 131,072 (persistent tail)
  unsigned short* Wr2B  = wbuf + 3276800;       // 81,920
  unsigned short* Wr3B  = wbuf + 3358720;       // 114,688

  float* out_f = (float*)d_out;

  init_h<<<2048, 256, 0, stream>>>(datas, h_f32, h_bf, 524288);
  reorder_w<<<320, 256, 0, stream>>>(Kc2, Wr2B, 5, 81920);
  reorder_w<<<448, 256, 0, stream>>>(Kc3, Wr3B, 7, 114688);
  hipMemcpyAsync(biasG, bv1, 128 * sizeof(float), hipMemcpyDeviceToDevice, stream);
  hipMemcpyAsync(biasG + 128, bu1, 128 * sizeof(float), hipMemcpyDeviceToDevice, stream);

  for (int l = 0; l < 2; l++) {
    CastJobs J{};
    J.src[0] = Wqkv + (size_t)l * 786432;  J.dst[0] = WqkvB; J.n4[0] = 196608;
    J.src[1] = Wo   + (size_t)l * 262144;  J.dst[1] = WoB;   J.n4[1] = 65536;
    J.src[2] = W1   + (size_t)l * 1048576; J.dst[2] = W1B;   J.n4[2] = 262144;
    J.src[3] = W2   + (size_t)l * 1048576; J.dst[3] = W2B;   J.n4[3] = 262144;
    J.njobs = 4;
    if (l == 0) {
      J.src[4] = Wv1; J.dst[4] = WvuB;         J.n4[4] = 16384;
      J.src[5] = Wu1; J.dst[5] = WvuB + 65536; J.n4[5] = 16384;
      J.njobs = 6;
    }
    cast_multi<<<512, 256, 0, stream>>>(J);

    mgemm<0, 1><<<dim3(12, 32), 256, 0, stream>>>(
        h_bf, WqkvB, bqkv + (size_t)l * 1536, nullptr, qkv_bf, 4096, 1536, 512);
    attn_mfma<<<dim3(64, 8), 256, 0, stream>>>(qkv_bf, O_bf);
    mgemm<0, 0><<<dim3(4, 32), 256, 0, stream>>>(
        O_bf, WoB, bo + (size_t)l * 512, projf, nullptr, 4096, 512, 512);
    residual_ln<<<4096, 64, 0, stream>>>(projf, h_f32, ln1g + l * 512, ln1b + l * 512,
                                         h_f32, h_bf);
    mgemm<1, 1><<<dim3(16, 32), 256, 0, stream>>>(
        h_bf, W1B, b1 + (size_t)l * 2048, nullptr, ff1_bf, 4096, 2048, 512);
    mgemm<0, 0><<<dim3(4, 32), 256, 0, stream>>>(
        ff1_bf, W2B, b2 + (size_t)l * 512, projf, nullptr, 4096, 512, 2048);
    residual_ln<<<4096, 64, 0, stream>>>(projf, h_f32, ln2g + l * 512, ln2b + l * 512,
                                         h_f32, h_bf);
  }

  // ---- gated pooling (stage 1: fused tanh/sigmoid GEMM, N=256) ----
  float* G    = R2f;              // 4096 x 256
  float* A1   = R2f + 1048576;
  float* out1 = R2f + 1052672;
  float* Gv2  = R2f + 1183744;
  float* Gu2  = R2f + 1216512;
  float* A2   = R2f + 1249280;
  float* out2 = R2f + 1249536;

  mgemm<4, 0><<<dim3(2, 32), 256, 0, stream>>>(h_bf, WvuB, biasG, G, nullptr, 4096, 256, 512);
  gate_dot<<<4096, 128, 0, stream>>>(G, G + 128, 256, Ww1, bw1, A1);
  seg_pool<<<256, 256, 0, stream>>>(A1, h_f32, out_f + 64, out1, 16);

  gemm_bias<2><<<dim3(2, 4), 256, 0, stream>>>(out1, Wv2, bv2, Gv2, 256, 128, 512);
  gemm_bias<3><<<dim3(2, 4), 256, 0, stream>>>(out1, Wu2, bu2, Gu2, 256, 128, 512);
  gate_dot<<<256, 128, 0, stream>>>(Gv2, Gu2, 128, Ww2, bw2, A2);
  seg_pool<<<32, 256, 0, stream>>>(A2, out1, out_f + 4160, out2, 8);

  // ---- CNN head, channels-last ----
  unsigned short* c1T = (unsigned short*)(R2f + 1310720);  // 2,097,152 ush
  unsigned short* c2T = (unsigned short*)(R2f + 2359296);  // 2,097,152 ush
  unsigned short* p2T = (unsigned short*)(R2f + 3407872);  // 1,048,576 ush
  float* c3T = R2f + 3932160;                              // 1,048,576 f
  float* p3R = R2f + 4980736;                              // 524,288 f
  float* f1  = R2f + 5505024;
  float* f2  = R2f + 5513216;

  conv1_bnT<<<8192, 256, 0, stream>>>(out2, Kc1, bc1, gc1, bb1, c1T);
  convT_mfma<5, 2, 512, 0><<<dim3(16, 32), 256, 0, stream>>>(
      c1T, Wr2B, bc2, gc2, bb2, c2T, nullptr);
  avgpool2_bf<<<1024, 256, 0, stream>>>(c2T, p2T, 256, 262144);
  convT_mfma<7, 3, 256, 1><<<dim3(8, 32), 256, 0, stream>>>(
      p2T, Wr3B, bc3, gc3, bb3, nullptr, c3T);
  pool3_transpose<<<2048, 256, 0, stream>>>(c3T, p3R);
  fc1_kernel<<<8192, 256, 0, stream>>>(p3R, Wf1, bf1, g4, b4, f1);
  fc2_kernel<<<4096, 256, 0, stream>>>(f1, Wf2, bf2, g5, b5, f2);
  fc3_kernel<<<1, 64, 0, stream>>>(f2, Wf3, bf3, out_f);
}

// Round 9
// 608.473 us; speedup vs baseline: 6.5721x; 1.0104x over previous
//
#include <hip/hip_runtime.h>
#include <math.h>

// T=4096, M=512, NH=8, HD=64, FF=2048, NL=2, NI=256 (16 tok/seg), NO=32 (8 seg/outer)

typedef float f32x4 __attribute__((ext_vector_type(4)));
typedef __bf16 bf16x8 __attribute__((ext_vector_type(8)));

__device__ __forceinline__ unsigned short f2bf(float x) {
  unsigned int u = __builtin_bit_cast(unsigned int, x);
  u += 0x7FFFu + ((u >> 16) & 1u);
  return (unsigned short)(u >> 16);
}
__device__ __forceinline__ float bf2f(unsigned short u) {
  unsigned int x = ((unsigned int)u) << 16;
  return __builtin_bit_cast(float, x);
}
// pack two f32 -> two bf16 (RTNE) in one instruction
__device__ __forceinline__ unsigned int pk_bf16(float a, float b) {
  unsigned int r;
  asm("v_cvt_pk_bf16_f32 %0, %1, %2" : "=v"(r) : "v"(a), "v"(b));
  return r;
}

__device__ __forceinline__ float wave_sum64(float v) {
#pragma unroll
  for (int o = 32; o > 0; o >>= 1) v += __shfl_xor(v, o);
  return v;
}

// XOR swizzle for LDS tiles with 128-byte rows (64 bf16/row).
__device__ __forceinline__ int swz(int byte) {
  return byte ^ (((byte >> 7) & 7) << 4);
}
// XOR swizzle for LDS tiles with 256-byte rows (128 bf16/row).
__device__ __forceinline__ int swz256(int byte) {
  return byte ^ (((byte >> 8) & 7) << 4);
}

// ============ bf16 MFMA GEMM: C[M,N] = act(A[M,K] @ B[N,K]^T + bias) ============
// ACT: 0 none, 1 relu, 2 tanh, 3 sigmoid, 4 col<128?tanh:sigmoid (fused gate)
// VSPLIT: cols >= 1024 go to VT[col-1024][row] (bf16, packed 4-row stores) —
// same RTNE values, transposed layout for attention's V operand.
template<int ACT, int OUTBF, int VSPLIT>
__global__ __launch_bounds__(256) void mgemm(
    const unsigned short* __restrict__ A, const unsigned short* __restrict__ B,
    const float* __restrict__ bias, float* __restrict__ Cf,
    unsigned short* __restrict__ Cb, unsigned short* __restrict__ VT,
    int M, int N, int K)
{
  __shared__ __align__(16) unsigned short As[128 * 64];
  __shared__ __align__(16) unsigned short Bs[128 * 64];
  const int tid = threadIdx.x;
  const int wid = tid >> 6, lane = tid & 63;
  const int wm = wid >> 1, wn = wid & 1;
  const int l15 = lane & 15, l4 = lane >> 4;
  const int m0 = blockIdx.y * 128, n0 = blockIdx.x * 128;
  const int srow = tid >> 3;
  const int scol = (tid & 7) * 8;

  f32x4 acc[4][4] = {};

  bf16x8 ra[4], rb[4];
#pragma unroll
  for (int i = 0; i < 4; i++) {
    ra[i] = *(const bf16x8*)&A[(size_t)(m0 + srow + i * 32) * K + scol];
    rb[i] = *(const bf16x8*)&B[(size_t)(n0 + srow + i * 32) * K + scol];
  }

  for (int k0 = 0; k0 < K; k0 += 64) {
    __syncthreads();   // all waves done reading previous LDS tile
#pragma unroll
    for (int i = 0; i < 4; i++) {
      int byte = (srow + i * 32) * 128 + scol * 2;
      *(bf16x8*)((char*)As + swz(byte)) = ra[i];
      *(bf16x8*)((char*)Bs + swz(byte)) = rb[i];
    }
    __syncthreads();   // LDS ready
    if (k0 + 64 < K) { // prefetch next tile; latency hides under MFMA below
#pragma unroll
      for (int i = 0; i < 4; i++) {
        ra[i] = *(const bf16x8*)&A[(size_t)(m0 + srow + i * 32) * K + k0 + 64 + scol];
        rb[i] = *(const bf16x8*)&B[(size_t)(n0 + srow + i * 32) * K + k0 + 64 + scol];
      }
    }
#pragma unroll
    for (int kc = 0; kc < 2; kc++) {
      bf16x8 af[4], bf_[4];
#pragma unroll
      for (int i = 0; i < 4; i++) {
        int byteA = (wm * 64 + i * 16 + l15) * 128 + kc * 64 + l4 * 16;
        af[i] = *(const bf16x8*)((const char*)As + swz(byteA));
        int byteB = (wn * 64 + i * 16 + l15) * 128 + kc * 64 + l4 * 16;
        bf_[i] = *(const bf16x8*)((const char*)Bs + swz(byteB));
      }
#pragma unroll
      for (int i = 0; i < 4; i++)
#pragma unroll
        for (int j = 0; j < 4; j++)
          acc[i][j] = __builtin_amdgcn_mfma_f32_16x16x32_bf16(af[i], bf_[j], acc[i][j], 0, 0, 0);
    }
  }
#pragma unroll
  for (int i = 0; i < 4; i++) {
#pragma unroll
    for (int j = 0; j < 4; j++) {
      int col = n0 + wn * 64 + j * 16 + l15;
      float bv = bias[col];
      if (VSPLIT && col >= 1024) {
        // V third: packed 4-row store into VT[col-1024][row0..row0+3]
        float x0 = acc[i][j][0] + bv, x1 = acc[i][j][1] + bv;
        float x2 = acc[i][j][2] + bv, x3 = acc[i][j][3] + bv;
        uint2 pv;
        pv.x = pk_bf16(x0, x1);
        pv.y = pk_bf16(x2, x3);
        int row0 = m0 + wm * 64 + i * 16 + l4 * 4;
        *(uint2*)&VT[(size_t)(col - 1024) * 4096 + row0] = pv;
      } else {
#pragma unroll
        for (int r = 0; r < 4; r++) {
          int row = m0 + wm * 64 + i * 16 + l4 * 4 + r;
          float x = acc[i][j][r] + bv;
          if (ACT == 1) x = fmaxf(x, 0.f);
          if (ACT == 2) x = tanhf(x);
          if (ACT == 3) x = 1.f / (1.f + expf(-x));
          if (ACT == 4) x = (col < 128) ? tanhf(x) : (1.f / (1.f + expf(-x)));
          if (OUTBF) Cb[(size_t)row * N + col] = f2bf(x);
          else       Cf[(size_t)row * N + col] = x;
        }
      }
    }
  }
}

// ============ MFMA flash attention (swapped operands: lane-local softmax) ============
// Bit-identical numerics to the round-8 passing kernel. V now arrives via the
// HBM-transposed VT[h*64+d][t] buffer, so V staging is 2 coalesced loads +
// 2 swizzled b128 LDS writes (replaces 16 scalar writes + 16 extracts).
__global__ __launch_bounds__(256) void attn_mfma(
    const unsigned short* __restrict__ qkv, const unsigned short* __restrict__ VT,
    unsigned short* __restrict__ O)
{
  __shared__ __align__(16) unsigned short Ks[64 * 64];   // [k][d]   swizzled
  __shared__ __align__(16) unsigned short VTs[64 * 64];  // [d][k]   swizzled
  __shared__ __align__(16) unsigned short Ps[64 * 64];   // [q][k]   swizzled
  const int tid = threadIdx.x;
  const int w = tid >> 6, lane = tid & 63;
  const int l15 = lane & 15, l4 = lane >> 4;
  const int h = blockIdx.y, qt = blockIdx.x;
  const float C = 0.18033688011112042f;   // 0.125 * log2(e)

  // Q fragment (B operand for S^T: col = q = l15)
  bf16x8 qf[2];
#pragma unroll
  for (int kc = 0; kc < 2; kc++)
    qf[kc] = *(const bf16x8*)&qkv[(size_t)(qt * 64 + w * 16 + l15) * 1536 + h * 64 + kc * 32 + l4 * 8];

  f32x4 oaccT[4] = {};
  float m = -1e30f, l = 0.f;

  const int sr = tid >> 3;
  const int sc = (tid & 7) * 8;
  // V^T staging: thread -> (d row, 16-k chunk)
  const int vd = tid >> 2;            // 0..63
  const int vk0 = (tid & 3) * 16;     // 0,16,32,48

  const unsigned short* kp0 = qkv + (size_t)sr * 1536 + 512 + h * 64 + sc;
  const unsigned short* kp1 = kp0 + 32 * 1536;
  const unsigned short* vp = VT + (size_t)(h * 64 + vd) * 4096 + vk0;

  bf16x8 rk0 = *(const bf16x8*)kp0;
  bf16x8 rk1 = *(const bf16x8*)kp1;
  bf16x8 rv0 = *(const bf16x8*)vp;
  bf16x8 rv1 = *(const bf16x8*)(vp + 8);

  for (int kt = 0; kt < 64; kt++) {
    __syncthreads();   // previous tile fully consumed
    {
      int b0 = sr * 128 + sc * 2;
      *(bf16x8*)((char*)Ks + swz(b0)) = rk0;
      int b1 = (sr + 32) * 128 + sc * 2;
      *(bf16x8*)((char*)Ks + swz(b1)) = rk1;
      int vb0 = vd * 128 + vk0 * 2;
      *(bf16x8*)((char*)VTs + swz(vb0)) = rv0;
      *(bf16x8*)((char*)VTs + swz(vb0 + 16)) = rv1;
    }
    __syncthreads();   // LDS ready
    if (kt < 63) {     // prefetch next tile (bit-exact; hides HBM latency)
      kp0 += 64 * 1536; kp1 += 64 * 1536; vp += 64;
      rk0 = *(const bf16x8*)kp0;
      rk1 = *(const bf16x8*)kp1;
      rv0 = *(const bf16x8*)vp;
      rv1 = *(const bf16x8*)(vp + 8);
    }

    // S^T = mfma(A=K, B=Q): lane holds st[nb][r] = S[k=nb*16+l4*4+r][q=w*16+l15]
    f32x4 st[4] = {};
    __builtin_amdgcn_s_setprio(1);
#pragma unroll
    for (int kc = 0; kc < 2; kc++) {
#pragma unroll
      for (int nb = 0; nb < 4; nb++) {
        int byte = (nb * 16 + l15) * 128 + kc * 64 + l4 * 16;
        bf16x8 kf = *(const bf16x8*)((const char*)Ks + swz(byte));
        st[nb] = __builtin_amdgcn_mfma_f32_16x16x32_bf16(kf, qf[kc], st[nb], 0, 0, 0);
      }
    }
    __builtin_amdgcn_s_setprio(0);

    // lane-local online softmax (always rescale — round-3/8 exact numerics)
    float tm = -1e30f;
#pragma unroll
    for (int nb = 0; nb < 4; nb++)
#pragma unroll
      for (int r = 0; r < 4; r++) tm = fmaxf(tm, st[nb][r]);
    tm = fmaxf(tm, __shfl_xor(tm, 16));
    tm = fmaxf(tm, __shfl_xor(tm, 32));
    float mn = fmaxf(m, tm);
    float alpha = exp2f((m - mn) * C);
    float e[4][4];
    float ps = 0.f;
#pragma unroll
    for (int nb = 0; nb < 4; nb++)
#pragma unroll
      for (int r = 0; r < 4; r++) {
        e[nb][r] = exp2f((st[nb][r] - mn) * C);
        ps += e[nb][r];
      }
    ps += __shfl_xor(ps, 16);
    ps += __shfl_xor(ps, 32);
    l = l * alpha + ps;
    m = mn;
#pragma unroll
    for (int nb = 0; nb < 4; nb++) oaccT[nb] *= alpha;

    // P rows -> Ps[q][k] (lane writes its own q-row; wave-local, no barrier)
#pragma unroll
    for (int nb = 0; nb < 4; nb++) {
      uint2 pr;
      pr.x = pk_bf16(e[nb][0], e[nb][1]);
      pr.y = pk_bf16(e[nb][2], e[nb][3]);
      int byte = (w * 16 + l15) * 128 + (nb * 16 + l4 * 4) * 2;
      *(uint2*)((char*)Ps + swz(byte)) = pr;
    }

    // O^T += mfma(A=V^T, B=P)
#pragma unroll
    for (int kc = 0; kc < 2; kc++) {
      int bp = (w * 16 + l15) * 128 + kc * 64 + l4 * 16;
      bf16x8 pb = *(const bf16x8*)((const char*)Ps + swz(bp));
      __builtin_amdgcn_s_setprio(1);
#pragma unroll
      for (int nb = 0; nb < 4; nb++) {
        int bv = (nb * 16 + l15) * 128 + kc * 64 + l4 * 16;
        bf16x8 vf = *(const bf16x8*)((const char*)VTs + swz(bv));
        oaccT[nb] = __builtin_amdgcn_mfma_f32_16x16x32_bf16(vf, pb, oaccT[nb], 0, 0, 0);
      }
      __builtin_amdgcn_s_setprio(0);
    }
  }

  // epilogue: in-lane 1/l, packed 8-byte stores
  float linv = 1.f / l;
  int row = qt * 64 + w * 16 + l15;
#pragma unroll
  for (int nb = 0; nb < 4; nb++) {
    uint2 ov;
    ov.x = pk_bf16(oaccT[nb][0] * linv, oaccT[nb][1] * linv);
    ov.y = pk_bf16(oaccT[nb][2] * linv, oaccT[nb][3] * linv);
    int col = h * 64 + nb * 16 + l4 * 4;
    *(uint2*)&O[(size_t)row * 512 + col] = ov;
  }
}

// ---------------- fp32 GEMM (tiny stage-2 gating) ----------------
template<int ACT>
__global__ __launch_bounds__(256) void gemm_bias(
    const float* __restrict__ A, const float* __restrict__ B,
    const float* __restrict__ bias, float* __restrict__ C,
    int M, int N, int K)
{
  __shared__ float As[16][68];
  __shared__ float Bs[16][68];
  const int tid = threadIdx.x;
  const int tx = tid & 15, ty = tid >> 4;
  const int m0 = blockIdx.y * 64, n0 = blockIdx.x * 64;
  const int lr = tid >> 2;
  const int lk = (tid & 3) * 4;
  float acc[4][4] = {};
  for (int k0 = 0; k0 < K; k0 += 16) {
    __syncthreads();
    float4 av = *(const float4*)&A[(size_t)(m0 + lr) * K + k0 + lk];
    float4 bv = *(const float4*)&B[(size_t)(n0 + lr) * K + k0 + lk];
    As[lk + 0][lr] = av.x; As[lk + 1][lr] = av.y; As[lk + 2][lr] = av.z; As[lk + 3][lr] = av.w;
    Bs[lk + 0][lr] = bv.x; Bs[lk + 1][lr] = bv.y; Bs[lk + 2][lr] = bv.z; Bs[lk + 3][lr] = bv.w;
    __syncthreads();
#pragma unroll
    for (int k = 0; k < 16; k++) {
      float a[4], b[4];
#pragma unroll
      for (int i = 0; i < 4; i++) a[i] = As[k][ty * 4 + i];
#pragma unroll
      for (int j = 0; j < 4; j++) b[j] = Bs[k][tx * 4 + j];
#pragma unroll
      for (int i = 0; i < 4; i++)
#pragma unroll
        for (int j = 0; j < 4; j++)
          acc[i][j] = fmaf(a[i], b[j], acc[i][j]);
    }
  }
#pragma unroll
  for (int i = 0; i < 4; i++)
#pragma unroll
    for (int j = 0; j < 4; j++) {
      float x = acc[i][j] + bias[n0 + tx * 4 + j];
      if (ACT == 1) x = fmaxf(x, 0.f);
      if (ACT == 2) x = tanhf(x);
      if (ACT == 3) x = 1.f / (1.f + expf(-x));
      C[(size_t)(m0 + ty * 4 + i) * N + n0 + tx * 4 + j] = x;
    }
}

// ---------------- LayerNorm(x + res), writes f32 + bf16 ----------------
__global__ __launch_bounds__(64) void residual_ln(
    const float* __restrict__ x, const float* __restrict__ res,
    const float* __restrict__ g, const float* __restrict__ b,
    float* __restrict__ out, unsigned short* __restrict__ out_bf)
{
  const int row = blockIdx.x, lane = threadIdx.x;
  const float* xp = x + (size_t)row * 512;
  const float* rp = res + (size_t)row * 512;
  float v[8];
  float s = 0.f;
#pragma unroll
  for (int i = 0; i < 8; i++) { v[i] = xp[lane + 64 * i] + rp[lane + 64 * i]; s += v[i]; }
  s = wave_sum64(s);
  float mu = s * (1.f / 512.f);
  float vs = 0.f;
#pragma unroll
  for (int i = 0; i < 8; i++) { float d = v[i] - mu; vs = fmaf(d, d, vs); }
  vs = wave_sum64(vs);
  float rstd = rsqrtf(vs * (1.f / 512.f) + 1e-5f);
  float* op = out + (size_t)row * 512;
  unsigned short* ob = out_bf + (size_t)row * 512;
#pragma unroll
  for (int i = 0; i < 8; i++) {
    float y = (v[i] - mu) * rstd * g[lane + 64 * i] + b[lane + 64 * i];
    op[lane + 64 * i] = y;
    ob[lane + 64 * i] = f2bf(y);
  }
}

// ---------------- multi-job f32 -> bf16 cast (one launch per batch) ----------------
struct CastJobs {
  const float* src[6];
  unsigned short* dst[6];
  int n4[6];
  int njobs;
};

__global__ void cast_multi(CastJobs J)
{
  for (int j = 0; j < J.njobs; j++) {
    const float4* s = (const float4*)J.src[j];
    ushort4* d = (ushort4*)J.dst[j];
    int n = J.n4[j];
    for (int i = blockIdx.x * 256 + threadIdx.x; i < n; i += gridDim.x * 256) {
      float4 v = s[i];
      ushort4 u;
      u.x = f2bf(v.x); u.y = f2bf(v.y); u.z = f2bf(v.z); u.w = f2bf(v.w);
      d[i] = u;
    }
  }
}

__global__ void init_h(const float* __restrict__ in, float* __restrict__ hf,
                       unsigned short* __restrict__ hb, int n4)
{
  int i = blockIdx.x * 256 + threadIdx.x;
  if (i < n4) {
    float4 v = ((const float4*)in)[i];
    ((float4*)hf)[i] = v;
    ushort4 u;
    u.x = f2bf(v.x); u.y = f2bf(v.y); u.z = f2bf(v.z); u.w = f2bf(v.w);
    ((ushort4*)hb)[i] = u;
  }
}

// ---------------- A[t] = sum_l Gv*Gu*Ww + bw ----------------
__global__ __launch_bounds__(128) void gate_dot(
    const float* __restrict__ Gv, const float* __restrict__ Gu, int ld,
    const float* __restrict__ Ww, const float* __restrict__ bw,
    float* __restrict__ A)
{
  const int t = blockIdx.x, l = threadIdx.x;
  float v = Gv[(size_t)t * ld + l] * Gu[(size_t)t * ld + l] * Ww[l];
  v = wave_sum64(v);
  __shared__ float red[2];
  if ((l & 63) == 0) red[l >> 6] = v;
  __syncthreads();
  if (l == 0) A[t] = red[0] + red[1] + bw[0];
}

// ------- contiguous-segment softmax + weighted pooled sum (D=512) -------
__global__ __launch_bounds__(256) void seg_pool(
    const float* __restrict__ A, const float* __restrict__ X,
    float* __restrict__ w_out, float* __restrict__ out, int seg_len)
{
  const int s = blockIdx.x, tid = threadIdx.x;
  __shared__ float ws[16];
  if (tid < 64) {
    float a = (tid < seg_len) ? A[s * seg_len + tid] : -1e30f;
    float mx = a;
#pragma unroll
    for (int o = 1; o < 16; o <<= 1) mx = fmaxf(mx, __shfl_xor(mx, o));
    float e = (tid < seg_len) ? expf(a - mx) : 0.f;
    float se = e;
#pragma unroll
    for (int o = 1; o < 16; o <<= 1) se += __shfl_xor(se, o);
    if (tid < seg_len) {
      float w = e / se;
      ws[tid] = w;
      w_out[s * seg_len + tid] = w;
    }
  }
  __syncthreads();
  for (int d = tid; d < 512; d += 256) {
    float acc = 0.f;
    for (int i = 0; i < seg_len; i++)
      acc = fmaf(ws[i], X[(size_t)(s * seg_len + i) * 512 + d], acc);
    out[(size_t)s * 512 + d] = acc;
  }
}

// ======================= CNN head (channels-last [n][L][C=128]) =======================

__global__ void conv1_bnT(
    const float* __restrict__ x, const float* __restrict__ K4,
    const float* __restrict__ bias, const float* __restrict__ g,
    const float* __restrict__ bb, unsigned short* __restrict__ y)
{
  int idx = blockIdx.x * 256 + threadIdx.x;   // (n*512+i)*128+o
  int o = idx & 127, i = (idx >> 7) & 511, n = idx >> 16;
  const float* xp = x + n * 512;
  float acc = bias[o];
#pragma unroll
  for (int k = 0; k < 4; k++) {
    int p = i + k - 1;
    float xv = (p >= 0 && p < 512) ? xp[p] : 0.f;
    acc = fmaf(xv, K4[o * 4 + k], acc);
  }
  float sc = g[o] * rsqrtf(1.f + 1e-5f);
  y[idx] = f2bf(fmaxf(fmaf(acc, sc, bb[o]), 0.f));
}

__global__ void reorder_w(const float* __restrict__ Kc, unsigned short* __restrict__ Wr,
                          int KS, int total)
{
  int idx = blockIdx.x * 256 + threadIdx.x;
  if (idx < total) {
    int c = idx & 127;
    int kk = (idx >> 7) % KS;
    int o = idx / (128 * KS);
    Wr[idx] = f2bf(Kc[(o * 128 + c) * KS + kk]);
  }
}

template<int KS, int PAD, int LEN, int OUTF>
__global__ __launch_bounds__(256) void convT_mfma(
    const unsigned short* __restrict__ X, const unsigned short* __restrict__ Wr,
    const float* __restrict__ bias, const float* __restrict__ g,
    const float* __restrict__ bb,
    unsigned short* __restrict__ Yb, float* __restrict__ Yf)
{
  constexpr int ROWS = 64 + KS - 1;
  __shared__ __align__(16) unsigned short XT[ROWS * 128];
  const int tid = threadIdx.x;
  const int w = tid >> 6, lane = tid & 63;
  const int l15 = lane & 15, l4 = lane >> 4;
  const int i0 = (blockIdx.x >> 1) * 64;
  const int o0 = (blockIdx.x & 1) * 64;
  const int n = blockIdx.y;

  {
    const int c = (tid & 15) * 8;
    for (int r = tid >> 4; r < ROWS; r += 16) {
      int gi = i0 - PAD + r;
      bf16x8 v = {};
      if (gi >= 0 && gi < LEN)
        v = *(const bf16x8*)&X[((size_t)n * LEN + gi) * 128 + c];
      int byte = r * 256 + c * 2;
      *(bf16x8*)((char*)XT + swz256(byte)) = v;
    }
  }
  __syncthreads();

  f32x4 acc[4] = {};
#pragma unroll
  for (int kk = 0; kk < KS; kk++) {
#pragma unroll
    for (int cc = 0; cc < 4; cc++) {
      int r = w * 16 + l15 + kk;
      int byte = r * 256 + cc * 64 + l4 * 16;
      bf16x8 a = *(const bf16x8*)((const char*)XT + swz256(byte));
      bf16x8 bfr[4];
#pragma unroll
      for (int nb = 0; nb < 4; nb++)
        bfr[nb] = *(const bf16x8*)&Wr[(size_t)(o0 + nb * 16 + l15) * (KS * 128) +
                                      kk * 128 + cc * 32 + l4 * 8];
#pragma unroll
      for (int nb = 0; nb < 4; nb++)
        acc[nb] = __builtin_amdgcn_mfma_f32_16x16x32_bf16(a, bfr[nb], acc[nb], 0, 0, 0);
    }
  }

#pragma unroll
  for (int nb = 0; nb < 4; nb++) {
    int o = o0 + nb * 16 + l15;
    float sc = g[o] * rsqrtf(1.f + 1e-5f);
    float bs = bias[o], bo_ = bb[o];
#pragma unroll
    for (int rr = 0; rr < 4; rr++) {
      int i = i0 + w * 16 + l4 * 4 + rr;
      float v = fmaxf(fmaf(acc[nb][rr] + bs, sc, bo_), 0.f);
      size_t oidx = ((size_t)n * LEN + i) * 128 + o;
      if (OUTF) Yf[oidx] = v;
      else Yb[oidx] = f2bf(v);
    }
  }
}

__global__ void avgpool2_bf(const unsigned short* __restrict__ x,
                            unsigned short* __restrict__ y, int nI, int nTot4)
{
  int j = blockIdx.x * 256 + threadIdx.x;
  if (j >= nTot4) return;
  int cq = j & 31;
  int i = (j >> 5) % nI;
  int n = j / (nI * 32);
  const ushort4* a = (const ushort4*)&x[(((size_t)n * nI + i) * 2) * 128 + cq * 4];
  const ushort4* b = (const ushort4*)&x[(((size_t)n * nI + i) * 2 + 1) * 128 + cq * 4];
  ushort4 ua = *a, ub = *b;
  ushort4 r;
  r.x = f2bf(0.5f * (bf2f(ua.x) + bf2f(ub.x)));
  r.y = f2bf(0.5f * (bf2f(ua.y) + bf2f(ub.y)));
  r.z = f2bf(0.5f * (bf2f(ua.z) + bf2f(ub.z)));
  r.w = f2bf(0.5f * (bf2f(ua.w) + bf2f(ub.w)));
  ((ushort4*)y)[j] = r;
}

__global__ void pool3_transpose(const float* __restrict__ x, float* __restrict__ y)
{
  int j = blockIdx.x * 256 + threadIdx.x;   // n*16384 + c*128 + i
  if (j >= 524288) return;
  int i = j & 127, c = (j >> 7) & 127, n = j >> 14;
  const float* b = x + ((size_t)n * 256 + 2 * i) * 128 + c;
  y[j] = 0.5f * (b[0] + b[128]);
}

__global__ __launch_bounds__(256) void fc1_kernel(
    const float* __restrict__ x, const float* __restrict__ W,
    const float* __restrict__ bias, const float* __restrict__ g,
    const float* __restrict__ bb, float* __restrict__ y)
{
  int o = blockIdx.x & 255, n = blockIdx.x >> 8;
  const float* xp = x + (size_t)n * 16384;
  const float* wp = W + (size_t)o * 16384;
  float s = 0.f;
  for (int j = threadIdx.x * 4; j < 16384; j += 1024) {
    float4 a = *(const float4*)(xp + j);
    float4 b = *(const float4*)(wp + j);
    s = fmaf(a.x, b.x, s); s = fmaf(a.y, b.y, s);
    s = fmaf(a.z, b.z, s); s = fmaf(a.w, b.w, s);
  }
  s = wave_sum64(s);
  __shared__ float red[4];
  if ((threadIdx.x & 63) == 0) red[threadIdx.x >> 6] = s;
  __syncthreads();
  if (threadIdx.x == 0) {
    float v = red[0] + red[1] + red[2] + red[3] + bias[o];
    v = fmaxf(v, 0.f);
    y[n * 256 + o] = fmaf(v, g[o] * rsqrtf(1.f + 1e-5f), bb[o]);
  }
}

__global__ __launch_bounds__(256) void fc2_kernel(
    const float* __restrict__ x, const float* __restrict__ W,
    const float* __restrict__ bias, const float* __restrict__ g,
    const float* __restrict__ bb, float* __restrict__ y)
{
  int o = blockIdx.x & 127, n = blockIdx.x >> 7;
  float s = x[n * 256 + threadIdx.x] * W[o * 256 + threadIdx.x];
  s = wave_sum64(s);
  __shared__ float red[4];
  if ((threadIdx.x & 63) == 0) red[threadIdx.x >> 6] = s;
  __syncthreads();
  if (threadIdx.x == 0) {
    float v = red[0] + red[1] + red[2] + red[3] + bias[o];
    v = fmaxf(v, 0.f);
    y[n * 128 + o] = fmaf(v, g[o] * rsqrtf(1.f + 1e-5f), bb[o]);
  }
}

__global__ __launch_bounds__(64) void fc3_kernel(
    const float* __restrict__ x, const float* __restrict__ W,
    const float* __restrict__ bias, float* __restrict__ out)
{
  int n = threadIdx.x;
  if (n < 32) {
    float s = bias[0];
    for (int k = 0; k < 128; k++) s = fmaf(x[n * 128 + k], W[k], s);
    float p = 1.f / (1.f + expf(-s));
    out[n] = p;
    out[32 + n] = (p >= 0.5f) ? 1.f : 0.f;
  }
}

extern "C" void kernel_launch(void* const* d_in, const int* in_sizes, int n_in,
                              void* d_out, int out_size, void* d_ws, size_t ws_size,
                              hipStream_t stream)
{
  const float* datas = (const float*)d_in[0];
  const float* Wqkv = (const float*)d_in[6];
  const float* bqkv = (const float*)d_in[7];
  const float* Wo   = (const float*)d_in[8];
  const float* bo   = (const float*)d_in[9];
  const float* ln1g = (const float*)d_in[10];
  const float* ln1b = (const float*)d_in[11];
  const float* W1   = (const float*)d_in[12];
  const float* b1   = (const float*)d_in[13];
  const float* W2   = (const float*)d_in[14];
  const float* b2   = (const float*)d_in[15];
  const float* ln2g = (const float*)d_in[16];
  const float* ln2b = (const float*)d_in[17];
  const float* Wv1  = (const float*)d_in[18];
  const float* bv1  = (const float*)d_in[19];
  const float* Wu1  = (const float*)d_in[20];
  const float* bu1  = (const float*)d_in[21];
  const float* Ww1  = (const float*)d_in[22];
  const float* bw1  = (const float*)d_in[23];
  const float* Wv2  = (const float*)d_in[24];
  const float* bv2  = (const float*)d_in[25];
  const float* Wu2  = (const float*)d_in[26];
  const float* bu2  = (const float*)d_in[27];
  const float* Ww2  = (const float*)d_in[28];
  const float* bw2  = (const float*)d_in[29];
  const float* Kc1  = (const float*)d_in[30];
  const float* bc1  = (const float*)d_in[31];
  const float* gc1  = (const float*)d_in[32];
  const float* bb1  = (const float*)d_in[33];
  const float* Kc2  = (const float*)d_in[34];
  const float* bc2  = (const float*)d_in[35];
  const float* gc2  = (const float*)d_in[36];
  const float* bb2  = (const float*)d_in[37];
  const float* Kc3  = (const float*)d_in[38];
  const float* bc3  = (const float*)d_in[39];
  const float* gc3  = (const float*)d_in[40];
  const float* bb3  = (const float*)d_in[41];
  const float* Wf1  = (const float*)d_in[42];
  const float* bf1  = (const float*)d_in[43];
  const float* g4   = (const float*)d_in[44];
  const float* b4   = (const float*)d_in[45];
  const float* Wf2  = (const float*)d_in[46];
  const float* bf2  = (const float*)d_in[47];
  const float* g5   = (const float*)d_in[48];
  const float* b5   = (const float*)d_in[49];
  const float* Wf3  = (const float*)d_in[50];
  const float* bf3  = (const float*)d_in[51];

  float* ws = (float*)d_ws;
  float* h_f32 = ws;                              // 2,097,152 f
  float* R2f   = ws + 2097152;                    // 6,291,456 f
  unsigned short* h_bf = (unsigned short*)(ws + 8388608);   // 2,097,152 ush
  unsigned short* wbuf = (unsigned short*)(ws + 9437184);   // 3,473,408 ush
  float* biasG = ws + 11173888;                   // 256 f
  unsigned short* VTg = (unsigned short*)(ws + 11174144);   // 2,097,152 ush (V^T [512][4096])
  // total ws: 12,222,720 floats = 48.9 MB (round-1 peak 50.3 MB fit)

  unsigned short* qkv_bf = (unsigned short*)R2f;
  unsigned short* O_bf   = (unsigned short*)(R2f + 3145728);
  unsigned short* ff1_bf = (unsigned short*)R2f;
  float* projf = R2f + 4194304;

  unsigned short* WqkvB = wbuf;                 // 786,432 (per-layer reuse)
  unsigned short* WoB   = wbuf + 786432;        // 262,144
  unsigned short* W1B   = wbuf + 1048576;       // 1,048,576
  unsigned short* W2B   = wbuf + 2097152;       // 1,048,576
  unsigned short* WvuB  = wbuf + 3145728;       // 131,072 (persistent tail)
  unsigned short* Wr2B  = wbuf + 3276800;       // 81,920
  unsigned short* Wr3B  = wbuf + 3358720;       // 114,688

  float* out_f = (float*)d_out;

  init_h<<<2048, 256, 0, stream>>>(datas, h_f32, h_bf, 524288);
  reorder_w<<<320, 256, 0, stream>>>(Kc2, Wr2B, 5, 81920);
  reorder_w<<<448, 256, 0, stream>>>(Kc3, Wr3B, 7, 114688);
  hipMemcpyAsync(biasG, bv1, 128 * sizeof(float), hipMemcpyDeviceToDevice, stream);
  hipMemcpyAsync(biasG + 128, bu1, 128 * sizeof(float), hipMemcpyDeviceToDevice, stream);

  for (int l = 0; l < 2; l++) {
    CastJobs J{};
    J.src[0] = Wqkv + (size_t)l * 786432;  J.dst[0] = WqkvB; J.n4[0] = 196608;
    J.src[1] = Wo   + (size_t)l * 262144;  J.dst[1] = WoB;   J.n4[1] = 65536;
    J.src[2] = W1   + (size_t)l * 1048576; J.dst[2] = W1B;   J.n4[2] = 262144;
    J.src[3] = W2   + (size_t)l * 1048576; J.dst[3] = W2B;   J.n4[3] = 262144;
    J.njobs = 4;
    if (l == 0) {
      J.src[4] = Wv1; J.dst[4] = WvuB;         J.n4[4] = 16384;
      J.src[5] = Wu1; J.dst[5] = WvuB + 65536; J.n4[5] = 16384;
      J.njobs = 6;
    }
    cast_multi<<<512, 256, 0, stream>>>(J);

    // qkv: Q,K -> qkv_bf [t][1536]; V -> VTg [h*64+d][t]
    mgemm<0, 1, 1><<<dim3(12, 32), 256, 0, stream>>>(
        h_bf, WqkvB, bqkv + (size_t)l * 1536, nullptr, qkv_bf, VTg, 4096, 1536, 512);
    attn_mfma<<<dim3(64, 8), 256, 0, stream>>>(qkv_bf, VTg, O_bf);
    mgemm<0, 0, 0><<<dim3(4, 32), 256, 0, stream>>>(
        O_bf, WoB, bo + (size_t)l * 512, projf, nullptr, nullptr, 4096, 512, 512);
    residual_ln<<<4096, 64, 0, stream>>>(projf, h_f32, ln1g + l * 512, ln1b + l * 512,
                                         h_f32, h_bf);
    mgemm<1, 1, 0><<<dim3(16, 32), 256, 0, stream>>>(
        h_bf, W1B, b1 + (size_t)l * 2048, nullptr, ff1_bf, nullptr, 4096, 2048, 512);
    mgemm<0, 0, 0><<<dim3(4, 32), 256, 0, stream>>>(
        ff1_bf, W2B, b2 + (size_t)l * 512, projf, nullptr, nullptr, 4096, 512, 2048);
    residual_ln<<<4096, 64, 0, stream>>>(projf, h_f32, ln2g + l * 512, ln2b + l * 512,
                                         h_f32, h_bf);
  }

  // ---- gated pooling (stage 1: fused tanh/sigmoid GEMM, N=256) ----
  float* G    = R2f;              // 4096 x 256
  float* A1   = R2f + 1048576;
  float* out1 = R2f + 1052672;
  float* Gv2  = R2f + 1183744;
  float* Gu2  = R2f + 1216512;
  float* A2   = R2f + 1249280;
  float* out2 = R2f + 1249536;

  mgemm<4, 0, 0><<<dim3(2, 32), 256, 0, stream>>>(
      h_bf, WvuB, biasG, G, nullptr, nullptr, 4096, 256, 512);
  gate_dot<<<4096, 128, 0, stream>>>(G, G + 128, 256, Ww1, bw1, A1);
  seg_pool<<<256, 256, 0, stream>>>(A1, h_f32, out_f + 64, out1, 16);

  gemm_bias<2><<<dim3(2, 4), 256, 0, stream>>>(out1, Wv2, bv2, Gv2, 256, 128, 512);
  gemm_bias<3><<<dim3(2, 4), 256, 0, stream>>>(out1, Wu2, bu2, Gu2, 256, 128, 512);
  gate_dot<<<256, 128, 0, stream>>>(Gv2, Gu2, 128, Ww2, bw2, A2);
  seg_pool<<<32, 256, 0, stream>>>(A2, out1, out_f + 4160, out2, 8);

  // ---- CNN head, channels-last ----
  unsigned short* c1T = (unsigned short*)(R2f + 1310720);  // 2,097,152 ush
  unsigned short* c2T = (unsigned short*)(R2f + 2359296);  // 2,097,152 ush
  unsigned short* p2T = (unsigned short*)(R2f + 3407872);  // 1,048,576 ush
  float* c3T = R2f + 3932160;                              // 1,048,576 f
  float* p3R = R2f + 4980736;                              // 524,288 f
  float* f1  = R2f + 5505024;
  float* f2  = R2f + 5513216;

  conv1_bnT<<<8192, 256, 0, stream>>>(out2, Kc1, bc1, gc1, bb1, c1T);
  convT_mfma<5, 2, 512, 0><<<dim3(16, 32), 256, 0, stream>>>(
      c1T, Wr2B, bc2, gc2, bb2, c2T, nullptr);
  avgpool2_bf<<<1024, 256, 0, stream>>>(c2T, p2T, 256, 262144);
  convT_mfma<7, 3, 256, 1><<<dim3(8, 32), 256, 0, stream>>>(
      p2T, Wr3B, bc3, gc3, bb3, nullptr, c3T);
  pool3_transpose<<<2048, 256, 0, stream>>>(c3T, p3R);
  fc1_kernel<<<8192, 256, 0, stream>>>(p3R, Wf1, bf1, g4, b4, f1);
  fc2_kernel<<<4096, 256, 0, stream>>>(f1, Wf2, bf2, g5, b5, f2);
  fc3_kernel<<<1, 64, 0, stream>>>(f2, Wf3, bf3, out_f);
}